// Round 1
// baseline (682.854 us; speedup 1.0000x reference)
//
#include <hip/hip_runtime.h>

#define EPS 1e-5f

// Problem constants
// B=4, C=64, H=128, W=128, N=B*W=512, OP2=128, HEAD=8, HP=16, qk_dim=4, v_dim=8

// workspace layout (float offsets)
//  y1: (b,l,o,w)  8,388,608 floats   [dead after k_tr; reused for av/avp]
//  y2: (n,o,l)    8,388,608 floats at 8,388,608
//  av : (n,h,c,p) 4,194,304 at 0      (overlaps y1)
//  avp: (n,h,c,p) 4,194,304 at 4,194,304
//  S  : stats 1024 floats at 16,777,216
//    [0..127] bn1 sum   [128..255] bn1 sumsq
//    [256..383] sc1     [384..511] sh1
//    [512..535] att sum (g*8+h)  [536..559] att sumsq
//    [560..567] C0  [568..575] C1  [576..583] C2  [584..591] C3
//    [592..607] v sum (av: h, avp: 8+h)  [608..623] v sumsq
//    [624..631] scv [632..639] shv [640..647] scvp [648..655] shvp

// ---------------- K1: qkv GEMM + relu + bn1 partial stats --------------------
__global__ __launch_bounds__(256) void k1_gemm(
    const float* __restrict__ x, const float* __restrict__ wq,
    float* __restrict__ y1, float* __restrict__ S)
{
  __shared__ float xs[64][132];
  const int b = blockIdx.x >> 7, l = blockIdx.x & 127;
  const int tid = threadIdx.x;
  const float* xp = x + (size_t)b * 1048576 + (size_t)l * 128;
  for (int idx = tid; idx < 8192; idx += 256) {
    int c = idx >> 7, wv = idx & 127;
    xs[c][wv] = xp[c * 16384 + wv];
  }
  __syncthreads();
  const int ty = tid >> 4, tx = tid & 15;
  const int o0 = ty * 8, w0 = tx * 4;
  float acc[8][8];
#pragma unroll
  for (int u = 0; u < 8; ++u)
#pragma unroll
    for (int v = 0; v < 8; ++v) acc[u][v] = 0.f;

  for (int c4 = 0; c4 < 64; c4 += 4) {
    float wr[8][4];
#pragma unroll
    for (int u = 0; u < 8; ++u)
      *(float4*)&wr[u][0] = *(const float4*)&wq[(o0 + u) * 64 + c4];
#pragma unroll
    for (int dc = 0; dc < 4; ++dc) {
      float4 xa = *(const float4*)&xs[c4 + dc][w0];
      float4 xb = *(const float4*)&xs[c4 + dc][w0 + 64];
#pragma unroll
      for (int u = 0; u < 8; ++u) {
        float wv = wr[u][dc];
        acc[u][0] += wv * xa.x; acc[u][1] += wv * xa.y;
        acc[u][2] += wv * xa.z; acc[u][3] += wv * xa.w;
        acc[u][4] += wv * xb.x; acc[u][5] += wv * xb.y;
        acc[u][6] += wv * xb.z; acc[u][7] += wv * xb.w;
      }
    }
  }
  float* y1p = y1 + (size_t)(b * 128 + l) * 16384;
#pragma unroll
  for (int u = 0; u < 8; ++u) {
#pragma unroll
    for (int v = 0; v < 8; ++v) acc[u][v] = fmaxf(acc[u][v], 0.f);
    float4 r0 = make_float4(acc[u][0], acc[u][1], acc[u][2], acc[u][3]);
    float4 r1 = make_float4(acc[u][4], acc[u][5], acc[u][6], acc[u][7]);
    *(float4*)&y1p[(o0 + u) * 128 + w0] = r0;
    *(float4*)&y1p[(o0 + u) * 128 + w0 + 64] = r1;
    float s  = acc[u][0] + acc[u][1] + acc[u][2] + acc[u][3]
             + acc[u][4] + acc[u][5] + acc[u][6] + acc[u][7];
    float ss = acc[u][0]*acc[u][0] + acc[u][1]*acc[u][1] + acc[u][2]*acc[u][2]
             + acc[u][3]*acc[u][3] + acc[u][4]*acc[u][4] + acc[u][5]*acc[u][5]
             + acc[u][6]*acc[u][6] + acc[u][7]*acc[u][7];
#pragma unroll
    for (int off = 1; off < 16; off <<= 1) {
      s  += __shfl_xor(s, off);
      ss += __shfl_xor(ss, off);
    }
    if (tx == 0) {
      atomicAdd(&S[o0 + u], s);
      atomicAdd(&S[128 + o0 + u], ss);
    }
  }
}

// ---------------- K2: finalize bn1 -> scale/shift ---------------------------
__global__ void k2_bn1(float* __restrict__ S, const float* __restrict__ g1,
                       const float* __restrict__ b1)
{
  int o = threadIdx.x;
  if (o >= 128) return;
  const float inv = 1.f / 65536.f;
  float m = S[o] * inv;
  float var = S[128 + o] * inv - m * m;
  float sc = g1[o] * rsqrtf(var + EPS);
  S[256 + o] = sc;
  S[384 + o] = b1[o] - m * sc;
}

// ---------------- K_tr: (b,l,o,w) -> (n=b*128+w, o, l) ----------------------
__global__ __launch_bounds__(256) void k_tr(const float* __restrict__ y1,
                                            float* __restrict__ y2)
{
  __shared__ float t[64][129];
  const int b = blockIdx.x >> 7, o = blockIdx.x & 127;
  const int tid = threadIdx.x;
  for (int half = 0; half < 2; ++half) {
    const int l0 = half * 64;
    for (int idx = tid; idx < 8192; idx += 256) {
      int ll = idx >> 7, wv = idx & 127;
      t[ll][wv] = y1[(size_t)b * 2097152 + (size_t)(l0 + ll) * 16384 + o * 128 + wv];
    }
    __syncthreads();
    for (int idx = tid; idx < 8192; idx += 256) {
      int wv = idx >> 6, ll = idx & 63;
      y2[((size_t)(b * 128 + wv) * 128 + o) * 128 + l0 + ll] = t[ll][wv];
    }
    __syncthreads();
  }
}

// ---------------- K3: att stats pass (raw sums, gates applied later) --------
__global__ __launch_bounds__(256) void k3_stats(
    const float* __restrict__ y2, const float* __restrict__ pos,
    float* __restrict__ S)
{
  __shared__ float qk_s[8][128];
  __shared__ float pos_s[8][256];
  __shared__ float red[4][6];
  const int n = blockIdx.x >> 3, h = blockIdx.x & 7;
  const int tid = threadIdx.x;
  const float* yb = y2 + ((size_t)n * 128 + h * 16) * 128;
  for (int idx = tid; idx < 1024; idx += 256) {
    int j = idx >> 7, l = idx & 127;
    qk_s[j][l] = yb[j * 128 + l] * S[256 + h * 16 + j] + S[384 + h * 16 + j];
  }
  for (int r = 0; r < 8; ++r)
    for (int u = tid; u < 255; u += 256) pos_s[r][u] = pos[r * 255 + u];
  __syncthreads();

  float s0 = 0, ss0 = 0, s1 = 0, ss1 = 0, s2 = 0, ss2 = 0;
  for (int idx = tid; idx < 16384; idx += 256) {
    int i = idx & 127, p = idx >> 7, u = p - i + 127;
    float a = 0, bq = 0, ck = 0;
#pragma unroll
    for (int c = 0; c < 4; ++c) {
      float qcp = qk_s[c][p], kcp = qk_s[4 + c][p];
      a  += qcp * qk_s[4 + c][i];
      bq += qcp * pos_s[c][u];
      ck += kcp * pos_s[4 + c][u];
    }
    s0 += a;  ss0 += a * a;
    s1 += bq; ss1 += bq * bq;
    s2 += ck; ss2 += ck * ck;
  }
  float vals[6] = {s0, ss0, s1, ss1, s2, ss2};
#pragma unroll
  for (int k = 0; k < 6; ++k) {
    float v = vals[k];
#pragma unroll
    for (int off = 1; off < 64; off <<= 1) v += __shfl_xor(v, off);
    vals[k] = v;
  }
  const int wid = tid >> 6, lane = tid & 63;
  if (lane == 0) {
#pragma unroll
    for (int k = 0; k < 6; ++k) red[wid][k] = vals[k];
  }
  __syncthreads();
  if (tid == 0) {
#pragma unroll
    for (int k = 0; k < 6; ++k) {
      float tv = red[0][k] + red[1][k] + red[2][k] + red[3][k];
      int g = k >> 1;
      atomicAdd(&S[((k & 1) ? 536 : 512) + g * 8 + h], tv);
    }
  }
}

// ---------------- K4: finalize att bn -> per-head coefs ---------------------
__global__ void k4_att(float* __restrict__ S, const float* __restrict__ ga,
                       const float* __restrict__ ba,
                       const float* __restrict__ gqr, const float* __restrict__ gkr)
{
  int h = threadIdx.x;
  if (h >= 8) return;
  const float inv = 1.f / 8388608.f;
  float gates[3] = {1.f, gqr[0], gkr[0]};
  float csum = 0.f;
#pragma unroll
  for (int g = 0; g < 3; ++g) {
    float mr = S[512 + g * 8 + h] * inv;
    float er = S[536 + g * 8 + h] * inv;
    float gt = gates[g];
    float mean = gt * mr;
    float var = gt * gt * er - mean * mean;
    float sc = ga[g * 8 + h] * rsqrtf(var + EPS);
    S[560 + g * 8 + h] = gt * sc;
    csum += ba[g * 8 + h] - mean * sc;
  }
  S[584 + h] = csum;
}

// ---------------- K5: scores + softmax + PV + v-bn partial stats ------------
__global__ __launch_bounds__(256) void k5_apply(
    const float* __restrict__ y2, const float* __restrict__ pos,
    float* __restrict__ S, float* __restrict__ av, float* __restrict__ avp,
    const float* __restrict__ gv_p, const float* __restrict__ gvp_p)
{
  __shared__ float qkv_s[16][128];
  __shared__ float pos_s[16][256];
  __shared__ float sl[64][129];
  __shared__ float red[4][4];
  const int ph = blockIdx.x & 1, h = (blockIdx.x >> 1) & 7, n = blockIdx.x >> 4;
  const int p0 = ph * 64;
  const int tid = threadIdx.x;
  const float* yb = y2 + ((size_t)n * 128 + h * 16) * 128;
  for (int idx = tid; idx < 2048; idx += 256) {
    int j = idx >> 7, l = idx & 127;
    qkv_s[j][l] = yb[j * 128 + l] * S[256 + h * 16 + j] + S[384 + h * 16 + j];
  }
  for (int r = 0; r < 16; ++r)
    for (int u = tid; u < 255; u += 256) pos_s[r][u] = pos[r * 255 + u];
  __syncthreads();

  const float C0 = S[560 + h], C1 = S[568 + h], C2 = S[576 + h], C3 = S[584 + h];
  for (int idx = tid; idx < 8192; idx += 256) {
    int i = idx & 127, pl = idx >> 7, p = p0 + pl, u = p - i + 127;
    float a = 0, bq = 0, ck = 0;
#pragma unroll
    for (int c = 0; c < 4; ++c) {
      float qcp = qkv_s[c][p], kcp = qkv_s[4 + c][p];
      a  += qcp * qkv_s[4 + c][i];
      bq += qcp * pos_s[c][u];
      ck += kcp * pos_s[4 + c][u];
    }
    sl[pl][i] = a * C0 + bq * C1 + ck * C2 + C3;
  }
  __syncthreads();

  const int wid = tid >> 6, lane = tid & 63;
  for (int r = 0; r < 16; ++r) {
    int pl = wid * 16 + r;
    float a0 = sl[pl][lane], a1 = sl[pl][64 + lane];
    float m = fmaxf(a0, a1);
#pragma unroll
    for (int off = 1; off < 64; off <<= 1) m = fmaxf(m, __shfl_xor(m, off));
    float e0 = __expf(a0 - m), e1 = __expf(a1 - m);
    float s = e0 + e1;
#pragma unroll
    for (int off = 1; off < 64; off <<= 1) s += __shfl_xor(s, off);
    float invs = 1.0f / s;
    sl[pl][lane] = e0 * invs;
    sl[pl][64 + lane] = e1 * invs;
  }
  __syncthreads();

  const float gv = gv_p[0], gvp = gvp_p[0];
  float sv = 0, ssv = 0, svp = 0, ssvp = 0;
#pragma unroll
  for (int t = 0; t < 2; ++t) {
    int oidx = t * 256 + tid;
    int pl = oidx & 63, c = oidx >> 6;
    int p = p0 + pl;
    float accv = 0, accvp = 0;
    for (int i = 0; i < 128; ++i) {
      float a = sl[pl][i];
      accv  += a * qkv_s[8 + c][i];
      accvp += a * pos_s[8 + c][p - i + 127];
    }
    accv *= gv; accvp *= gvp;
    av [(((size_t)n * 8 + h) * 8 + c) * 128 + p] = accv;
    avp[(((size_t)n * 8 + h) * 8 + c) * 128 + p] = accvp;
    sv += accv; ssv += accv * accv; svp += accvp; ssvp += accvp * accvp;
  }
  float vals[4] = {sv, ssv, svp, ssvp};
#pragma unroll
  for (int k = 0; k < 4; ++k) {
    float v = vals[k];
#pragma unroll
    for (int off = 1; off < 64; off <<= 1) v += __shfl_xor(v, off);
    vals[k] = v;
  }
  if (lane == 0) {
#pragma unroll
    for (int k = 0; k < 4; ++k) red[wid][k] = vals[k];
  }
  __syncthreads();
  if (tid == 0) {
    float t0 = red[0][0] + red[1][0] + red[2][0] + red[3][0];
    float t1 = red[0][1] + red[1][1] + red[2][1] + red[3][1];
    float t2 = red[0][2] + red[1][2] + red[2][2] + red[3][2];
    float t3 = red[0][3] + red[1][3] + red[2][3] + red[3][3];
    atomicAdd(&S[592 + h], t0);
    atomicAdd(&S[608 + h], t1);
    atomicAdd(&S[600 + h], t2);
    atomicAdd(&S[616 + h], t3);
  }
}

// ---------------- K6: finalize v bn ----------------------------------------
__global__ void k6_v(float* __restrict__ S, const float* __restrict__ gv,
                     const float* __restrict__ bv)
{
  int h = threadIdx.x;
  if (h >= 8) return;
  const float inv = 1.f / 524288.f;
  float m = S[592 + h] * inv;
  float var = S[608 + h] * inv - m * m;
  float sc = gv[h] * rsqrtf(var + EPS);
  S[624 + h] = sc;
  S[632 + h] = bv[h] - m * sc;
  m = S[600 + h] * inv;
  var = S[616 + h] * inv - m * m;
  sc = gv[8 + h] * rsqrtf(var + EPS);
  S[640 + h] = sc;
  S[648 + h] = bv[8 + h] - m * sc;
}

// ---------------- K7: final bn apply + sum halves + transpose out -----------
__global__ __launch_bounds__(256) void k7_out(
    const float* __restrict__ av, const float* __restrict__ avp,
    const float* __restrict__ S, float* __restrict__ out, int total)
{
  int oi = blockIdx.x * 256 + threadIdx.x;
  if (oi >= total) return;
  int wi = oi & 127;
  int p  = (oi >> 7) & 127;
  int d  = (oi >> 14) & 63;
  int bi = oi >> 20;
  int h = d >> 3, c = d & 7;
  int n = bi * 128 + wi;
  size_t base = (((size_t)n * 8 + h) * 8 + c) * 128 + p;
  out[oi] = av[base] * S[624 + h] + S[632 + h] + avp[base] * S[640 + h] + S[648 + h];
}

// ---------------- launch ----------------------------------------------------
extern "C" void kernel_launch(void* const* d_in, const int* in_sizes, int n_in,
                              void* d_out, int out_size, void* d_ws, size_t ws_size,
                              hipStream_t stream)
{
  const float* x   = (const float*)d_in[0];
  const float* wq  = (const float*)d_in[1];
  const float* g1  = (const float*)d_in[2];
  const float* b1  = (const float*)d_in[3];
  const float* pos = (const float*)d_in[4];
  const float* gqr = (const float*)d_in[5];
  const float* gkr = (const float*)d_in[6];
  const float* gvp = (const float*)d_in[7];
  const float* gv  = (const float*)d_in[8];
  const float* ga  = (const float*)d_in[9];
  const float* ba  = (const float*)d_in[10];
  const float* gv2 = (const float*)d_in[11];
  const float* bv2 = (const float*)d_in[12];

  float* ws  = (float*)d_ws;
  float* y1  = ws;                       // (b,l,o,w)
  float* y2  = ws + 8388608;             // (n,o,l)
  float* av  = ws;                       // reuse y1
  float* avp = ws + 4194304;
  float* S   = ws + 16777216;            // stats
  float* out = (float*)d_out;

  hipMemsetAsync(S, 0, 1024 * sizeof(float), stream);
  k1_gemm<<<512, 256, 0, stream>>>(x, wq, y1, S);
  k2_bn1<<<1, 128, 0, stream>>>(S, g1, b1);
  k_tr<<<512, 256, 0, stream>>>(y1, y2);
  k3_stats<<<4096, 256, 0, stream>>>(y2, pos, S);
  k4_att<<<1, 64, 0, stream>>>(S, ga, ba, gqr, gkr);
  k5_apply<<<8192, 256, 0, stream>>>(y2, pos, S, av, avp, gv, gvp);
  k6_v<<<1, 64, 0, stream>>>(S, gv2, bv2);
  k7_out<<<(out_size + 255) / 256, 256, 0, stream>>>(av, avp, S, out, out_size);
}

// Round 2
// 572.117 us; speedup vs baseline: 1.1936x; 1.1936x over previous
//
#include <hip/hip_runtime.h>

#define EPS 1e-5f

// Problem constants
// B=4, C=64, H=128, W=128, N=B*W=512, OP2=128, HEAD=8, HP=16, qk_dim=4, v_dim=8

// workspace layout (float offsets)
//  y1: (b,l,o,w)  8,388,608 floats   [dead after k_tr; region reused for PT, then av/avp]
//  y2: (n,o,l)    8,388,608 floats at 8,388,608
//  PT : pos window tables, 3584 floats at 0 (written by k0 after k_tr, read by k3)
//  av : (n,h,c,p) 4,194,304 at 0      (k5 writes, after k3 consumed PT)
//  avp: (n,h,c,p) 4,194,304 at 4,194,304
//  S  : stats 1024 floats at 16,777,216
//    [0..127] bn1 sum   [128..255] bn1 sumsq
//    [256..383] sc1     [384..511] sh1
//    [512..535] att sum (g*8+h)  [536..559] att sumsq
//    [560..567] C0  [568..575] C1  [576..583] C2  [584..591] C3
//    [592..607] v sum (av: h, avp: 8+h)  [608..623] v sumsq
//    [624..631] scv [632..639] shv [640..647] scvp [648..655] shvp
//  PT layout (floats): Pq[c*128+p] at 0, Pk at 512, Wq[m*128+p] at 1024, Wk at 2304

__device__ __constant__ int pair_c [10] = {0,0,0,0,1,1,1,2,2,3};
__device__ __constant__ int pair_cp[10] = {0,1,2,3,1,2,3,2,3,3};

// ---------------- K1: qkv GEMM + relu + bn1 partial stats --------------------
__global__ __launch_bounds__(256) void k1_gemm(
    const float* __restrict__ x, const float* __restrict__ wq,
    float* __restrict__ y1, float* __restrict__ S)
{
  __shared__ float xs[64][132];
  const int b = blockIdx.x >> 7, l = blockIdx.x & 127;
  const int tid = threadIdx.x;
  const float* xp = x + (size_t)b * 1048576 + (size_t)l * 128;
  for (int idx = tid; idx < 8192; idx += 256) {
    int c = idx >> 7, wv = idx & 127;
    xs[c][wv] = xp[c * 16384 + wv];
  }
  __syncthreads();
  const int ty = tid >> 4, tx = tid & 15;
  const int o0 = ty * 8, w0 = tx * 4;
  float acc[8][8];
#pragma unroll
  for (int u = 0; u < 8; ++u)
#pragma unroll
    for (int v = 0; v < 8; ++v) acc[u][v] = 0.f;

  for (int c4 = 0; c4 < 64; c4 += 4) {
    float wr[8][4];
#pragma unroll
    for (int u = 0; u < 8; ++u)
      *(float4*)&wr[u][0] = *(const float4*)&wq[(o0 + u) * 64 + c4];
#pragma unroll
    for (int dc = 0; dc < 4; ++dc) {
      float4 xa = *(const float4*)&xs[c4 + dc][w0];
      float4 xb = *(const float4*)&xs[c4 + dc][w0 + 64];
#pragma unroll
      for (int u = 0; u < 8; ++u) {
        float wv = wr[u][dc];
        acc[u][0] += wv * xa.x; acc[u][1] += wv * xa.y;
        acc[u][2] += wv * xa.z; acc[u][3] += wv * xa.w;
        acc[u][4] += wv * xb.x; acc[u][5] += wv * xb.y;
        acc[u][6] += wv * xb.z; acc[u][7] += wv * xb.w;
      }
    }
  }
  float* y1p = y1 + (size_t)(b * 128 + l) * 16384;
#pragma unroll
  for (int u = 0; u < 8; ++u) {
#pragma unroll
    for (int v = 0; v < 8; ++v) acc[u][v] = fmaxf(acc[u][v], 0.f);
    float4 r0 = make_float4(acc[u][0], acc[u][1], acc[u][2], acc[u][3]);
    float4 r1 = make_float4(acc[u][4], acc[u][5], acc[u][6], acc[u][7]);
    *(float4*)&y1p[(o0 + u) * 128 + w0] = r0;
    *(float4*)&y1p[(o0 + u) * 128 + w0 + 64] = r1;
    float s  = acc[u][0] + acc[u][1] + acc[u][2] + acc[u][3]
             + acc[u][4] + acc[u][5] + acc[u][6] + acc[u][7];
    float ss = acc[u][0]*acc[u][0] + acc[u][1]*acc[u][1] + acc[u][2]*acc[u][2]
             + acc[u][3]*acc[u][3] + acc[u][4]*acc[u][4] + acc[u][5]*acc[u][5]
             + acc[u][6]*acc[u][6] + acc[u][7]*acc[u][7];
#pragma unroll
    for (int off = 1; off < 16; off <<= 1) {
      s  += __shfl_xor(s, off);
      ss += __shfl_xor(ss, off);
    }
    if (tx == 0) {
      atomicAdd(&S[o0 + u], s);
      atomicAdd(&S[128 + o0 + u], ss);
    }
  }
}

// ---------------- K2: finalize bn1 -> scale/shift ---------------------------
__global__ void k2_bn1(float* __restrict__ S, const float* __restrict__ g1,
                       const float* __restrict__ b1)
{
  int o = threadIdx.x;
  if (o >= 128) return;
  const float inv = 1.f / 65536.f;
  float m = S[o] * inv;
  float var = S[128 + o] * inv - m * m;
  float sc = g1[o] * rsqrtf(var + EPS);
  S[256 + o] = sc;
  S[384 + o] = b1[o] - m * sc;
}

// ---------------- K_tr: (b,l,o,w) -> (n=b*128+w, o, l) ----------------------
__global__ __launch_bounds__(256) void k_tr(const float* __restrict__ y1,
                                            float* __restrict__ y2)
{
  __shared__ float t[64][129];
  const int b = blockIdx.x >> 7, o = blockIdx.x & 127;
  const int tid = threadIdx.x;
  for (int half = 0; half < 2; ++half) {
    const int l0 = half * 64;
    for (int idx = tid; idx < 8192; idx += 256) {
      int ll = idx >> 7, wv = idx & 127;
      t[ll][wv] = y1[(size_t)b * 2097152 + (size_t)(l0 + ll) * 16384 + o * 128 + wv];
    }
    __syncthreads();
    for (int idx = tid; idx < 8192; idx += 256) {
      int wv = idx >> 6, ll = idx & 63;
      y2[((size_t)(b * 128 + wv) * 128 + o) * 128 + l0 + ll] = t[ll][wv];
    }
    __syncthreads();
  }
}

// ---------------- K0: pos window tables (shared by all n,h) -----------------
// blocks 0..3: Pq (row c),  4..13: Wq (pair m), 14..17: Pk, 18..27: Wk
__global__ __launch_bounds__(128) void k0_pos(const float* __restrict__ pos,
                                              float* __restrict__ PT)
{
  __shared__ float r0[255], r1[255];
  const int blk = blockIdx.x, tid = threadIdx.x;
  int rowA, rowB, out;
  bool prod;
  if (blk < 4)       { rowA = blk;                 rowB = rowA;               out = blk * 128;              prod = false; }
  else if (blk < 14) { int m = blk - 4;  rowA = pair_c[m];     rowB = pair_cp[m];     out = 1024 + m * 128; prod = true; }
  else if (blk < 18) { rowA = 4 + (blk - 14);      rowB = rowA;               out = 512 + (blk - 14) * 128; prod = false; }
  else               { int m = blk - 18; rowA = 4 + pair_c[m]; rowB = 4 + pair_cp[m]; out = 2304 + m * 128; prod = true; }
  for (int u = tid; u < 255; u += 128) {
    r0[u] = pos[rowA * 255 + u];
    r1[u] = pos[rowB * 255 + u];
  }
  __syncthreads();
  float s = 0.f;
  if (prod) {
    for (int d = 0; d < 128; ++d) s += r0[tid + d] * r1[tid + d];
  } else {
    for (int d = 0; d < 128; ++d) s += r0[tid + d];
  }
  PT[out + tid] = s;
}

// ---------------- K3: att stats via Gram/window tables ----------------------
// one wave per (n,h)
__global__ __launch_bounds__(256) void k3_stats(
    const float* __restrict__ y2, float* __restrict__ S,
    const float* __restrict__ PT)
{
  const int unit = blockIdx.x * 4 + (threadIdx.x >> 6);
  const int lane = threadIdx.x & 63;
  const int n = unit >> 3, h = unit & 7;
  const float* yb = y2 + ((size_t)n * 128 + h * 16) * 128;
  float q[4][2], k[4][2];
#pragma unroll
  for (int c = 0; c < 4; ++c) {
    float sc = S[256 + h * 16 + c],     sh = S[384 + h * 16 + c];
    float sck = S[256 + h * 16 + 4 + c], shk = S[384 + h * 16 + 4 + c];
    q[c][0] = yb[c * 128 + lane] * sc + sh;
    q[c][1] = yb[c * 128 + 64 + lane] * sc + sh;
    k[c][0] = yb[(4 + c) * 128 + lane] * sck + shk;
    k[c][1] = yb[(4 + c) * 128 + 64 + lane] * sck + shk;
  }
  float vals[32];
#pragma unroll
  for (int c = 0; c < 4; ++c) {
    vals[c]     = q[c][0] + q[c][1];      // sq
    vals[4 + c] = k[c][0] + k[c][1];      // sk
  }
#pragma unroll
  for (int m = 0; m < 10; ++m) {
    int c = pair_c[m], cp = pair_cp[m];
    vals[8 + m]  = q[c][0] * q[cp][0] + q[c][1] * q[cp][1];   // Gq
    vals[18 + m] = k[c][0] * k[cp][0] + k[c][1] * k[cp][1];   // Gk
  }
  float qr = 0, qrss = 0, kr = 0, krss = 0;
#pragma unroll
  for (int c = 0; c < 4; ++c) {
    qr += q[c][0] * PT[c * 128 + lane]       + q[c][1] * PT[c * 128 + 64 + lane];
    kr += k[c][0] * PT[512 + c * 128 + lane] + k[c][1] * PT[512 + c * 128 + 64 + lane];
  }
#pragma unroll
  for (int m = 0; m < 10; ++m) {
    int c = pair_c[m], cp = pair_cp[m];
    float mult = (c == cp) ? 1.f : 2.f;
    qrss += mult * (q[c][0] * q[cp][0] * PT[1024 + m * 128 + lane]
                  + q[c][1] * q[cp][1] * PT[1024 + m * 128 + 64 + lane]);
    krss += mult * (k[c][0] * k[cp][0] * PT[2304 + m * 128 + lane]
                  + k[c][1] * k[cp][1] * PT[2304 + m * 128 + 64 + lane]);
  }
  vals[28] = qr; vals[29] = qrss; vals[30] = kr; vals[31] = krss;
#pragma unroll
  for (int v = 0; v < 32; ++v) {
    float t = vals[v];
#pragma unroll
    for (int off = 1; off < 64; off <<= 1) t += __shfl_xor(t, off);
    vals[v] = t;
  }
  if (lane == 0) {
    float qk_sum = 0, qk_ss = 0;
#pragma unroll
    for (int c = 0; c < 4; ++c) qk_sum += vals[c] * vals[4 + c];
#pragma unroll
    for (int m = 0; m < 10; ++m) {
      float mult = (pair_c[m] == pair_cp[m]) ? 1.f : 2.f;
      qk_ss += mult * vals[8 + m] * vals[18 + m];
    }
    atomicAdd(&S[512 + h], qk_sum);
    atomicAdd(&S[536 + h], qk_ss);
    atomicAdd(&S[520 + h], vals[28]);
    atomicAdd(&S[544 + h], vals[29]);
    atomicAdd(&S[528 + h], vals[30]);
    atomicAdd(&S[552 + h], vals[31]);
  }
}

// ---------------- K4: finalize att bn -> per-head coefs ---------------------
__global__ void k4_att(float* __restrict__ S, const float* __restrict__ ga,
                       const float* __restrict__ ba,
                       const float* __restrict__ gqr, const float* __restrict__ gkr)
{
  int h = threadIdx.x;
  if (h >= 8) return;
  const float inv = 1.f / 8388608.f;
  float gates[3] = {1.f, gqr[0], gkr[0]};
  float csum = 0.f;
#pragma unroll
  for (int g = 0; g < 3; ++g) {
    float mr = S[512 + g * 8 + h] * inv;
    float er = S[536 + g * 8 + h] * inv;
    float gt = gates[g];
    float mean = gt * mr;
    float var = gt * gt * er - mean * mean;
    float sc = ga[g * 8 + h] * rsqrtf(var + EPS);
    S[560 + g * 8 + h] = gt * sc;
    csum += ba[g * 8 + h] - mean * sc;
  }
  S[584 + h] = csum;
}

// ---------------- K5: scores + softmax + PV + v-bn partial stats ------------
// thread owns p = ph*64 + (tid>>2), i in {(tid&3) + 4j}; scores in registers
__global__ __launch_bounds__(256) void k5_apply(
    const float* __restrict__ y2, const float* __restrict__ pos,
    float* __restrict__ S, float* __restrict__ av, float* __restrict__ avp,
    const float* __restrict__ gv_p, const float* __restrict__ gvp_p)
{
  __shared__ __align__(16) float qkv_t[128][20];    // [l][q0..3 k4..7 v8..15]
  __shared__ __align__(16) float qkpos_t[255][12];  // [u][qpos0..3 kpos4..7]
  __shared__ __align__(16) float vpos_t[255][12];   // [u][vpos0..7]
  __shared__ float red[4][4];
  const int ph = blockIdx.x & 1, h = (blockIdx.x >> 1) & 7;
  const int n = blockIdx.x >> 4;
  const int tid = threadIdx.x;
  const float* yb = y2 + ((size_t)n * 128 + h * 16) * 128;
  for (int idx = tid; idx < 2048; idx += 256) {
    int c = idx >> 7, l = idx & 127;
    qkv_t[l][c] = yb[c * 128 + l] * S[256 + h * 16 + c] + S[384 + h * 16 + c];
  }
#pragma unroll
  for (int r = 0; r < 8; ++r) {
    for (int u = tid; u < 255; u += 256) {
      qkpos_t[u][r] = pos[r * 255 + u];
      vpos_t[u][r]  = pos[(8 + r) * 255 + u];
    }
  }
  __syncthreads();

  const int p = ph * 64 + (tid >> 2);
  const int isub = tid & 3;
  const float4 qv = *(const float4*)&qkv_t[p][0];
  const float4 kv = *(const float4*)&qkv_t[p][4];
  const float C0 = S[560 + h], C1 = S[568 + h], C2 = S[576 + h], C3 = S[584 + h];

  float a[32];
  float m = -1e30f;
#pragma unroll
  for (int j = 0; j < 32; ++j) {
    int i = isub + 4 * j;
    int u = p - i + 127;
    float4 kt = *(const float4*)&qkv_t[i][4];
    float4 qp = *(const float4*)&qkpos_t[u][0];
    float4 kp = *(const float4*)&qkpos_t[u][4];
    float aa = qv.x * kt.x + qv.y * kt.y + qv.z * kt.z + qv.w * kt.w;
    float bq = qv.x * qp.x + qv.y * qp.y + qv.z * qp.z + qv.w * qp.w;
    float ck = kv.x * kp.x + kv.y * kp.y + kv.z * kp.z + kv.w * kp.w;
    float s = aa * C0 + bq * C1 + ck * C2 + C3;
    a[j] = s;
    m = fmaxf(m, s);
  }
  m = fmaxf(m, __shfl_xor(m, 1));
  m = fmaxf(m, __shfl_xor(m, 2));
  float sum = 0.f;
#pragma unroll
  for (int j = 0; j < 32; ++j) {
    a[j] = __expf(a[j] - m);
    sum += a[j];
  }
  sum += __shfl_xor(sum, 1);
  sum += __shfl_xor(sum, 2);
  const float inv = 1.0f / sum;

  float accv[8], accvp[8];
#pragma unroll
  for (int c = 0; c < 8; ++c) { accv[c] = 0.f; accvp[c] = 0.f; }
#pragma unroll
  for (int j = 0; j < 32; ++j) {
    int i = isub + 4 * j;
    int u = p - i + 127;
    float aj = a[j] * inv;
    float4 v0 = *(const float4*)&qkv_t[i][8];
    float4 v1 = *(const float4*)&qkv_t[i][12];
    float4 w0 = *(const float4*)&vpos_t[u][0];
    float4 w1 = *(const float4*)&vpos_t[u][4];
    accv[0] += aj * v0.x; accv[1] += aj * v0.y; accv[2] += aj * v0.z; accv[3] += aj * v0.w;
    accv[4] += aj * v1.x; accv[5] += aj * v1.y; accv[6] += aj * v1.z; accv[7] += aj * v1.w;
    accvp[0] += aj * w0.x; accvp[1] += aj * w0.y; accvp[2] += aj * w0.z; accvp[3] += aj * w0.w;
    accvp[4] += aj * w1.x; accvp[5] += aj * w1.y; accvp[6] += aj * w1.z; accvp[7] += aj * w1.w;
  }
#pragma unroll
  for (int c = 0; c < 8; ++c) {
    accv[c]  += __shfl_xor(accv[c], 1);  accv[c]  += __shfl_xor(accv[c], 2);
    accvp[c] += __shfl_xor(accvp[c], 1); accvp[c] += __shfl_xor(accvp[c], 2);
  }
  const float gv = gv_p[0], gvp = gvp_p[0];
  float sv = 0, ssv = 0, svp = 0, ssvp = 0;
  if (isub == 0) {
    size_t base = (((size_t)n * 8 + h) * 8) * 128 + p;
#pragma unroll
    for (int c = 0; c < 8; ++c) {
      float x1 = accv[c] * gv, x2 = accvp[c] * gvp;
      av [base + c * 128] = x1;
      avp[base + c * 128] = x2;
      sv += x1; ssv += x1 * x1; svp += x2; ssvp += x2 * x2;
    }
  }
  float vals[4] = {sv, ssv, svp, ssvp};
#pragma unroll
  for (int kk = 0; kk < 4; ++kk) {
    float v = vals[kk];
#pragma unroll
    for (int off = 1; off < 64; off <<= 1) v += __shfl_xor(v, off);
    vals[kk] = v;
  }
  const int wid = tid >> 6, lane = tid & 63;
  if (lane == 0) {
#pragma unroll
    for (int kk = 0; kk < 4; ++kk) red[wid][kk] = vals[kk];
  }
  __syncthreads();
  if (tid == 0) {
    float t0 = red[0][0] + red[1][0] + red[2][0] + red[3][0];
    float t1 = red[0][1] + red[1][1] + red[2][1] + red[3][1];
    float t2 = red[0][2] + red[1][2] + red[2][2] + red[3][2];
    float t3 = red[0][3] + red[1][3] + red[2][3] + red[3][3];
    atomicAdd(&S[592 + h], t0);
    atomicAdd(&S[608 + h], t1);
    atomicAdd(&S[600 + h], t2);
    atomicAdd(&S[616 + h], t3);
  }
}

// ---------------- K6: finalize v bn ----------------------------------------
__global__ void k6_v(float* __restrict__ S, const float* __restrict__ gv,
                     const float* __restrict__ bv)
{
  int h = threadIdx.x;
  if (h >= 8) return;
  const float inv = 1.f / 524288.f;
  float m = S[592 + h] * inv;
  float var = S[608 + h] * inv - m * m;
  float sc = gv[h] * rsqrtf(var + EPS);
  S[624 + h] = sc;
  S[632 + h] = bv[h] - m * sc;
  m = S[600 + h] * inv;
  var = S[616 + h] * inv - m * m;
  sc = gv[8 + h] * rsqrtf(var + EPS);
  S[640 + h] = sc;
  S[648 + h] = bv[8 + h] - m * sc;
}

// ---------------- K7: final bn apply + sum halves + transpose out -----------
__global__ __launch_bounds__(256) void k7_out(
    const float* __restrict__ av, const float* __restrict__ avp,
    const float* __restrict__ S, float* __restrict__ out, int total)
{
  int oi = blockIdx.x * 256 + threadIdx.x;
  if (oi >= total) return;
  int wi = oi & 127;
  int p  = (oi >> 7) & 127;
  int d  = (oi >> 14) & 63;
  int bi = oi >> 20;
  int h = d >> 3, c = d & 7;
  int n = bi * 128 + wi;
  size_t base = (((size_t)n * 8 + h) * 8 + c) * 128 + p;
  out[oi] = av[base] * S[624 + h] + S[632 + h] + avp[base] * S[640 + h] + S[648 + h];
}

// ---------------- launch ----------------------------------------------------
extern "C" void kernel_launch(void* const* d_in, const int* in_sizes, int n_in,
                              void* d_out, int out_size, void* d_ws, size_t ws_size,
                              hipStream_t stream)
{
  const float* x   = (const float*)d_in[0];
  const float* wq  = (const float*)d_in[1];
  const float* g1  = (const float*)d_in[2];
  const float* b1  = (const float*)d_in[3];
  const float* pos = (const float*)d_in[4];
  const float* gqr = (const float*)d_in[5];
  const float* gkr = (const float*)d_in[6];
  const float* gvp = (const float*)d_in[7];
  const float* gv  = (const float*)d_in[8];
  const float* ga  = (const float*)d_in[9];
  const float* ba  = (const float*)d_in[10];
  const float* gv2 = (const float*)d_in[11];
  const float* bv2 = (const float*)d_in[12];

  float* ws  = (float*)d_ws;
  float* y1  = ws;                       // (b,l,o,w)
  float* y2  = ws + 8388608;             // (n,o,l)
  float* PT  = ws;                       // pos tables (after k_tr frees y1)
  float* av  = ws;                       // reuse y1 (after k3 consumed PT)
  float* avp = ws + 4194304;
  float* S   = ws + 16777216;            // stats
  float* out = (float*)d_out;

  hipMemsetAsync(S, 0, 1024 * sizeof(float), stream);
  k1_gemm<<<512, 256, 0, stream>>>(x, wq, y1, S);
  k2_bn1<<<1, 128, 0, stream>>>(S, g1, b1);
  k_tr<<<512, 256, 0, stream>>>(y1, y2);
  k0_pos<<<28, 128, 0, stream>>>(pos, PT);
  k3_stats<<<1024, 256, 0, stream>>>(y2, S, PT);
  k4_att<<<1, 64, 0, stream>>>(S, ga, ba, gqr, gkr);
  k5_apply<<<8192, 256, 0, stream>>>(y2, pos, S, av, avp, gv, gvp);
  k6_v<<<1, 64, 0, stream>>>(S, gv2, bv2);
  k7_out<<<(out_size + 255) / 256, 256, 0, stream>>>(av, avp, S, out, out_size);
}

// Round 3
// 483.000 us; speedup vs baseline: 1.4138x; 1.1845x over previous
//
#include <hip/hip_runtime.h>
#include <hip/hip_fp16.h>

#define EPS 1e-5f

// Problem constants: B=4, C=64, H=128, W=128, N=512, OP2=128, HEAD=8, HP=16
// qk_dim=4, v_dim=8

// workspace layout (float offsets)
//  y1: (b,l,o,w)  8,388,608 floats at 0   [dead after k_tr]
//  Pbuf: k1 partial stats 512*256 floats at 8,388,608 (y2 region, pre-k_tr)
//  y2: (n,o,l)    8,388,608 floats at 8,388,608 (k_tr clobbers Pbuf after k2)
//  PT : pos window tables, 3584 floats at 0 (after k_tr frees y1)
//  av : (n,h,c,p) half, 4,194,304 halves at float-offset 0      (after k3)
//  avp: (n,h,c,p) half, 4,194,304 halves at float-offset 2,097,152
//  S  : stats 1024 floats at 16,777,216
//    [256..383] sc1  [384..511] sh1
//    [512..535] att sum (g*8+h)  [536..559] att sumsq
//    [560..567] C0  [568..575] C1  [576..583] C2  [584..591] C3
//    [592..607] v sum  [608..623] v sumsq
//    [624..631] scv [632..639] shv [640..647] scvp [648..655] shvp
//  PT: Pq[c*128+p] at 0, Pk at 512, Wq[m*128+p] at 1024, Wk at 2304

typedef _Float16 half2_t __attribute__((ext_vector_type(2)));

__device__ __constant__ int pair_c [10] = {0,0,0,0,1,1,1,2,2,3};
__device__ __constant__ int pair_cp[10] = {0,1,2,3,1,2,3,2,3,3};

__device__ inline float fdot2(half2_t a, half2_t b, float c) {
#if __has_builtin(__builtin_amdgcn_fdot2)
  return __builtin_amdgcn_fdot2(a, b, c, false);
#else
  return c + (float)a[0] * (float)b[0] + (float)a[1] * (float)b[1];
#endif
}
__device__ inline half2_t bch2(unsigned u) {
  union { unsigned u; half2_t h; } x; x.u = u; return x.h;
}
__device__ inline unsigned packf2(float a, float b) {
  half2_t h; h[0] = (_Float16)a; h[1] = (_Float16)b;
  union { unsigned u; half2_t h; } x; x.h = h; return x.u;
}

// ---------------- K1: qkv GEMM + relu + bn1 partials (no atomics) -----------
__global__ __launch_bounds__(256) void k1_gemm(
    const float* __restrict__ x, const float* __restrict__ wq,
    float* __restrict__ y1, float* __restrict__ Pbuf)
{
  __shared__ float xs[64][132];
  const int b = blockIdx.x >> 7, l = blockIdx.x & 127;
  const int tid = threadIdx.x;
  const float* xp = x + (size_t)b * 1048576 + (size_t)l * 128;
  for (int idx = tid; idx < 8192; idx += 256) {
    int c = idx >> 7, wv = idx & 127;
    xs[c][wv] = xp[c * 16384 + wv];
  }
  __syncthreads();
  const int ty = tid >> 4, tx = tid & 15;
  const int o0 = ty * 8, w0 = tx * 4;
  float acc[8][8];
#pragma unroll
  for (int u = 0; u < 8; ++u)
#pragma unroll
    for (int v = 0; v < 8; ++v) acc[u][v] = 0.f;

  for (int c4 = 0; c4 < 64; c4 += 4) {
    float wr[8][4];
#pragma unroll
    for (int u = 0; u < 8; ++u)
      *(float4*)&wr[u][0] = *(const float4*)&wq[(o0 + u) * 64 + c4];
#pragma unroll
    for (int dc = 0; dc < 4; ++dc) {
      float4 xa = *(const float4*)&xs[c4 + dc][w0];
      float4 xb = *(const float4*)&xs[c4 + dc][w0 + 64];
#pragma unroll
      for (int u = 0; u < 8; ++u) {
        float wv = wr[u][dc];
        acc[u][0] += wv * xa.x; acc[u][1] += wv * xa.y;
        acc[u][2] += wv * xa.z; acc[u][3] += wv * xa.w;
        acc[u][4] += wv * xb.x; acc[u][5] += wv * xb.y;
        acc[u][6] += wv * xb.z; acc[u][7] += wv * xb.w;
      }
    }
  }
  float* y1p = y1 + (size_t)(b * 128 + l) * 16384;
#pragma unroll
  for (int u = 0; u < 8; ++u) {
#pragma unroll
    for (int v = 0; v < 8; ++v) acc[u][v] = fmaxf(acc[u][v], 0.f);
    float4 r0 = make_float4(acc[u][0], acc[u][1], acc[u][2], acc[u][3]);
    float4 r1 = make_float4(acc[u][4], acc[u][5], acc[u][6], acc[u][7]);
    *(float4*)&y1p[(o0 + u) * 128 + w0] = r0;
    *(float4*)&y1p[(o0 + u) * 128 + w0 + 64] = r1;
    float s  = acc[u][0] + acc[u][1] + acc[u][2] + acc[u][3]
             + acc[u][4] + acc[u][5] + acc[u][6] + acc[u][7];
    float ss = acc[u][0]*acc[u][0] + acc[u][1]*acc[u][1] + acc[u][2]*acc[u][2]
             + acc[u][3]*acc[u][3] + acc[u][4]*acc[u][4] + acc[u][5]*acc[u][5]
             + acc[u][6]*acc[u][6] + acc[u][7]*acc[u][7];
#pragma unroll
    for (int off = 1; off < 16; off <<= 1) {
      s  += __shfl_xor(s, off);
      ss += __shfl_xor(ss, off);
    }
    if (tx == 0) {
      Pbuf[blockIdx.x * 256 + o0 + u] = s;
      Pbuf[blockIdx.x * 256 + 128 + o0 + u] = ss;
    }
  }
}

// ---------------- K2: reduce partials -> bn1 scale/shift --------------------
__global__ __launch_bounds__(256) void k2_bn1(
    const float* __restrict__ Pbuf, float* __restrict__ S,
    const float* __restrict__ g1, const float* __restrict__ b1)
{
  __shared__ float red[256];
  const int t = threadIdx.x;
  float acc = 0.f;
  for (int blk = 0; blk < 512; ++blk) acc += Pbuf[blk * 256 + t];
  red[t] = acc;
  __syncthreads();
  if (t < 128) {
    const float inv = 1.f / 65536.f;
    float m = red[t] * inv;
    float var = red[128 + t] * inv - m * m;
    float sc = g1[t] * rsqrtf(var + EPS);
    S[256 + t] = sc;
    S[384 + t] = b1[t] - m * sc;
  }
}

// ---------------- K_tr: (b,l,o,w) -> (n=b*128+w, o, l) ----------------------
__global__ __launch_bounds__(256) void k_tr(const float* __restrict__ y1,
                                            float* __restrict__ y2)
{
  __shared__ float t[64][129];
  const int b = blockIdx.x >> 7, o = blockIdx.x & 127;
  const int tid = threadIdx.x;
  for (int half = 0; half < 2; ++half) {
    const int l0 = half * 64;
    for (int idx = tid; idx < 8192; idx += 256) {
      int ll = idx >> 7, wv = idx & 127;
      t[ll][wv] = y1[(size_t)b * 2097152 + (size_t)(l0 + ll) * 16384 + o * 128 + wv];
    }
    __syncthreads();
    for (int idx = tid; idx < 8192; idx += 256) {
      int wv = idx >> 6, ll = idx & 63;
      y2[((size_t)(b * 128 + wv) * 128 + o) * 128 + l0 + ll] = t[ll][wv];
    }
    __syncthreads();
  }
}

// ---------------- K0: pos window tables -------------------------------------
__global__ __launch_bounds__(128) void k0_pos(const float* __restrict__ pos,
                                              float* __restrict__ PT)
{
  __shared__ float r0[255], r1[255];
  const int blk = blockIdx.x, tid = threadIdx.x;
  int rowA, rowB, out;
  bool prod;
  if (blk < 4)       { rowA = blk;                 rowB = rowA;               out = blk * 128;              prod = false; }
  else if (blk < 14) { int m = blk - 4;  rowA = pair_c[m];     rowB = pair_cp[m];     out = 1024 + m * 128; prod = true; }
  else if (blk < 18) { rowA = 4 + (blk - 14);      rowB = rowA;               out = 512 + (blk - 14) * 128; prod = false; }
  else               { int m = blk - 18; rowA = 4 + pair_c[m]; rowB = 4 + pair_cp[m]; out = 2304 + m * 128; prod = true; }
  for (int u = tid; u < 255; u += 128) {
    r0[u] = pos[rowA * 255 + u];
    r1[u] = pos[rowB * 255 + u];
  }
  __syncthreads();
  float s = 0.f;
  if (prod) {
    for (int d = 0; d < 128; ++d) s += r0[tid + d] * r1[tid + d];
  } else {
    for (int d = 0; d < 128; ++d) s += r0[tid + d];
  }
  PT[out + tid] = s;
}

// ---------------- K3: att stats via Gram/window tables ----------------------
__global__ __launch_bounds__(256) void k3_stats(
    const float* __restrict__ y2, float* __restrict__ S,
    const float* __restrict__ PT)
{
  const int unit = blockIdx.x * 4 + (threadIdx.x >> 6);
  const int lane = threadIdx.x & 63;
  const int n = unit >> 3, h = unit & 7;
  const float* yb = y2 + ((size_t)n * 128 + h * 16) * 128;
  float q[4][2], k[4][2];
#pragma unroll
  for (int c = 0; c < 4; ++c) {
    float sc = S[256 + h * 16 + c],      sh = S[384 + h * 16 + c];
    float sck = S[256 + h * 16 + 4 + c], shk = S[384 + h * 16 + 4 + c];
    q[c][0] = yb[c * 128 + lane] * sc + sh;
    q[c][1] = yb[c * 128 + 64 + lane] * sc + sh;
    k[c][0] = yb[(4 + c) * 128 + lane] * sck + shk;
    k[c][1] = yb[(4 + c) * 128 + 64 + lane] * sck + shk;
  }
  float vals[32];
#pragma unroll
  for (int c = 0; c < 4; ++c) {
    vals[c]     = q[c][0] + q[c][1];
    vals[4 + c] = k[c][0] + k[c][1];
  }
#pragma unroll
  for (int m = 0; m < 10; ++m) {
    int c = pair_c[m], cp = pair_cp[m];
    vals[8 + m]  = q[c][0] * q[cp][0] + q[c][1] * q[cp][1];
    vals[18 + m] = k[c][0] * k[cp][0] + k[c][1] * k[cp][1];
  }
  float qr = 0, qrss = 0, kr = 0, krss = 0;
#pragma unroll
  for (int c = 0; c < 4; ++c) {
    qr += q[c][0] * PT[c * 128 + lane]       + q[c][1] * PT[c * 128 + 64 + lane];
    kr += k[c][0] * PT[512 + c * 128 + lane] + k[c][1] * PT[512 + c * 128 + 64 + lane];
  }
#pragma unroll
  for (int m = 0; m < 10; ++m) {
    int c = pair_c[m], cp = pair_cp[m];
    float mult = (c == cp) ? 1.f : 2.f;
    qrss += mult * (q[c][0] * q[cp][0] * PT[1024 + m * 128 + lane]
                  + q[c][1] * q[cp][1] * PT[1024 + m * 128 + 64 + lane]);
    krss += mult * (k[c][0] * k[cp][0] * PT[2304 + m * 128 + lane]
                  + k[c][1] * k[cp][1] * PT[2304 + m * 128 + 64 + lane]);
  }
  vals[28] = qr; vals[29] = qrss; vals[30] = kr; vals[31] = krss;
#pragma unroll
  for (int v = 0; v < 32; ++v) {
    float t = vals[v];
#pragma unroll
    for (int off = 1; off < 64; off <<= 1) t += __shfl_xor(t, off);
    vals[v] = t;
  }
  if (lane == 0) {
    float qk_sum = 0, qk_ss = 0;
#pragma unroll
    for (int c = 0; c < 4; ++c) qk_sum += vals[c] * vals[4 + c];
#pragma unroll
    for (int m = 0; m < 10; ++m) {
      float mult = (pair_c[m] == pair_cp[m]) ? 1.f : 2.f;
      qk_ss += mult * vals[8 + m] * vals[18 + m];
    }
    atomicAdd(&S[512 + h], qk_sum);
    atomicAdd(&S[536 + h], qk_ss);
    atomicAdd(&S[520 + h], vals[28]);
    atomicAdd(&S[544 + h], vals[29]);
    atomicAdd(&S[528 + h], vals[30]);
    atomicAdd(&S[552 + h], vals[31]);
  }
}

// ---------------- K4: finalize att bn -> per-head coefs ---------------------
__global__ void k4_att(float* __restrict__ S, const float* __restrict__ ga,
                       const float* __restrict__ ba,
                       const float* __restrict__ gqr, const float* __restrict__ gkr)
{
  int h = threadIdx.x;
  if (h >= 8) return;
  const float inv = 1.f / 8388608.f;
  float gates[3] = {1.f, gqr[0], gkr[0]};
  float csum = 0.f;
#pragma unroll
  for (int g = 0; g < 3; ++g) {
    float mr = S[512 + g * 8 + h] * inv;
    float er = S[536 + g * 8 + h] * inv;
    float gt = gates[g];
    float mean = gt * mr;
    float var = gt * gt * er - mean * mean;
    float sc = ga[g * 8 + h] * rsqrtf(var + EPS);
    S[560 + g * 8 + h] = gt * sc;
    csum += ba[g * 8 + h] - mean * sc;
  }
  S[584 + h] = csum;
}

// ---------------- K5: fp16-packed scores + softmax + PV ---------------------
// thread owns p = ph*64 + (tid>>2), i in {(tid&3)+4j}; scores in registers
__global__ __launch_bounds__(256) void k5_apply(
    const float* __restrict__ y2, const float* __restrict__ pos,
    float* __restrict__ S, _Float16* __restrict__ av, _Float16* __restrict__ avp,
    const float* __restrict__ gv_p, const float* __restrict__ gvp_p)
{
  // per-l slots: 0:q01 1:q23 2:k01 3:k23 4:v01 5:v23 6:v45 7:v67 (half2 as uint)
  __shared__ __align__(16) unsigned qkv_h[128][12];
  // per-u slots: 0:qp01 1:qp23 2:kp01 3:kp23 4:vp01 5:vp23 6:vp45 7:vp67
  __shared__ __align__(16) unsigned posm[255][12];
  __shared__ float red[4][4];
  const int ph = blockIdx.x & 1, h = (blockIdx.x >> 1) & 7;
  const int n = blockIdx.x >> 4;
  const int tid = threadIdx.x;
  const float* yb = y2 + ((size_t)n * 128 + h * 16) * 128;
  for (int idx = tid; idx < 1024; idx += 256) {
    int s = idx >> 7, l = idx & 127;
    int c0 = 2 * s, c1 = 2 * s + 1;
    float f0 = yb[c0 * 128 + l] * S[256 + h * 16 + c0] + S[384 + h * 16 + c0];
    float f1 = yb[c1 * 128 + l] * S[256 + h * 16 + c1] + S[384 + h * 16 + c1];
    qkv_h[l][s] = packf2(f0, f1);
  }
  for (int idx = tid; idx < 2048; idx += 256) {
    int s = idx >> 8, u = idx & 255;
    if (u < 255)
      posm[u][s] = packf2(pos[(2 * s) * 255 + u], pos[(2 * s + 1) * 255 + u]);
  }
  __syncthreads();

  const int p = ph * 64 + (tid >> 2);
  const int isub = tid & 3;
  uint4 qk4 = *(const uint4*)&qkv_h[p][0];
  const half2_t q01 = bch2(qk4.x), q23 = bch2(qk4.y);
  const half2_t k01 = bch2(qk4.z), k23 = bch2(qk4.w);
  const float C0 = S[560 + h], C1 = S[568 + h], C2 = S[576 + h], C3 = S[584 + h];

  float a[32];
  float m = -1e30f;
#pragma unroll
  for (int j = 0; j < 32; ++j) {
    int i = isub + 4 * j;
    int u = p - i + 127;
    uint2 kt  = *(const uint2*)&qkv_h[i][2];
    uint4 qkp = *(const uint4*)&posm[u][0];
    float aa = fdot2(q23, bch2(kt.y),  fdot2(q01, bch2(kt.x),  0.f));
    float bq = fdot2(q23, bch2(qkp.y), fdot2(q01, bch2(qkp.x), 0.f));
    float ck = fdot2(k23, bch2(qkp.w), fdot2(k01, bch2(qkp.z), 0.f));
    float s = aa * C0 + bq * C1 + ck * C2 + C3;
    a[j] = s;
    m = fmaxf(m, s);
  }
  m = fmaxf(m, __shfl_xor(m, 1));
  m = fmaxf(m, __shfl_xor(m, 2));
  float sum = 0.f;
#pragma unroll
  for (int j = 0; j < 32; ++j) {
    a[j] = __expf(a[j] - m);
    sum += a[j];
  }
  sum += __shfl_xor(sum, 1);
  sum += __shfl_xor(sum, 2);
  const float inv = 1.0f / sum;

  float accv[8], accvp[8];
#pragma unroll
  for (int c = 0; c < 8; ++c) { accv[c] = 0.f; accvp[c] = 0.f; }
#pragma unroll
  for (int j = 0; j < 32; ++j) {
    int i = isub + 4 * j;
    int u = p - i + 127;
    float aj = a[j] * inv;
    uint4 vv = *(const uint4*)&qkv_h[i][4];
    uint4 vp = *(const uint4*)&posm[u][4];
    half2_t v0 = bch2(vv.x), v1 = bch2(vv.y), v2 = bch2(vv.z), v3 = bch2(vv.w);
    half2_t w0 = bch2(vp.x), w1 = bch2(vp.y), w2 = bch2(vp.z), w3 = bch2(vp.w);
    accv[0] += aj * (float)v0[0]; accv[1] += aj * (float)v0[1];
    accv[2] += aj * (float)v1[0]; accv[3] += aj * (float)v1[1];
    accv[4] += aj * (float)v2[0]; accv[5] += aj * (float)v2[1];
    accv[6] += aj * (float)v3[0]; accv[7] += aj * (float)v3[1];
    accvp[0] += aj * (float)w0[0]; accvp[1] += aj * (float)w0[1];
    accvp[2] += aj * (float)w1[0]; accvp[3] += aj * (float)w1[1];
    accvp[4] += aj * (float)w2[0]; accvp[5] += aj * (float)w2[1];
    accvp[6] += aj * (float)w3[0]; accvp[7] += aj * (float)w3[1];
  }
#pragma unroll
  for (int c = 0; c < 8; ++c) {
    accv[c]  += __shfl_xor(accv[c], 1);  accv[c]  += __shfl_xor(accv[c], 2);
    accvp[c] += __shfl_xor(accvp[c], 1); accvp[c] += __shfl_xor(accvp[c], 2);
  }
  const float gv = gv_p[0], gvp = gvp_p[0];
  float sv = 0, ssv = 0, svp = 0, ssvp = 0;
  if (isub == 0) {
    size_t base = (((size_t)n * 8 + h) * 8) * 128 + p;
#pragma unroll
    for (int c = 0; c < 8; ++c) {
      float x1 = accv[c] * gv, x2 = accvp[c] * gvp;
      av [base + c * 128] = (_Float16)x1;
      avp[base + c * 128] = (_Float16)x2;
      sv += x1; ssv += x1 * x1; svp += x2; ssvp += x2 * x2;
    }
  }
  float vals[4] = {sv, ssv, svp, ssvp};
#pragma unroll
  for (int kk = 0; kk < 4; ++kk) {
    float v = vals[kk];
#pragma unroll
    for (int off = 1; off < 64; off <<= 1) v += __shfl_xor(v, off);
    vals[kk] = v;
  }
  const int wid = tid >> 6, lane = tid & 63;
  if (lane == 0) {
#pragma unroll
    for (int kk = 0; kk < 4; ++kk) red[wid][kk] = vals[kk];
  }
  __syncthreads();
  if (tid == 0) {
    float t0 = red[0][0] + red[1][0] + red[2][0] + red[3][0];
    float t1 = red[0][1] + red[1][1] + red[2][1] + red[3][1];
    float t2 = red[0][2] + red[1][2] + red[2][2] + red[3][2];
    float t3 = red[0][3] + red[1][3] + red[2][3] + red[3][3];
    atomicAdd(&S[592 + h], t0);
    atomicAdd(&S[608 + h], t1);
    atomicAdd(&S[600 + h], t2);
    atomicAdd(&S[616 + h], t3);
  }
}

// ---------------- K6: finalize v bn ----------------------------------------
__global__ void k6_v(float* __restrict__ S, const float* __restrict__ gv,
                     const float* __restrict__ bv)
{
  int h = threadIdx.x;
  if (h >= 8) return;
  const float inv = 1.f / 524288.f;
  float m = S[592 + h] * inv;
  float var = S[608 + h] * inv - m * m;
  float sc = gv[h] * rsqrtf(var + EPS);
  S[624 + h] = sc;
  S[632 + h] = bv[h] - m * sc;
  m = S[600 + h] * inv;
  var = S[616 + h] * inv - m * m;
  sc = gv[8 + h] * rsqrtf(var + EPS);
  S[640 + h] = sc;
  S[648 + h] = bv[8 + h] - m * sc;
}

// ---------------- K7: bn apply + sum halves + LDS-tiled transpose out -------
// block = (b, d=h*8+c, w-half); tile[w][p]; coalesced reads and writes
__global__ __launch_bounds__(256) void k7_out(
    const _Float16* __restrict__ av, const _Float16* __restrict__ avp,
    const float* __restrict__ S, float* __restrict__ out)
{
  __shared__ float tile[64][129];
  const int wt = blockIdx.x & 1;
  const int d  = (blockIdx.x >> 1) & 63;
  const int b  = blockIdx.x >> 7;
  const int h = d >> 3, c = d & 7;
  const float scv = S[624 + h], shv = S[632 + h];
  const float scp = S[640 + h], shp = S[648 + h];
  const int tid = threadIdx.x;
  for (int idx = tid; idx < 8192; idx += 256) {
    int wl = idx >> 7, p = idx & 127;
    int n = b * 128 + wt * 64 + wl;
    size_t base = (((size_t)n * 8 + h) * 8 + c) * 128 + p;
    tile[wl][p] = (float)av[base] * scv + shv + (float)avp[base] * scp + shp;
  }
  __syncthreads();
  for (int idx = tid; idx < 8192; idx += 256) {
    int p = idx >> 6, wl = idx & 63;
    out[(((size_t)b * 64 + d) * 128 + p) * 128 + wt * 64 + wl] = tile[wl][p];
  }
}

// ---------------- launch ----------------------------------------------------
extern "C" void kernel_launch(void* const* d_in, const int* in_sizes, int n_in,
                              void* d_out, int out_size, void* d_ws, size_t ws_size,
                              hipStream_t stream)
{
  const float* x   = (const float*)d_in[0];
  const float* wq  = (const float*)d_in[1];
  const float* g1  = (const float*)d_in[2];
  const float* b1  = (const float*)d_in[3];
  const float* pos = (const float*)d_in[4];
  const float* gqr = (const float*)d_in[5];
  const float* gkr = (const float*)d_in[6];
  const float* gvp = (const float*)d_in[7];
  const float* gv  = (const float*)d_in[8];
  const float* ga  = (const float*)d_in[9];
  const float* ba  = (const float*)d_in[10];
  const float* gv2 = (const float*)d_in[11];
  const float* bv2 = (const float*)d_in[12];

  float* ws   = (float*)d_ws;
  float* y1   = ws;                       // (b,l,o,w)
  float* Pbuf = ws + 8388608;             // k1 partials (y2 region, pre-k_tr)
  float* y2   = ws + 8388608;             // (n,o,l)
  float* PT   = ws;                       // pos tables (after k_tr frees y1)
  _Float16* av  = (_Float16*)ws;                   // after k3 consumed PT
  _Float16* avp = (_Float16*)ws + 4194304;         // = float offset 2,097,152
  float* S    = ws + 16777216;            // stats
  float* out  = (float*)d_out;

  hipMemsetAsync(S, 0, 1024 * sizeof(float), stream);
  k1_gemm<<<512, 256, 0, stream>>>(x, wq, y1, Pbuf);
  k2_bn1<<<1, 256, 0, stream>>>(Pbuf, S, g1, b1);
  k_tr<<<512, 256, 0, stream>>>(y1, y2);
  k0_pos<<<28, 128, 0, stream>>>(pos, PT);
  k3_stats<<<1024, 256, 0, stream>>>(y2, S, PT);
  k4_att<<<1, 64, 0, stream>>>(S, ga, ba, gqr, gkr);
  k5_apply<<<8192, 256, 0, stream>>>(y2, pos, S, av, avp, gv, gvp);
  k6_v<<<1, 64, 0, stream>>>(S, gv2, bv2);
  k7_out<<<512, 256, 0, stream>>>(av, avp, S, out);
}

// Round 6
// 355.630 us; speedup vs baseline: 1.9201x; 1.3582x over previous
//
#include <hip/hip_runtime.h>
#include <hip/hip_fp16.h>

#define EPS 1e-5f

// Problem constants: B=4, C=64, H=128, W=128, N=512, OP2=128, HEAD=8, HP=16
// qk_dim=4, v_dim=8

// workspace layout (float offsets)
//  y1 : (b,l,o,w) f32, 8,388,608 at 0            [dead after k_tr]
//  av : (n,h,c,p) half, 4,194,304 halves at 0    (k5 writes; y1 region)
//  avp: (n,h,c,p) half at float-offset 2,097,152
//  Pbuf: k1 partials 512*256 f32 at 8,388,608    [dead after k2]
//  y2h: (n,h,slot,l) packed half2 per uint, 1,048,576 uints at 8,388,608
//       slot: 0 q01 1 q23 2 k01 3 k23 4 v01 5 v23 6 v45 7 v67 (BN applied)
//  S  : stats 1024 f32 at 16,777,216
//  pos_h: packed pos image [u=0..254][12 uints] at 16,778,240
//  PT : f32 window tables at 16,781,312

typedef _Float16 half2_t __attribute__((ext_vector_type(2)));

__device__ __constant__ int pair_c [10] = {0,0,0,0,1,1,1,2,2,3};
__device__ __constant__ int pair_cp[10] = {0,1,2,3,1,2,3,2,3,3};

__device__ inline float fdot2(half2_t a, half2_t b, float c) {
#if __has_builtin(__builtin_amdgcn_fdot2)
  return __builtin_amdgcn_fdot2(a, b, c, false);
#else
  return c + (float)a[0] * (float)b[0] + (float)a[1] * (float)b[1];
#endif
}
__device__ inline half2_t bch2(unsigned u) {
  union { unsigned u; half2_t h; } x; x.u = u; return x.h;
}
__device__ inline unsigned packf2(float a, float b) {
  half2_t h; h[0] = (_Float16)a; h[1] = (_Float16)b;
  union { unsigned u; half2_t h; } x; x.h = h; return x.u;
}

// ---------------- K1: qkv GEMM + relu + bn1 partials (no atomics) -----------
__global__ __launch_bounds__(256) void k1_gemm(
    const float* __restrict__ x, const float* __restrict__ wq,
    float* __restrict__ y1, float* __restrict__ Pbuf)
{
  __shared__ float xs[64][132];
  const int b = blockIdx.x >> 7, l = blockIdx.x & 127;
  const int tid = threadIdx.x;
  const float* xp = x + (size_t)b * 1048576 + (size_t)l * 128;
  for (int idx = tid; idx < 8192; idx += 256) {
    int c = idx >> 7, wv = idx & 127;
    xs[c][wv] = xp[c * 16384 + wv];
  }
  __syncthreads();
  const int ty = tid >> 4, tx = tid & 15;
  const int o0 = ty * 8, w0 = tx * 4;
  float acc[8][8];
#pragma unroll
  for (int u = 0; u < 8; ++u)
#pragma unroll
    for (int v = 0; v < 8; ++v) acc[u][v] = 0.f;

  for (int c4 = 0; c4 < 64; c4 += 4) {
    float wr[8][4];
#pragma unroll
    for (int u = 0; u < 8; ++u)
      *(float4*)&wr[u][0] = *(const float4*)&wq[(o0 + u) * 64 + c4];
#pragma unroll
    for (int dc = 0; dc < 4; ++dc) {
      float4 xa = *(const float4*)&xs[c4 + dc][w0];
      float4 xb = *(const float4*)&xs[c4 + dc][w0 + 64];
#pragma unroll
      for (int u = 0; u < 8; ++u) {
        float wv = wr[u][dc];
        acc[u][0] += wv * xa.x; acc[u][1] += wv * xa.y;
        acc[u][2] += wv * xa.z; acc[u][3] += wv * xa.w;
        acc[u][4] += wv * xb.x; acc[u][5] += wv * xb.y;
        acc[u][6] += wv * xb.z; acc[u][7] += wv * xb.w;
      }
    }
  }
  float* y1p = y1 + (size_t)(b * 128 + l) * 16384;
#pragma unroll
  for (int u = 0; u < 8; ++u) {
#pragma unroll
    for (int v = 0; v < 8; ++v) acc[u][v] = fmaxf(acc[u][v], 0.f);
    float4 r0 = make_float4(acc[u][0], acc[u][1], acc[u][2], acc[u][3]);
    float4 r1 = make_float4(acc[u][4], acc[u][5], acc[u][6], acc[u][7]);
    *(float4*)&y1p[(o0 + u) * 128 + w0] = r0;
    *(float4*)&y1p[(o0 + u) * 128 + w0 + 64] = r1;
    float s  = acc[u][0] + acc[u][1] + acc[u][2] + acc[u][3]
             + acc[u][4] + acc[u][5] + acc[u][6] + acc[u][7];
    float ss = acc[u][0]*acc[u][0] + acc[u][1]*acc[u][1] + acc[u][2]*acc[u][2]
             + acc[u][3]*acc[u][3] + acc[u][4]*acc[u][4] + acc[u][5]*acc[u][5]
             + acc[u][6]*acc[u][6] + acc[u][7]*acc[u][7];
#pragma unroll
    for (int off = 1; off < 16; off <<= 1) {
      s  += __shfl_xor(s, off);
      ss += __shfl_xor(ss, off);
    }
    if (tx == 0) {
      Pbuf[blockIdx.x * 256 + o0 + u] = s;
      Pbuf[blockIdx.x * 256 + 128 + o0 + u] = ss;
    }
  }
}

// ---------------- K2: parallel reduce partials -> bn1 scale/shift -----------
__global__ __launch_bounds__(64) void k2_bn1(
    const float* __restrict__ Pbuf, float* __restrict__ S,
    const float* __restrict__ g1, const float* __restrict__ b1)
{
  const int t = blockIdx.x;
  const int lane = threadIdx.x;
  float s1 = 0.f, s2 = 0.f;
#pragma unroll
  for (int m = 0; m < 8; ++m) {
    int blk = lane + 64 * m;
    s1 += Pbuf[blk * 256 + t];
    s2 += Pbuf[blk * 256 + 128 + t];
  }
#pragma unroll
  for (int off = 1; off < 64; off <<= 1) {
    s1 += __shfl_xor(s1, off);
    s2 += __shfl_xor(s2, off);
  }
  if (lane == 0) {
    const float inv = 1.f / 65536.f;
    float m = s1 * inv;
    float var = s2 * inv - m * m;
    float sc = g1[t] * rsqrtf(var + EPS);
    S[256 + t] = sc;
    S[384 + t] = b1[t] - m * sc;
  }
}

// ---------------- K_tr: y1 -> y2h (BN applied, packed half2, planar) --------
__global__ __launch_bounds__(256) void k_tr(
    const float* __restrict__ y1, const float* __restrict__ S,
    unsigned* __restrict__ y2h)
{
  __shared__ _Float16 th[2][64][134];
  const int s = blockIdx.x & 63, b = blockIdx.x >> 6;
  const int h = s >> 3, slot = s & 7;
  const int o0 = 2 * s, o1 = 2 * s + 1;
  const float sc0 = S[256 + o0], sh0 = S[384 + o0];
  const float sc1 = S[256 + o1], sh1 = S[384 + o1];
  const int tid = threadIdx.x;
  for (int lh = 0; lh < 2; ++lh) {
    const int l0 = lh * 64;
    for (int idx = tid; idx < 8192; idx += 256) {
      int ll = idx >> 7, w = idx & 127;
      size_t base = ((size_t)(b * 128 + l0 + ll) * 128) * 128 + w;
      float v0 = y1[base + (size_t)o0 * 128];
      float v1 = y1[base + (size_t)o1 * 128];
      th[0][ll][w] = (_Float16)(v0 * sc0 + sh0);
      th[1][ll][w] = (_Float16)(v1 * sc1 + sh1);
    }
    __syncthreads();
    for (int idx = tid; idx < 8192; idx += 256) {
      int w = idx >> 6, ll = idx & 63;
      unsigned pk;
      { half2_t hh; hh[0] = th[0][ll][w]; hh[1] = th[1][ll][w];
        union { unsigned u; half2_t h; } xx; xx.h = hh; pk = xx.u; }
      y2h[((size_t)((b * 128 + w) * 8 + h) * 8 + slot) * 128 + l0 + ll] = pk;
    }
    __syncthreads();
  }
}

// ---------------- K0: pos window tables (f32) + packed pos image ------------
__global__ __launch_bounds__(128) void k0_pos(const float* __restrict__ pos,
                                              float* __restrict__ PT,
                                              unsigned* __restrict__ pos_h)
{
  const int blk = blockIdx.x, tid = threadIdx.x;
  if (blk == 28) {
    for (int u = tid; u < 255; u += 128) {
#pragma unroll
      for (int s = 0; s < 12; ++s) {
        unsigned val = 0;
        if (s < 8) val = packf2(pos[(2 * s) * 255 + u], pos[(2 * s + 1) * 255 + u]);
        pos_h[u * 12 + s] = val;
      }
    }
    return;
  }
  __shared__ float r0[255], r1[255];
  int rowA, rowB, out;
  bool prod;
  if (blk < 4)       { rowA = blk;                 rowB = rowA;               out = blk * 128;              prod = false; }
  else if (blk < 14) { int m = blk - 4;  rowA = pair_c[m];     rowB = pair_cp[m];     out = 1024 + m * 128; prod = true; }
  else if (blk < 18) { rowA = 4 + (blk - 14);      rowB = rowA;               out = 512 + (blk - 14) * 128; prod = false; }
  else               { int m = blk - 18; rowA = 4 + pair_c[m]; rowB = 4 + pair_cp[m]; out = 2304 + m * 128; prod = true; }
  for (int u = tid; u < 255; u += 128) {
    r0[u] = pos[rowA * 255 + u];
    r1[u] = pos[rowB * 255 + u];
  }
  __syncthreads();
  float s = 0.f;
  if (prod) {
    for (int d = 0; d < 128; ++d) s += r0[tid + d] * r1[tid + d];
  } else {
    for (int d = 0; d < 128; ++d) s += r0[tid + d];
  }
  PT[out + tid] = s;
}

// ---------------- K3: att stats via Gram/window tables (reads y2h) ----------
__global__ __launch_bounds__(256) void k3_stats(
    const unsigned* __restrict__ y2h, float* __restrict__ S,
    const float* __restrict__ PT)
{
  const int unit = blockIdx.x * 4 + (threadIdx.x >> 6);
  const int lane = threadIdx.x & 63;
  const int h = unit & 7;
  const unsigned* yb = y2h + (size_t)unit * 1024;
  float q[4][2], k[4][2];
#pragma unroll
  for (int pl = 0; pl < 2; ++pl) {
    half2_t ha = bch2(yb[pl * 128 + lane]);
    half2_t hb = bch2(yb[pl * 128 + 64 + lane]);
    q[2 * pl][0] = (float)ha[0]; q[2 * pl + 1][0] = (float)ha[1];
    q[2 * pl][1] = (float)hb[0]; q[2 * pl + 1][1] = (float)hb[1];
  }
#pragma unroll
  for (int pl = 0; pl < 2; ++pl) {
    half2_t ha = bch2(yb[(2 + pl) * 128 + lane]);
    half2_t hb = bch2(yb[(2 + pl) * 128 + 64 + lane]);
    k[2 * pl][0] = (float)ha[0]; k[2 * pl + 1][0] = (float)ha[1];
    k[2 * pl][1] = (float)hb[0]; k[2 * pl + 1][1] = (float)hb[1];
  }
  float vals[32];
#pragma unroll
  for (int c = 0; c < 4; ++c) {
    vals[c]     = q[c][0] + q[c][1];
    vals[4 + c] = k[c][0] + k[c][1];
  }
#pragma unroll
  for (int m = 0; m < 10; ++m) {
    int c = pair_c[m], cp = pair_cp[m];
    vals[8 + m]  = q[c][0] * q[cp][0] + q[c][1] * q[cp][1];
    vals[18 + m] = k[c][0] * k[cp][0] + k[c][1] * k[cp][1];
  }
  float qr = 0, qrss = 0, kr = 0, krss = 0;
#pragma unroll
  for (int c = 0; c < 4; ++c) {
    qr += q[c][0] * PT[c * 128 + lane]       + q[c][1] * PT[c * 128 + 64 + lane];
    kr += k[c][0] * PT[512 + c * 128 + lane] + k[c][1] * PT[512 + c * 128 + 64 + lane];
  }
#pragma unroll
  for (int m = 0; m < 10; ++m) {
    int c = pair_c[m], cp = pair_cp[m];
    float mult = (c == cp) ? 1.f : 2.f;
    qrss += mult * (q[c][0] * q[cp][0] * PT[1024 + m * 128 + lane]
                  + q[c][1] * q[cp][1] * PT[1024 + m * 128 + 64 + lane]);
    krss += mult * (k[c][0] * k[cp][0] * PT[2304 + m * 128 + lane]
                  + k[c][1] * k[cp][1] * PT[2304 + m * 128 + 64 + lane]);
  }
  vals[28] = qr; vals[29] = qrss; vals[30] = kr; vals[31] = krss;
#pragma unroll
  for (int v = 0; v < 32; ++v) {
    float t = vals[v];
#pragma unroll
    for (int off = 1; off < 64; off <<= 1) t += __shfl_xor(t, off);
    vals[v] = t;
  }
  if (lane == 0) {
    float qk_sum = 0, qk_ss = 0;
#pragma unroll
    for (int c = 0; c < 4; ++c) qk_sum += vals[c] * vals[4 + c];
#pragma unroll
    for (int m = 0; m < 10; ++m) {
      float mult = (pair_c[m] == pair_cp[m]) ? 1.f : 2.f;
      qk_ss += mult * vals[8 + m] * vals[18 + m];
    }
    atomicAdd(&S[512 + h], qk_sum);
    atomicAdd(&S[536 + h], qk_ss);
    atomicAdd(&S[520 + h], vals[28]);
    atomicAdd(&S[544 + h], vals[29]);
    atomicAdd(&S[528 + h], vals[30]);
    atomicAdd(&S[552 + h], vals[31]);
  }
}

// ---------------- K4: finalize att bn -> per-head coefs ---------------------
__global__ void k4_att(float* __restrict__ S, const float* __restrict__ ga,
                       const float* __restrict__ ba,
                       const float* __restrict__ gqr, const float* __restrict__ gkr)
{
  int h = threadIdx.x;
  if (h >= 8) return;
  const float inv = 1.f / 8388608.f;
  float gates[3] = {1.f, gqr[0], gkr[0]};
  float csum = 0.f;
#pragma unroll
  for (int g = 0; g < 3; ++g) {
    float mr = S[512 + g * 8 + h] * inv;
    float er = S[536 + g * 8 + h] * inv;
    float gt = gates[g];
    float mean = gt * mr;
    float var = gt * gt * er - mean * mean;
    float sc = ga[g * 8 + h] * rsqrtf(var + EPS);
    S[560 + g * 8 + h] = gt * sc;
    csum += ba[g * 8 + h] - mean * sc;
  }
  S[584 + h] = csum;
}

// ---------------- K5: fused scores + fixed-shift softmax + f32 PV -----------
// 512 threads: thread = (p = tid>>2, isub = tid&3), 32 i per thread.
// softmax via e = exp(s - 9) (uniform shift -> exact); PV accumulated in f32
// (v_fma_mix) to avoid fp16 overflow; normalize by row-sum at the end.
__global__ __launch_bounds__(512, 6) void k5_apply(
    const unsigned* __restrict__ y2h, const unsigned* __restrict__ pos_h,
    float* __restrict__ S, _Float16* __restrict__ av, _Float16* __restrict__ avp,
    const float* __restrict__ gv_p, const float* __restrict__ gvp_p)
{
  __shared__ __align__(16) unsigned qkv_s[128][8];
  __shared__ __align__(16) unsigned posm[255][12];
  __shared__ float red[8][4];
  const int h = blockIdx.x & 7, n = blockIdx.x >> 3;
  const int tid = threadIdx.x;
  const unsigned* yb = y2h + (size_t)(n * 8 + h) * 1024;
  unsigned* qf = (unsigned*)qkv_s;
  for (int m = tid; m < 1024; m += 512)
    qf[m] = yb[(m & 7) * 128 + (m >> 3)];
  unsigned* pf = (unsigned*)posm;
  for (int m = tid; m < 3060; m += 512) pf[m] = pos_h[m];
  __syncthreads();

  const int p = tid >> 2, isub = tid & 3;
  uint4 qk4 = *(const uint4*)&qkv_s[p][0];
  const half2_t q01 = bch2(qk4.x), q23 = bch2(qk4.y);
  const half2_t k01 = bch2(qk4.z), k23 = bch2(qk4.w);
  const float C0 = S[560 + h], C1 = S[568 + h], C2 = S[576 + h], C3v = S[584 + h];

  float sum = 0.f;
  float accv[8], accvp[8];
#pragma unroll
  for (int c = 0; c < 8; ++c) { accv[c] = 0.f; accvp[c] = 0.f; }

#pragma unroll 4
  for (int j = 0; j < 32; ++j) {
    int i = isub + 4 * j;
    int u = p - i + 127;
    uint2 kt  = *(const uint2*)&qkv_s[i][2];
    uint4 qkp = *(const uint4*)&posm[u][0];
    float aa = fdot2(q23, bch2(kt.y),  fdot2(q01, bch2(kt.x),  0.f));
    float bq = fdot2(q23, bch2(qkp.y), fdot2(q01, bch2(qkp.x), 0.f));
    float ck = fdot2(k23, bch2(qkp.w), fdot2(k01, bch2(qkp.z), 0.f));
    float s = aa * C0 + bq * C1 + ck * C2 + C3v;
    float e = __expf(s - 9.f);
    sum += e;
    uint4 vv = *(const uint4*)&qkv_s[i][4];
    uint4 vp = *(const uint4*)&posm[u][4];
    half2_t v0 = bch2(vv.x), v1 = bch2(vv.y), v2 = bch2(vv.z), v3 = bch2(vv.w);
    half2_t w0 = bch2(vp.x), w1 = bch2(vp.y), w2 = bch2(vp.z), w3 = bch2(vp.w);
    accv[0] += e * (float)v0[0]; accv[1] += e * (float)v0[1];
    accv[2] += e * (float)v1[0]; accv[3] += e * (float)v1[1];
    accv[4] += e * (float)v2[0]; accv[5] += e * (float)v2[1];
    accv[6] += e * (float)v3[0]; accv[7] += e * (float)v3[1];
    accvp[0] += e * (float)w0[0]; accvp[1] += e * (float)w0[1];
    accvp[2] += e * (float)w1[0]; accvp[3] += e * (float)w1[1];
    accvp[4] += e * (float)w2[0]; accvp[5] += e * (float)w2[1];
    accvp[6] += e * (float)w3[0]; accvp[7] += e * (float)w3[1];
  }
  sum += __shfl_xor(sum, 1);
  sum += __shfl_xor(sum, 2);
#pragma unroll
  for (int c = 0; c < 8; ++c) {
    accv[c]  += __shfl_xor(accv[c], 1);  accv[c]  += __shfl_xor(accv[c], 2);
    accvp[c] += __shfl_xor(accvp[c], 1); accvp[c] += __shfl_xor(accvp[c], 2);
  }

  float sv = 0, ssv = 0, svp = 0, ssvp = 0;
  if (isub == 0) {
    const float fv = gv_p[0] / sum, fp2 = gvp_p[0] / sum;
    size_t base = ((size_t)(n * 8 + h) * 8) * 128 + p;
#pragma unroll
    for (int c = 0; c < 8; ++c) {
      float x1 = accv[c] * fv;
      float x2 = accvp[c] * fp2;
      av [base + c * 128] = (_Float16)x1;
      avp[base + c * 128] = (_Float16)x2;
      sv += x1; ssv += x1 * x1; svp += x2; ssvp += x2 * x2;
    }
  }
  float vals[4] = {sv, ssv, svp, ssvp};
#pragma unroll
  for (int kk = 0; kk < 4; ++kk) {
    float v = vals[kk];
#pragma unroll
    for (int off = 1; off < 64; off <<= 1) v += __shfl_xor(v, off);
    vals[kk] = v;
  }
  const int wid = tid >> 6, lane = tid & 63;
  if (lane == 0) {
#pragma unroll
    for (int kk = 0; kk < 4; ++kk) red[wid][kk] = vals[kk];
  }
  __syncthreads();
  if (tid == 0) {
    float t0 = 0, t1 = 0, t2 = 0, t3 = 0;
#pragma unroll
    for (int w = 0; w < 8; ++w) {
      t0 += red[w][0]; t1 += red[w][1]; t2 += red[w][2]; t3 += red[w][3];
    }
    atomicAdd(&S[592 + h], t0);
    atomicAdd(&S[608 + h], t1);
    atomicAdd(&S[600 + h], t2);
    atomicAdd(&S[616 + h], t3);
  }
}

// ---------------- K6: finalize v bn ----------------------------------------
__global__ void k6_v(float* __restrict__ S, const float* __restrict__ gv,
                     const float* __restrict__ bv)
{
  int h = threadIdx.x;
  if (h >= 8) return;
  const float inv = 1.f / 524288.f;
  float m = S[592 + h] * inv;
  float var = S[608 + h] * inv - m * m;
  float sc = gv[h] * rsqrtf(var + EPS);
  S[624 + h] = sc;
  S[632 + h] = bv[h] - m * sc;
  m = S[600 + h] * inv;
  var = S[616 + h] * inv - m * m;
  sc = gv[8 + h] * rsqrtf(var + EPS);
  S[640 + h] = sc;
  S[648 + h] = bv[8 + h] - m * sc;
}

// ---------------- K7: bn apply + sum halves + LDS-tiled transpose out -------
__global__ __launch_bounds__(256) void k7_out(
    const _Float16* __restrict__ av, const _Float16* __restrict__ avp,
    const float* __restrict__ S, float* __restrict__ out)
{
  __shared__ float tile[64][129];
  const int wt = blockIdx.x & 1;
  const int d  = (blockIdx.x >> 1) & 63;
  const int b  = blockIdx.x >> 7;
  const int h = d >> 3, c = d & 7;
  const float scv = S[624 + h], shv = S[632 + h];
  const float scp = S[640 + h], shp = S[648 + h];
  const int tid = threadIdx.x;
  for (int idx = tid; idx < 8192; idx += 256) {
    int wl = idx >> 7, p = idx & 127;
    int n = b * 128 + wt * 64 + wl;
    size_t base = (((size_t)n * 8 + h) * 8 + c) * 128 + p;
    tile[wl][p] = (float)av[base] * scv + shv + (float)avp[base] * scp + shp;
  }
  __syncthreads();
  for (int idx = tid; idx < 8192; idx += 256) {
    int p = idx >> 6, wl = idx & 63;
    out[(((size_t)b * 64 + d) * 128 + p) * 128 + wt * 64 + wl] = tile[wl][p];
  }
}

// ---------------- launch ----------------------------------------------------
extern "C" void kernel_launch(void* const* d_in, const int* in_sizes, int n_in,
                              void* d_out, int out_size, void* d_ws, size_t ws_size,
                              hipStream_t stream)
{
  const float* x   = (const float*)d_in[0];
  const float* wq  = (const float*)d_in[1];
  const float* g1  = (const float*)d_in[2];
  const float* b1  = (const float*)d_in[3];
  const float* pos = (const float*)d_in[4];
  const float* gqr = (const float*)d_in[5];
  const float* gkr = (const float*)d_in[6];
  const float* gvp = (const float*)d_in[7];
  const float* gv  = (const float*)d_in[8];
  const float* ga  = (const float*)d_in[9];
  const float* ba  = (const float*)d_in[10];
  const float* gv2 = (const float*)d_in[11];
  const float* bv2 = (const float*)d_in[12];

  float* ws = (float*)d_ws;
  float*    y1    = ws;                          // f32 (b,l,o,w)
  _Float16* av    = (_Float16*)ws;               // reuses y1 region
  _Float16* avp   = (_Float16*)ws + 4194304;
  float*    Pbuf  = ws + 8388608;                // k1 partials (pre-k_tr)
  unsigned* y2h   = (unsigned*)(ws + 8388608);   // packed qkv (clobbers Pbuf)
  float*    S     = ws + 16777216;
  unsigned* pos_h = (unsigned*)(ws + 16778240);
  float*    PT    = ws + 16781312;
  float*    out   = (float*)d_out;

  hipMemsetAsync(S, 0, 1024 * sizeof(float), stream);
  k0_pos<<<29, 128, 0, stream>>>(pos, PT, pos_h);
  k1_gemm<<<512, 256, 0, stream>>>(x, wq, y1, Pbuf);
  k2_bn1<<<128, 64, 0, stream>>>(Pbuf, S, g1, b1);
  k_tr<<<256, 256, 0, stream>>>(y1, S, y2h);
  k3_stats<<<1024, 256, 0, stream>>>(y2h, S, PT);
  k4_att<<<1, 64, 0, stream>>>(S, ga, ba, gqr, gkr);
  k5_apply<<<4096, 512, 0, stream>>>(y2h, pos_h, S, av, avp, gv, gvp);
  k6_v<<<1, 64, 0, stream>>>(S, gv2, bv2);
  k7_out<<<512, 256, 0, stream>>>(av, avp, S, out);
}

// Round 7
// 218.433 us; speedup vs baseline: 3.1261x; 1.6281x over previous
//
#include <hip/hip_runtime.h>
#include <hip/hip_fp16.h>

#define EPS 1e-5f

// Problem constants: B=4, C=64, H=128, W=128, N=512, OP2=128, HEAD=8, HP=16
// qk_dim=4, v_dim=8

// workspace layout (float offsets)
//  y1 : (b,l,o,w) f32, 8,388,608 at 0            [dead after k_tr]
//  av : (n,h,c,p) half, 4,194,304 halves at 0    (k5 writes; y1 region)
//  avp: (n,h,c,p) half at float-offset 2,097,152
//  Pb3: k3 partials 512*6 f32 at 4,200,000       (y1 dead zone)
//  Vbuf: k5 partials 4096*4 f32 at 4,250,000     (y1 dead zone)
//  Pbuf: k1 partials 512*256 f32 at 8,388,608    [dead after k2]
//  y2h: (n,h,slot,l) packed half2 per uint, 1,048,576 uints at 8,388,608
//       slot: 0 q01 1 q23 2 k01 3 k23 4 v01 5 v23 6 v45 7 v67 (BN applied)
//  S  : stats 1024 f32 at 16,777,216
//  pos_h: packed pos image [u=0..254][12 uints] at 16,778,240
//  PT : f32 window tables at 16,781,312

typedef _Float16 half2_t __attribute__((ext_vector_type(2)));

__device__ __constant__ int pair_c [10] = {0,0,0,0,1,1,1,2,2,3};
__device__ __constant__ int pair_cp[10] = {0,1,2,3,1,2,3,2,3,3};
// k3_red: stat k -> S slot base
__device__ __constant__ int s_base[6] = {512, 536, 520, 544, 528, 552};

__device__ inline float fdot2(half2_t a, half2_t b, float c) {
#if __has_builtin(__builtin_amdgcn_fdot2)
  return __builtin_amdgcn_fdot2(a, b, c, false);
#else
  return c + (float)a[0] * (float)b[0] + (float)a[1] * (float)b[1];
#endif
}
__device__ inline half2_t bch2(unsigned u) {
  union { unsigned u; half2_t h; } x; x.u = u; return x.h;
}
__device__ inline unsigned packf2(float a, float b) {
  half2_t h; h[0] = (_Float16)a; h[1] = (_Float16)b;
  union { unsigned u; half2_t h; } x; x.h = h; return x.u;
}

// ---------------- K1: qkv GEMM + relu + bn1 partials (no atomics) -----------
__global__ __launch_bounds__(256) void k1_gemm(
    const float* __restrict__ x, const float* __restrict__ wq,
    float* __restrict__ y1, float* __restrict__ Pbuf)
{
  __shared__ float xs[64][132];
  const int b = blockIdx.x >> 7, l = blockIdx.x & 127;
  const int tid = threadIdx.x;
  const float* xp = x + (size_t)b * 1048576 + (size_t)l * 128;
  for (int idx = tid; idx < 8192; idx += 256) {
    int c = idx >> 7, wv = idx & 127;
    xs[c][wv] = xp[c * 16384 + wv];
  }
  __syncthreads();
  const int ty = tid >> 4, tx = tid & 15;
  const int o0 = ty * 8, w0 = tx * 4;
  float acc[8][8];
#pragma unroll
  for (int u = 0; u < 8; ++u)
#pragma unroll
    for (int v = 0; v < 8; ++v) acc[u][v] = 0.f;

  for (int c4 = 0; c4 < 64; c4 += 4) {
    float wr[8][4];
#pragma unroll
    for (int u = 0; u < 8; ++u)
      *(float4*)&wr[u][0] = *(const float4*)&wq[(o0 + u) * 64 + c4];
#pragma unroll
    for (int dc = 0; dc < 4; ++dc) {
      float4 xa = *(const float4*)&xs[c4 + dc][w0];
      float4 xb = *(const float4*)&xs[c4 + dc][w0 + 64];
#pragma unroll
      for (int u = 0; u < 8; ++u) {
        float wv = wr[u][dc];
        acc[u][0] += wv * xa.x; acc[u][1] += wv * xa.y;
        acc[u][2] += wv * xa.z; acc[u][3] += wv * xa.w;
        acc[u][4] += wv * xb.x; acc[u][5] += wv * xb.y;
        acc[u][6] += wv * xb.z; acc[u][7] += wv * xb.w;
      }
    }
  }
  float* y1p = y1 + (size_t)(b * 128 + l) * 16384;
#pragma unroll
  for (int u = 0; u < 8; ++u) {
#pragma unroll
    for (int v = 0; v < 8; ++v) acc[u][v] = fmaxf(acc[u][v], 0.f);
    float4 r0 = make_float4(acc[u][0], acc[u][1], acc[u][2], acc[u][3]);
    float4 r1 = make_float4(acc[u][4], acc[u][5], acc[u][6], acc[u][7]);
    *(float4*)&y1p[(o0 + u) * 128 + w0] = r0;
    *(float4*)&y1p[(o0 + u) * 128 + w0 + 64] = r1;
    float s  = acc[u][0] + acc[u][1] + acc[u][2] + acc[u][3]
             + acc[u][4] + acc[u][5] + acc[u][6] + acc[u][7];
    float ss = acc[u][0]*acc[u][0] + acc[u][1]*acc[u][1] + acc[u][2]*acc[u][2]
             + acc[u][3]*acc[u][3] + acc[u][4]*acc[u][4] + acc[u][5]*acc[u][5]
             + acc[u][6]*acc[u][6] + acc[u][7]*acc[u][7];
#pragma unroll
    for (int off = 1; off < 16; off <<= 1) {
      s  += __shfl_xor(s, off);
      ss += __shfl_xor(ss, off);
    }
    if (tx == 0) {
      Pbuf[blockIdx.x * 256 + o0 + u] = s;
      Pbuf[blockIdx.x * 256 + 128 + o0 + u] = ss;
    }
  }
}

// ---------------- K2: parallel reduce partials -> bn1 scale/shift -----------
__global__ __launch_bounds__(64) void k2_bn1(
    const float* __restrict__ Pbuf, float* __restrict__ S,
    const float* __restrict__ g1, const float* __restrict__ b1)
{
  const int t = blockIdx.x;
  const int lane = threadIdx.x;
  float s1 = 0.f, s2 = 0.f;
#pragma unroll
  for (int m = 0; m < 8; ++m) {
    int blk = lane + 64 * m;
    s1 += Pbuf[blk * 256 + t];
    s2 += Pbuf[blk * 256 + 128 + t];
  }
#pragma unroll
  for (int off = 1; off < 64; off <<= 1) {
    s1 += __shfl_xor(s1, off);
    s2 += __shfl_xor(s2, off);
  }
  if (lane == 0) {
    const float inv = 1.f / 65536.f;
    float m = s1 * inv;
    float var = s2 * inv - m * m;
    float sc = g1[t] * rsqrtf(var + EPS);
    S[256 + t] = sc;
    S[384 + t] = b1[t] - m * sc;
  }
}

// ---------------- K_tr: y1 -> y2h (BN applied, packed half2, planar) --------
__global__ __launch_bounds__(256) void k_tr(
    const float* __restrict__ y1, const float* __restrict__ S,
    unsigned* __restrict__ y2h)
{
  __shared__ _Float16 th[2][64][134];
  const int s = blockIdx.x & 63, b = blockIdx.x >> 6;
  const int h = s >> 3, slot = s & 7;
  const int o0 = 2 * s, o1 = 2 * s + 1;
  const float sc0 = S[256 + o0], sh0 = S[384 + o0];
  const float sc1 = S[256 + o1], sh1 = S[384 + o1];
  const int tid = threadIdx.x;
  for (int lh = 0; lh < 2; ++lh) {
    const int l0 = lh * 64;
    for (int idx = tid; idx < 8192; idx += 256) {
      int ll = idx >> 7, w = idx & 127;
      size_t base = ((size_t)(b * 128 + l0 + ll) * 128) * 128 + w;
      float v0 = y1[base + (size_t)o0 * 128];
      float v1 = y1[base + (size_t)o1 * 128];
      th[0][ll][w] = (_Float16)(v0 * sc0 + sh0);
      th[1][ll][w] = (_Float16)(v1 * sc1 + sh1);
    }
    __syncthreads();
    for (int idx = tid; idx < 8192; idx += 256) {
      int w = idx >> 6, ll = idx & 63;
      unsigned pk;
      { half2_t hh; hh[0] = th[0][ll][w]; hh[1] = th[1][ll][w];
        union { unsigned u; half2_t h; } xx; xx.h = hh; pk = xx.u; }
      y2h[((size_t)((b * 128 + w) * 8 + h) * 8 + slot) * 128 + l0 + ll] = pk;
    }
    __syncthreads();
  }
}

// ---------------- K0: pos window tables (f32) + packed pos image ------------
__global__ __launch_bounds__(128) void k0_pos(const float* __restrict__ pos,
                                              float* __restrict__ PT,
                                              unsigned* __restrict__ pos_h)
{
  const int blk = blockIdx.x, tid = threadIdx.x;
  if (blk == 28) {
    for (int u = tid; u < 255; u += 128) {
#pragma unroll
      for (int s = 0; s < 12; ++s) {
        unsigned val = 0;
        if (s < 8) val = packf2(pos[(2 * s) * 255 + u], pos[(2 * s + 1) * 255 + u]);
        pos_h[u * 12 + s] = val;
      }
    }
    return;
  }
  __shared__ float r0[255], r1[255];
  int rowA, rowB, out;
  bool prod;
  if (blk < 4)       { rowA = blk;                 rowB = rowA;               out = blk * 128;              prod = false; }
  else if (blk < 14) { int m = blk - 4;  rowA = pair_c[m];     rowB = pair_cp[m];     out = 1024 + m * 128; prod = true; }
  else if (blk < 18) { rowA = 4 + (blk - 14);      rowB = rowA;               out = 512 + (blk - 14) * 128; prod = false; }
  else               { int m = blk - 18; rowA = 4 + pair_c[m]; rowB = 4 + pair_cp[m]; out = 2304 + m * 128; prod = true; }
  for (int u = tid; u < 255; u += 128) {
    r0[u] = pos[rowA * 255 + u];
    r1[u] = pos[rowB * 255 + u];
  }
  __syncthreads();
  float s = 0.f;
  if (prod) {
    for (int d = 0; d < 128; ++d) s += r0[tid + d] * r1[tid + d];
  } else {
    for (int d = 0; d < 128; ++d) s += r0[tid + d];
  }
  PT[out + tid] = s;
}

// ---------------- K3: att stats, 8 n per wave, NO atomics -------------------
// wave W = blockIdx*4 + wid: h = W&7, n = (W>>3)*8 .. +8
// writes 6 partials to Pb3[W*6 + k]  (k: 0 qk 1 qkss 2 qr 3 qrss 4 kr 5 krss)
__global__ __launch_bounds__(256) void k3_stats(
    const unsigned* __restrict__ y2h, const float* __restrict__ PT,
    float* __restrict__ Pb3)
{
  const int W = blockIdx.x * 4 + (threadIdx.x >> 6);
  const int lane = threadIdx.x & 63;
  const int h = W & 7;
  const int n0 = (W >> 3) * 8;
  // hoist PT loads (lane-indexed only)
  float Pq[4][2], Pk[4][2], Wq[10][2], Wk[10][2];
#pragma unroll
  for (int c = 0; c < 4; ++c) {
    Pq[c][0] = PT[c * 128 + lane];        Pq[c][1] = PT[c * 128 + 64 + lane];
    Pk[c][0] = PT[512 + c * 128 + lane];  Pk[c][1] = PT[512 + c * 128 + 64 + lane];
  }
#pragma unroll
  for (int m = 0; m < 10; ++m) {
    Wq[m][0] = PT[1024 + m * 128 + lane]; Wq[m][1] = PT[1024 + m * 128 + 64 + lane];
    Wk[m][0] = PT[2304 + m * 128 + lane]; Wk[m][1] = PT[2304 + m * 128 + 64 + lane];
  }
  float acc_qk = 0, acc_qkss = 0, acc_qr = 0, acc_qrss = 0, acc_kr = 0, acc_krss = 0;
  for (int t = 0; t < 8; ++t) {
    const unsigned* yb = y2h + (size_t)((n0 + t) * 8 + h) * 1024;
    float q[4][2], k[4][2];
#pragma unroll
    for (int pl = 0; pl < 2; ++pl) {
      half2_t ha = bch2(yb[pl * 128 + lane]);
      half2_t hb = bch2(yb[pl * 128 + 64 + lane]);
      q[2 * pl][0] = (float)ha[0]; q[2 * pl + 1][0] = (float)ha[1];
      q[2 * pl][1] = (float)hb[0]; q[2 * pl + 1][1] = (float)hb[1];
      half2_t hc = bch2(yb[(2 + pl) * 128 + lane]);
      half2_t hd = bch2(yb[(2 + pl) * 128 + 64 + lane]);
      k[2 * pl][0] = (float)hc[0]; k[2 * pl + 1][0] = (float)hc[1];
      k[2 * pl][1] = (float)hd[0]; k[2 * pl + 1][1] = (float)hd[1];
    }
    // linear accumulators (per-lane, reduced once at end)
#pragma unroll
    for (int c = 0; c < 4; ++c) {
      acc_qr += q[c][0] * Pq[c][0] + q[c][1] * Pq[c][1];
      acc_kr += k[c][0] * Pk[c][0] + k[c][1] * Pk[c][1];
    }
#pragma unroll
    for (int m = 0; m < 10; ++m) {
      int c = pair_c[m], cp = pair_cp[m];
      float mult = (c == cp) ? 1.f : 2.f;
      acc_qrss += mult * (q[c][0] * q[cp][0] * Wq[m][0] + q[c][1] * q[cp][1] * Wq[m][1]);
      acc_krss += mult * (k[c][0] * k[cp][0] * Wk[m][0] + k[c][1] * k[cp][1] * Wk[m][1]);
    }
    // nonlinear: butterfly 28 vals, then per-unit products
    float vals[28];
#pragma unroll
    for (int c = 0; c < 4; ++c) {
      vals[c]     = q[c][0] + q[c][1];
      vals[4 + c] = k[c][0] + k[c][1];
    }
#pragma unroll
    for (int m = 0; m < 10; ++m) {
      int c = pair_c[m], cp = pair_cp[m];
      vals[8 + m]  = q[c][0] * q[cp][0] + q[c][1] * q[cp][1];
      vals[18 + m] = k[c][0] * k[cp][0] + k[c][1] * k[cp][1];
    }
#pragma unroll
    for (int v = 0; v < 28; ++v) {
      float tv = vals[v];
#pragma unroll
      for (int off = 1; off < 64; off <<= 1) tv += __shfl_xor(tv, off);
      vals[v] = tv;
    }
    float qk = 0, qkss = 0;
#pragma unroll
    for (int c = 0; c < 4; ++c) qk += vals[c] * vals[4 + c];
#pragma unroll
    for (int m = 0; m < 10; ++m) {
      float mult = (pair_c[m] == pair_cp[m]) ? 1.f : 2.f;
      qkss += mult * vals[8 + m] * vals[18 + m];
    }
    acc_qk += qk; acc_qkss += qkss;
  }
  float lin[4] = {acc_qr, acc_qrss, acc_kr, acc_krss};
#pragma unroll
  for (int v = 0; v < 4; ++v) {
    float tv = lin[v];
#pragma unroll
    for (int off = 1; off < 64; off <<= 1) tv += __shfl_xor(tv, off);
    lin[v] = tv;
  }
  if (lane == 0) {
    float* o = Pb3 + W * 6;
    o[0] = acc_qk; o[1] = acc_qkss;
    o[2] = lin[0]; o[3] = lin[1]; o[4] = lin[2]; o[5] = lin[3];
  }
}

// ---------------- K3r: reduce Pb3 -> S[512..559] ----------------------------
// 48 blocks x 64 lanes; block = h*6 + k
__global__ __launch_bounds__(64) void k3_red(
    const float* __restrict__ Pb3, float* __restrict__ S)
{
  const int h = blockIdx.x / 6, k = blockIdx.x % 6;
  const int g = threadIdx.x;
  float v = Pb3[(h + 8 * g) * 6 + k];
#pragma unroll
  for (int off = 1; off < 64; off <<= 1) v += __shfl_xor(v, off);
  if (g == 0) S[s_base[k] + h] = v;
}

// ---------------- K4: finalize att bn -> per-head coefs ---------------------
__global__ void k4_att(float* __restrict__ S, const float* __restrict__ ga,
                       const float* __restrict__ ba,
                       const float* __restrict__ gqr, const float* __restrict__ gkr)
{
  int h = threadIdx.x;
  if (h >= 8) return;
  const float inv = 1.f / 8388608.f;
  float gates[3] = {1.f, gqr[0], gkr[0]};
  float csum = 0.f;
#pragma unroll
  for (int g = 0; g < 3; ++g) {
    float mr = S[512 + g * 8 + h] * inv;
    float er = S[536 + g * 8 + h] * inv;
    float gt = gates[g];
    float mean = gt * mr;
    float var = gt * gt * er - mean * mean;
    float sc = ga[g * 8 + h] * rsqrtf(var + EPS);
    S[560 + g * 8 + h] = gt * sc;
    csum += ba[g * 8 + h] - mean * sc;
  }
  S[584 + h] = csum;
}

// ---------------- K5: fused scores + fixed-shift softmax + f32 PV -----------
// 512 threads: thread = (p = tid>>2, isub = tid&3), 32 i per thread.
// partial v-stats -> Vbuf (no atomics)
__global__ __launch_bounds__(512, 6) void k5_apply(
    const unsigned* __restrict__ y2h, const unsigned* __restrict__ pos_h,
    float* __restrict__ S, _Float16* __restrict__ av, _Float16* __restrict__ avp,
    const float* __restrict__ gv_p, const float* __restrict__ gvp_p,
    float* __restrict__ Vbuf)
{
  __shared__ __align__(16) unsigned qkv_s[128][8];
  __shared__ __align__(16) unsigned posm[255][12];
  __shared__ float red[8][4];
  const int h = blockIdx.x & 7, n = blockIdx.x >> 3;
  const int tid = threadIdx.x;
  const unsigned* yb = y2h + (size_t)(n * 8 + h) * 1024;
  unsigned* qf = (unsigned*)qkv_s;
  for (int m = tid; m < 1024; m += 512)
    qf[m] = yb[(m & 7) * 128 + (m >> 3)];
  unsigned* pf = (unsigned*)posm;
  for (int m = tid; m < 3060; m += 512) pf[m] = pos_h[m];
  __syncthreads();

  const int p = tid >> 2, isub = tid & 3;
  uint4 qk4 = *(const uint4*)&qkv_s[p][0];
  const half2_t q01 = bch2(qk4.x), q23 = bch2(qk4.y);
  const half2_t k01 = bch2(qk4.z), k23 = bch2(qk4.w);
  const float C0 = S[560 + h], C1 = S[568 + h], C2 = S[576 + h], C3v = S[584 + h];

  float sum = 0.f;
  float accv[8], accvp[8];
#pragma unroll
  for (int c = 0; c < 8; ++c) { accv[c] = 0.f; accvp[c] = 0.f; }

#pragma unroll 4
  for (int j = 0; j < 32; ++j) {
    int i = isub + 4 * j;
    int u = p - i + 127;
    uint2 kt  = *(const uint2*)&qkv_s[i][2];
    uint4 qkp = *(const uint4*)&posm[u][0];
    float aa = fdot2(q23, bch2(kt.y),  fdot2(q01, bch2(kt.x),  0.f));
    float bq = fdot2(q23, bch2(qkp.y), fdot2(q01, bch2(qkp.x), 0.f));
    float ck = fdot2(k23, bch2(qkp.w), fdot2(k01, bch2(qkp.z), 0.f));
    float s = aa * C0 + bq * C1 + ck * C2 + C3v;
    float e = __expf(s - 9.f);
    sum += e;
    uint4 vv = *(const uint4*)&qkv_s[i][4];
    uint4 vp = *(const uint4*)&posm[u][4];
    half2_t v0 = bch2(vv.x), v1 = bch2(vv.y), v2 = bch2(vv.z), v3 = bch2(vv.w);
    half2_t w0 = bch2(vp.x), w1 = bch2(vp.y), w2 = bch2(vp.z), w3 = bch2(vp.w);
    accv[0] += e * (float)v0[0]; accv[1] += e * (float)v0[1];
    accv[2] += e * (float)v1[0]; accv[3] += e * (float)v1[1];
    accv[4] += e * (float)v2[0]; accv[5] += e * (float)v2[1];
    accv[6] += e * (float)v3[0]; accv[7] += e * (float)v3[1];
    accvp[0] += e * (float)w0[0]; accvp[1] += e * (float)w0[1];
    accvp[2] += e * (float)w1[0]; accvp[3] += e * (float)w1[1];
    accvp[4] += e * (float)w2[0]; accvp[5] += e * (float)w2[1];
    accvp[6] += e * (float)w3[0]; accvp[7] += e * (float)w3[1];
  }
  sum += __shfl_xor(sum, 1);
  sum += __shfl_xor(sum, 2);
#pragma unroll
  for (int c = 0; c < 8; ++c) {
    accv[c]  += __shfl_xor(accv[c], 1);  accv[c]  += __shfl_xor(accv[c], 2);
    accvp[c] += __shfl_xor(accvp[c], 1); accvp[c] += __shfl_xor(accvp[c], 2);
  }

  float sv = 0, ssv = 0, svp = 0, ssvp = 0;
  if (isub == 0) {
    const float fv = gv_p[0] / sum, fp2 = gvp_p[0] / sum;
    size_t base = ((size_t)(n * 8 + h) * 8) * 128 + p;
#pragma unroll
    for (int c = 0; c < 8; ++c) {
      float x1 = accv[c] * fv;
      float x2 = accvp[c] * fp2;
      av [base + c * 128] = (_Float16)x1;
      avp[base + c * 128] = (_Float16)x2;
      sv += x1; ssv += x1 * x1; svp += x2; ssvp += x2 * x2;
    }
  }
  float vals[4] = {sv, ssv, svp, ssvp};
#pragma unroll
  for (int kk = 0; kk < 4; ++kk) {
    float v = vals[kk];
#pragma unroll
    for (int off = 1; off < 64; off <<= 1) v += __shfl_xor(v, off);
    vals[kk] = v;
  }
  const int wid = tid >> 6, lane = tid & 63;
  if (lane == 0) {
#pragma unroll
    for (int kk = 0; kk < 4; ++kk) red[wid][kk] = vals[kk];
  }
  __syncthreads();
  if (tid == 0) {
    float t0 = 0, t1 = 0, t2 = 0, t3 = 0;
#pragma unroll
    for (int w = 0; w < 8; ++w) {
      t0 += red[w][0]; t1 += red[w][1]; t2 += red[w][2]; t3 += red[w][3];
    }
    float* o = Vbuf + (size_t)blockIdx.x * 4;
    o[0] = t0; o[1] = t1; o[2] = t2; o[3] = t3;
  }
}

// ---------------- K6r: reduce Vbuf -> S[592..623] ---------------------------
// 32 blocks x 64 lanes; block = k*8 + h  (k: 0 sv 1 ssv 2 svp 3 ssvp)
__global__ __launch_bounds__(64) void k6_red(
    const float* __restrict__ Vbuf, float* __restrict__ S)
{
  const int k = blockIdx.x >> 3, h = blockIdx.x & 7;
  const int lane = threadIdx.x;
  float v = 0.f;
#pragma unroll
  for (int j = 0; j < 8; ++j) {
    int n = lane + 64 * j;
    v += Vbuf[(size_t)(n * 8 + h) * 4 + k];
  }
#pragma unroll
  for (int off = 1; off < 64; off <<= 1) v += __shfl_xor(v, off);
  if (lane == 0) {
    const int dst[4] = {592, 608, 600, 616};
    S[dst[k] + h] = v;
  }
}

// ---------------- K6: finalize v bn ----------------------------------------
__global__ void k6_v(float* __restrict__ S, const float* __restrict__ gv,
                     const float* __restrict__ bv)
{
  int h = threadIdx.x;
  if (h >= 8) return;
  const float inv = 1.f / 524288.f;
  float m = S[592 + h] * inv;
  float var = S[608 + h] * inv - m * m;
  float sc = gv[h] * rsqrtf(var + EPS);
  S[624 + h] = sc;
  S[632 + h] = bv[h] - m * sc;
  m = S[600 + h] * inv;
  var = S[616 + h] * inv - m * m;
  sc = gv[8 + h] * rsqrtf(var + EPS);
  S[640 + h] = sc;
  S[648 + h] = bv[8 + h] - m * sc;
}

// ---------------- K7: bn apply + sum halves + LDS-tiled transpose out -------
__global__ __launch_bounds__(256) void k7_out(
    const _Float16* __restrict__ av, const _Float16* __restrict__ avp,
    const float* __restrict__ S, float* __restrict__ out)
{
  __shared__ float tile[64][129];
  const int wt = blockIdx.x & 1;
  const int d  = (blockIdx.x >> 1) & 63;
  const int b  = blockIdx.x >> 7;
  const int h = d >> 3, c = d & 7;
  const float scv = S[624 + h], shv = S[632 + h];
  const float scp = S[640 + h], shp = S[648 + h];
  const int tid = threadIdx.x;
  for (int idx = tid; idx < 8192; idx += 256) {
    int wl = idx >> 7, p = idx & 127;
    int n = b * 128 + wt * 64 + wl;
    size_t base = (((size_t)n * 8 + h) * 8 + c) * 128 + p;
    tile[wl][p] = (float)av[base] * scv + shv + (float)avp[base] * scp + shp;
  }
  __syncthreads();
  for (int idx = tid; idx < 8192; idx += 256) {
    int p = idx >> 6, wl = idx & 63;
    out[(((size_t)b * 64 + d) * 128 + p) * 128 + wt * 64 + wl] = tile[wl][p];
  }
}

// ---------------- launch ----------------------------------------------------
extern "C" void kernel_launch(void* const* d_in, const int* in_sizes, int n_in,
                              void* d_out, int out_size, void* d_ws, size_t ws_size,
                              hipStream_t stream)
{
  const float* x   = (const float*)d_in[0];
  const float* wq  = (const float*)d_in[1];
  const float* g1  = (const float*)d_in[2];
  const float* b1  = (const float*)d_in[3];
  const float* pos = (const float*)d_in[4];
  const float* gqr = (const float*)d_in[5];
  const float* gkr = (const float*)d_in[6];
  const float* gvp = (const float*)d_in[7];
  const float* gv  = (const float*)d_in[8];
  const float* ga  = (const float*)d_in[9];
  const float* ba  = (const float*)d_in[10];
  const float* gv2 = (const float*)d_in[11];
  const float* bv2 = (const float*)d_in[12];

  float* ws = (float*)d_ws;
  float*    y1    = ws;                          // f32 (b,l,o,w)
  _Float16* av    = (_Float16*)ws;               // reuses y1 region
  _Float16* avp   = (_Float16*)ws + 4194304;
  float*    Pb3   = ws + 4200000;                // k3 partials (y1 dead zone)
  float*    Vbuf  = ws + 4250000;                // k5 partials (y1 dead zone)
  float*    Pbuf  = ws + 8388608;                // k1 partials (pre-k_tr)
  unsigned* y2h   = (unsigned*)(ws + 8388608);   // packed qkv (clobbers Pbuf)
  float*    S     = ws + 16777216;
  unsigned* pos_h = (unsigned*)(ws + 16778240);
  float*    PT    = ws + 16781312;
  float*    out   = (float*)d_out;

  hipMemsetAsync(S, 0, 1024 * sizeof(float), stream);
  k0_pos<<<29, 128, 0, stream>>>(pos, PT, pos_h);
  k1_gemm<<<512, 256, 0, stream>>>(x, wq, y1, Pbuf);
  k2_bn1<<<128, 64, 0, stream>>>(Pbuf, S, g1, b1);
  k_tr<<<256, 256, 0, stream>>>(y1, S, y2h);
  k3_stats<<<128, 256, 0, stream>>>(y2h, PT, Pb3);
  k3_red<<<48, 64, 0, stream>>>(Pb3, S);
  k4_att<<<1, 64, 0, stream>>>(S, ga, ba, gqr, gkr);
  k5_apply<<<4096, 512, 0, stream>>>(y2h, pos_h, S, av, avp, gv, gvp, Vbuf);
  k6_red<<<32, 64, 0, stream>>>(Vbuf, S);
  k6_v<<<1, 64, 0, stream>>>(S, gv2, bv2);
  k7_out<<<512, 256, 0, stream>>>(av, avp, S, out);
}

// Round 10
// 215.735 us; speedup vs baseline: 3.1652x; 1.0125x over previous
//
#include <hip/hip_runtime.h>
#include <hip/hip_fp16.h>

#define EPS 1e-5f

// Problem constants: B=4, C=64, H=128, W=128, N=512, OP2=128, HEAD=8, HP=16
// qk_dim=4, v_dim=8

// workspace layout (float offsets)
//  y1h: (b,l,o,w) half, 8,388,608 halves at 0    [dead after k_tr]
//  av : (n,h,c,p) half, 4,194,304 halves at 0    (k5 writes; y1h region)
//  avp: (n,h,c,p) half at float-offset 2,097,152
//  Pb3: k3 partials 512*6 f32 at 4,200,000
//  Vbuf: k5 partials 4096*4 f32 at 4,250,000
//  Pbuf: k1 partials 512*256 f32 at 8,388,608    [dead after k2]
//  y2h: (n,h,slot,l) packed half2 per uint, 1,048,576 uints at 8,388,608
//       slot: 0 q01 1 q23 2 k01 3 k23 4 v01 5 v23 6 v45 7 v67 (BN applied)
//  S  : stats 1024 f32 at 16,777,216
//  pos_h: packed qk-pos [u=0..254][4 uints] at 16,778,240 (1020 uints)
//  PT : f32 window tables at 16,781,312 (3584)
//  vpxg: reversed/parity-split vp pairs, 3072 uints at 16,785,000

typedef _Float16 half2_t __attribute__((ext_vector_type(2)));

__device__ __constant__ int pair_c [10] = {0,0,0,0,1,1,1,2,2,3};
__device__ __constant__ int pair_cp[10] = {0,1,2,3,1,2,3,2,3,3};

__device__ inline float fdot2(half2_t a, half2_t b, float c) {
#if __has_builtin(__builtin_amdgcn_fdot2)
  return __builtin_amdgcn_fdot2(a, b, c, false);
#else
  return c + (float)a[0] * (float)b[0] + (float)a[1] * (float)b[1];
#endif
}
__device__ inline half2_t bch2(unsigned u) {
  union { unsigned u; half2_t h; } x; x.u = u; return x.h;
}
__device__ inline unsigned packf2(float a, float b) {
  half2_t h; h[0] = (_Float16)a; h[1] = (_Float16)b;
  union { unsigned u; half2_t h; } x; x.h = h; return x.u;
}

// ---------------- K1: qkv GEMM + relu + bn1 partials; y1 stored HALF --------
__global__ __launch_bounds__(256) void k1_gemm(
    const float* __restrict__ x, const float* __restrict__ wq,
    _Float16* __restrict__ y1h, float* __restrict__ Pbuf)
{
  __shared__ float xs[64][132];
  const int b = blockIdx.x >> 7, l = blockIdx.x & 127;
  const int tid = threadIdx.x;
  const float* xp = x + (size_t)b * 1048576 + (size_t)l * 128;
  for (int idx = tid; idx < 8192; idx += 256) {
    int c = idx >> 7, wv = idx & 127;
    xs[c][wv] = xp[c * 16384 + wv];
  }
  __syncthreads();
  const int ty = tid >> 4, tx = tid & 15;
  const int o0 = ty * 8, w0 = tx * 4;
  float acc[8][8];
#pragma unroll
  for (int u = 0; u < 8; ++u)
#pragma unroll
    for (int v = 0; v < 8; ++v) acc[u][v] = 0.f;

  for (int c4 = 0; c4 < 64; c4 += 4) {
    float wr[8][4];
#pragma unroll
    for (int u = 0; u < 8; ++u)
      *(float4*)&wr[u][0] = *(const float4*)&wq[(o0 + u) * 64 + c4];
#pragma unroll
    for (int dc = 0; dc < 4; ++dc) {
      float4 xa = *(const float4*)&xs[c4 + dc][w0];
      float4 xb = *(const float4*)&xs[c4 + dc][w0 + 64];
#pragma unroll
      for (int u = 0; u < 8; ++u) {
        float wv = wr[u][dc];
        acc[u][0] += wv * xa.x; acc[u][1] += wv * xa.y;
        acc[u][2] += wv * xa.z; acc[u][3] += wv * xa.w;
        acc[u][4] += wv * xb.x; acc[u][5] += wv * xb.y;
        acc[u][6] += wv * xb.z; acc[u][7] += wv * xb.w;
      }
    }
  }
  _Float16* y1p = y1h + (size_t)(b * 128 + l) * 16384;
#pragma unroll
  for (int u = 0; u < 8; ++u) {
#pragma unroll
    for (int v = 0; v < 8; ++v) acc[u][v] = fmaxf(acc[u][v], 0.f);
    uint2 pa, pb;
    pa.x = packf2(acc[u][0], acc[u][1]); pa.y = packf2(acc[u][2], acc[u][3]);
    pb.x = packf2(acc[u][4], acc[u][5]); pb.y = packf2(acc[u][6], acc[u][7]);
    *(uint2*)&y1p[(o0 + u) * 128 + w0] = pa;
    *(uint2*)&y1p[(o0 + u) * 128 + w0 + 64] = pb;
    float s  = acc[u][0] + acc[u][1] + acc[u][2] + acc[u][3]
             + acc[u][4] + acc[u][5] + acc[u][6] + acc[u][7];
    float ss = acc[u][0]*acc[u][0] + acc[u][1]*acc[u][1] + acc[u][2]*acc[u][2]
             + acc[u][3]*acc[u][3] + acc[u][4]*acc[u][4] + acc[u][5]*acc[u][5]
             + acc[u][6]*acc[u][6] + acc[u][7]*acc[u][7];
#pragma unroll
    for (int off = 1; off < 16; off <<= 1) {
      s  += __shfl_xor(s, off);
      ss += __shfl_xor(ss, off);
    }
    if (tx == 0) {
      Pbuf[blockIdx.x * 256 + o0 + u] = s;
      Pbuf[blockIdx.x * 256 + 128 + o0 + u] = ss;
    }
  }
}

// ---------------- K2: parallel reduce partials -> bn1 scale/shift -----------
__global__ __launch_bounds__(64) void k2_bn1(
    const float* __restrict__ Pbuf, float* __restrict__ S,
    const float* __restrict__ g1, const float* __restrict__ b1)
{
  const int t = blockIdx.x;
  const int lane = threadIdx.x;
  float s1 = 0.f, s2 = 0.f;
#pragma unroll
  for (int m = 0; m < 8; ++m) {
    int blk = lane + 64 * m;
    s1 += Pbuf[blk * 256 + t];
    s2 += Pbuf[blk * 256 + 128 + t];
  }
#pragma unroll
  for (int off = 1; off < 64; off <<= 1) {
    s1 += __shfl_xor(s1, off);
    s2 += __shfl_xor(s2, off);
  }
  if (lane == 0) {
    const float inv = 1.f / 65536.f;
    float m = s1 * inv;
    float var = s2 * inv - m * m;
    float sc = g1[t] * rsqrtf(var + EPS);
    S[256 + t] = sc;
    S[384 + t] = b1[t] - m * sc;
  }
}

// ---------------- K_tr: y1h -> y2h (BN applied, packed half2, planar) -------
__global__ __launch_bounds__(256) void k_tr(
    const _Float16* __restrict__ y1h, const float* __restrict__ S,
    unsigned* __restrict__ y2h)
{
  __shared__ _Float16 th[2][64][134];
  const int s = blockIdx.x & 63, b = blockIdx.x >> 6;
  const int h = s >> 3, slot = s & 7;
  const int o0 = 2 * s, o1 = 2 * s + 1;
  const float sc0 = S[256 + o0], sh0 = S[384 + o0];
  const float sc1 = S[256 + o1], sh1 = S[384 + o1];
  const int tid = threadIdx.x;
  for (int lh = 0; lh < 2; ++lh) {
    const int l0 = lh * 64;
    for (int idx = tid; idx < 4096; idx += 256) {
      int ll = idx >> 6, wp = idx & 63;
      size_t base = ((size_t)(b * 128 + l0 + ll) * 128) * 128 + 2 * wp;
      unsigned a0 = *(const unsigned*)&y1h[base + (size_t)o0 * 128];
      unsigned a1 = *(const unsigned*)&y1h[base + (size_t)o1 * 128];
      half2_t ha = bch2(a0), hb = bch2(a1);
      *(unsigned*)&th[0][ll][2 * wp] =
          packf2((float)ha[0] * sc0 + sh0, (float)ha[1] * sc0 + sh0);
      *(unsigned*)&th[1][ll][2 * wp] =
          packf2((float)hb[0] * sc1 + sh1, (float)hb[1] * sc1 + sh1);
    }
    __syncthreads();
    for (int idx = tid; idx < 8192; idx += 256) {
      int w = idx >> 6, ll = idx & 63;
      unsigned pk;
      { half2_t hh; hh[0] = th[0][ll][w]; hh[1] = th[1][ll][w];
        union { unsigned u; half2_t h; } xx; xx.h = hh; pk = xx.u; }
      y2h[((size_t)((b * 128 + w) * 8 + h) * 8 + slot) * 128 + l0 + ll] = pk;
    }
    __syncthreads();
  }
}

// ---------------- K0: PT tables + packed qk-pos + vpx tables ----------------
// blocks 0..3: Pq, 4..13: Wq, 14..17: Pk, 18..27: Wk, 28: pos_h, 29: vpxg
__global__ __launch_bounds__(128) void k0_pos(const float* __restrict__ pos,
                                              float* __restrict__ PT,
                                              unsigned* __restrict__ pos_h,
                                              unsigned* __restrict__ vpxg)
{
  const int blk = blockIdx.x, tid = threadIdx.x;
  if (blk == 28) {
    for (int u = tid; u < 255; u += 128) {
#pragma unroll
      for (int s = 0; s < 4; ++s)
        pos_h[u * 4 + s] = packf2(pos[(2 * s) * 255 + u], pos[(2 * s + 1) * 255 + u]);
    }
    return;
  }
  if (blk == 29) {
    // vpxg[sel][rp][c12]: sel=0 (p even): (vp_c(253-2rp), vp_c(252-2rp))
    //                     sel=1 (p odd):  (vp_c(254-2rp), vp_c(253-2rp))
    for (int m = tid; m < 3072; m += 128) {
      int sel = m / 1536, rem = m % 1536, rp = rem / 12, c = rem % 12;
      unsigned val = 0;
      if (c < 8) {
        int ua = (sel ? 254 : 253) - 2 * rp;
        int ub = ua - 1;
        float fa = (ua >= 0) ? pos[(8 + c) * 255 + ua] : 0.f;
        float fb = (ub >= 0) ? pos[(8 + c) * 255 + ub] : 0.f;
        val = packf2(fa, fb);
      }
      vpxg[m] = val;
    }
    return;
  }
  __shared__ float r0[255], r1[255];
  int rowA, rowB, out;
  bool prod;
  if (blk < 4)       { rowA = blk;                 rowB = rowA;               out = blk * 128;              prod = false; }
  else if (blk < 14) { int m = blk - 4;  rowA = pair_c[m];     rowB = pair_cp[m];     out = 1024 + m * 128; prod = true; }
  else if (blk < 18) { rowA = 4 + (blk - 14);      rowB = rowA;               out = 512 + (blk - 14) * 128; prod = false; }
  else               { int m = blk - 18; rowA = 4 + pair_c[m]; rowB = 4 + pair_cp[m]; out = 2304 + m * 128; prod = true; }
  for (int u = tid; u < 255; u += 128) {
    r0[u] = pos[rowA * 255 + u];
    r1[u] = pos[rowB * 255 + u];
  }
  __syncthreads();
  float s = 0.f;
  if (prod) {
    for (int d = 0; d < 128; ++d) s += r0[tid + d] * r1[tid + d];
  } else {
    for (int d = 0; d < 128; ++d) s += r0[tid + d];
  }
  PT[out + tid] = s;
}

// ---------------- K3: att stats, 8 n per wave, no atomics -------------------
__global__ __launch_bounds__(256) void k3_stats(
    const unsigned* __restrict__ y2h, const float* __restrict__ PT,
    float* __restrict__ Pb3)
{
  const int W = blockIdx.x * 4 + (threadIdx.x >> 6);
  const int lane = threadIdx.x & 63;
  const int h = W & 7;
  const int n0 = (W >> 3) * 8;
  float Pq[4][2], Pk[4][2], Wq[10][2], Wk[10][2];
#pragma unroll
  for (int c = 0; c < 4; ++c) {
    Pq[c][0] = PT[c * 128 + lane];        Pq[c][1] = PT[c * 128 + 64 + lane];
    Pk[c][0] = PT[512 + c * 128 + lane];  Pk[c][1] = PT[512 + c * 128 + 64 + lane];
  }
#pragma unroll
  for (int m = 0; m < 10; ++m) {
    Wq[m][0] = PT[1024 + m * 128 + lane]; Wq[m][1] = PT[1024 + m * 128 + 64 + lane];
    Wk[m][0] = PT[2304 + m * 128 + lane]; Wk[m][1] = PT[2304 + m * 128 + 64 + lane];
  }
  float acc_qk = 0, acc_qkss = 0, acc_qr = 0, acc_qrss = 0, acc_kr = 0, acc_krss = 0;
  for (int t = 0; t < 8; ++t) {
    const unsigned* yb = y2h + (size_t)((n0 + t) * 8 + h) * 1024;
    float q[4][2], k[4][2];
#pragma unroll
    for (int pl = 0; pl < 2; ++pl) {
      half2_t ha = bch2(yb[pl * 128 + lane]);
      half2_t hb = bch2(yb[pl * 128 + 64 + lane]);
      q[2 * pl][0] = (float)ha[0]; q[2 * pl + 1][0] = (float)ha[1];
      q[2 * pl][1] = (float)hb[0]; q[2 * pl + 1][1] = (float)hb[1];
      half2_t hc = bch2(yb[(2 + pl) * 128 + lane]);
      half2_t hd = bch2(yb[(2 + pl) * 128 + 64 + lane]);
      k[2 * pl][0] = (float)hc[0]; k[2 * pl + 1][0] = (float)hc[1];
      k[2 * pl][1] = (float)hd[0]; k[2 * pl + 1][1] = (float)hd[1];
    }
#pragma unroll
    for (int c = 0; c < 4; ++c) {
      acc_qr += q[c][0] * Pq[c][0] + q[c][1] * Pq[c][1];
      acc_kr += k[c][0] * Pk[c][0] + k[c][1] * Pk[c][1];
    }
#pragma unroll
    for (int m = 0; m < 10; ++m) {
      int c = pair_c[m], cp = pair_cp[m];
      float mult = (c == cp) ? 1.f : 2.f;
      acc_qrss += mult * (q[c][0] * q[cp][0] * Wq[m][0] + q[c][1] * q[cp][1] * Wq[m][1]);
      acc_krss += mult * (k[c][0] * k[cp][0] * Wk[m][0] + k[c][1] * k[cp][1] * Wk[m][1]);
    }
    float vals[28];
#pragma unroll
    for (int c = 0; c < 4; ++c) {
      vals[c]     = q[c][0] + q[c][1];
      vals[4 + c] = k[c][0] + k[c][1];
    }
#pragma unroll
    for (int m = 0; m < 10; ++m) {
      int c = pair_c[m], cp = pair_cp[m];
      vals[8 + m]  = q[c][0] * q[cp][0] + q[c][1] * q[cp][1];
      vals[18 + m] = k[c][0] * k[cp][0] + k[c][1] * k[cp][1];
    }
#pragma unroll
    for (int v = 0; v < 28; ++v) {
      float tv = vals[v];
#pragma unroll
      for (int off = 1; off < 64; off <<= 1) tv += __shfl_xor(tv, off);
      vals[v] = tv;
    }
    float qk = 0, qkss = 0;
#pragma unroll
    for (int c = 0; c < 4; ++c) qk += vals[c] * vals[4 + c];
#pragma unroll
    for (int m = 0; m < 10; ++m) {
      float mult = (pair_c[m] == pair_cp[m]) ? 1.f : 2.f;
      qkss += mult * vals[8 + m] * vals[18 + m];
    }
    acc_qk += qk; acc_qkss += qkss;
  }
  float lin[4] = {acc_qr, acc_qrss, acc_kr, acc_krss};
#pragma unroll
  for (int v = 0; v < 4; ++v) {
    float tv = lin[v];
#pragma unroll
    for (int off = 1; off < 64; off <<= 1) tv += __shfl_xor(tv, off);
    lin[v] = tv;
  }
  if (lane == 0) {
    float* o = Pb3 + W * 6;
    o[0] = acc_qk; o[1] = acc_qkss;
    o[2] = lin[0]; o[3] = lin[1]; o[4] = lin[2]; o[5] = lin[3];
  }
}

// ---------------- KR1: reduce Pb3 + finalize att bn coefs (merged) ----------
__global__ __launch_bounds__(64) void kR1(
    const float* __restrict__ Pb3, float* __restrict__ S,
    const float* __restrict__ ga, const float* __restrict__ ba,
    const float* __restrict__ gqr, const float* __restrict__ gkr)
{
  __shared__ float sums[48];
  const int t = threadIdx.x;
  if (t < 48) {
    int h = t / 6, k = t % 6;
    float v = 0.f;
    for (int g = 0; g < 64; ++g) v += Pb3[(h + 8 * g) * 6 + k];
    sums[t] = v;
  }
  __syncthreads();
  if (t < 8) {
    const int h = t;
    const float inv = 1.f / 8388608.f;
    float gates[3] = {1.f, gqr[0], gkr[0]};
    float csum = 0.f;
#pragma unroll
    for (int g = 0; g < 3; ++g) {
      float mr = sums[h * 6 + 2 * g] * inv;
      float er = sums[h * 6 + 2 * g + 1] * inv;
      float gt = gates[g];
      float mean = gt * mr;
      float var = gt * gt * er - mean * mean;
      float sc = ga[g * 8 + h] * rsqrtf(var + EPS);
      S[560 + g * 8 + h] = gt * sc;
      csum += ba[g * 8 + h] - mean * sc;
    }
    S[584 + h] = csum;
  }
}

// ---------------- K5: pair-scores + ONLINE-MAX softmax + dot2 PV ------------
// 512 threads: p = tid>>2, isub = tid&3; 16 i-pairs per thread.
// e = exp(s - running_max) <= 1 always -> half pack can never overflow.
__global__ __launch_bounds__(512, 6) void k5_apply(
    const unsigned* __restrict__ y2h, const unsigned* __restrict__ pos_h,
    const unsigned* __restrict__ vpxg,
    float* __restrict__ S, _Float16* __restrict__ av, _Float16* __restrict__ avp,
    const float* __restrict__ gv_p, const float* __restrict__ gvp_p,
    float* __restrict__ Vbuf)
{
  __shared__ __align__(16) unsigned qkv_s[128][4];   // [l][q01,q23,k01,k23]
  __shared__ __align__(16) unsigned posm[255][4];    // [u][qp01,qp23,kp01,kp23]
  __shared__ __align__(16) unsigned vt[64][8];       // [i-pair][v ch 0..7]
  __shared__ __align__(16) unsigned vpx[2][128][12]; // [sel][rp][vp ch 0..7 +pad]
  __shared__ float red[8][4];
  const int h = blockIdx.x & 7, n = blockIdx.x >> 3;
  const int tid = threadIdx.x;
  const unsigned* yb = y2h + (size_t)(n * 8 + h) * 1024;
  {
    int l = tid >> 2, s = tid & 3;
    qkv_s[l][s] = yb[s * 128 + l];
  }
  {
    unsigned* pf = (unsigned*)posm;
    for (int m = tid; m < 1020; m += 512) pf[m] = pos_h[m];
  }
  {
    unsigned* pf = (unsigned*)vpx;
    for (int m = tid; m < 3072; m += 512) pf[m] = vpxg[m];
  }
  if (tid < 256) {
    int s = tid & 3, jp = tid >> 2;
    unsigned a0 = yb[(4 + s) * 128 + 2 * jp];
    unsigned a1 = yb[(4 + s) * 128 + 2 * jp + 1];
    vt[jp][2 * s]     = (a0 & 0xffffu) | (a1 << 16);
    vt[jp][2 * s + 1] = (a0 >> 16) | (a1 & 0xffff0000u);
  }
  __syncthreads();

  const int p = tid >> 2, isub = tid & 3;
  uint2 qk2 = *(const uint2*)&qkv_s[p][0];
  uint2 kown = *(const uint2*)&qkv_s[p][2];
  const half2_t q01 = bch2(qk2.x), q23 = bch2(qk2.y);
  const half2_t k01o = bch2(kown.x), k23o = bch2(kown.y);
  const float C0 = S[560 + h], C1 = S[568 + h], C2 = S[576 + h], C3v = S[584 + h];
  const unsigned* vprow = &vpx[p & 1][63 - (p >> 1)][0];

  float mcur = -1e30f;
  float sum = 0.f;
  float accv[8], accvp[8];
#pragma unroll
  for (int c = 0; c < 8; ++c) { accv[c] = 0.f; accvp[c] = 0.f; }

#pragma unroll 4
  for (int j = 0; j < 16; ++j) {
    const int jp = isub + 4 * j;
    const int i0 = 2 * jp;
    const int u0 = p - i0 + 127;
    uint2 ka = *(const uint2*)&qkv_s[i0][2];
    uint2 kb = *(const uint2*)&qkv_s[i0 + 1][2];
    uint4 pa = *(const uint4*)&posm[u0][0];
    uint4 pb = *(const uint4*)&posm[u0 - 1][0];
    float aa0 = fdot2(q23, bch2(ka.y), fdot2(q01, bch2(ka.x), 0.f));
    float bq0 = fdot2(q23, bch2(pa.y), fdot2(q01, bch2(pa.x), 0.f));
    float ckA = fdot2(k23o, bch2(pa.w), fdot2(k01o, bch2(pa.z), 0.f));
    float aa1 = fdot2(q23, bch2(kb.y), fdot2(q01, bch2(kb.x), 0.f));
    float bq1 = fdot2(q23, bch2(pb.y), fdot2(q01, bch2(pb.x), 0.f));
    float ckB = fdot2(k23o, bch2(pb.w), fdot2(k01o, bch2(pb.z), 0.f));
    float s0 = aa0 * C0 + bq0 * C1 + ckA * C2 + C3v;
    float s1 = aa1 * C0 + bq1 * C1 + ckB * C2 + C3v;
    // online max: keep e <= 1 always
    float mp = fmaxf(s0, s1);
    if (mp > mcur) {
      float r = __expf(mcur - mp);
      mcur = mp;
      sum *= r;
#pragma unroll
      for (int c = 0; c < 8; ++c) { accv[c] *= r; accvp[c] *= r; }
    }
    float e0 = __expf(s0 - mcur);
    float e1 = __expf(s1 - mcur);
    sum += e0 + e1;
    const half2_t e2 = bch2(packf2(e0, e1));
    uint4 va = *(const uint4*)&vt[jp][0];
    uint4 vb = *(const uint4*)&vt[jp][4];
    const unsigned* wr = vprow + jp * 12;
    uint4 wa = *(const uint4*)wr;
    uint4 wb = *(const uint4*)(wr + 4);
    accv[0] = fdot2(e2, bch2(va.x), accv[0]);
    accv[1] = fdot2(e2, bch2(va.y), accv[1]);
    accv[2] = fdot2(e2, bch2(va.z), accv[2]);
    accv[3] = fdot2(e2, bch2(va.w), accv[3]);
    accv[4] = fdot2(e2, bch2(vb.x), accv[4]);
    accv[5] = fdot2(e2, bch2(vb.y), accv[5]);
    accv[6] = fdot2(e2, bch2(vb.z), accv[6]);
    accv[7] = fdot2(e2, bch2(vb.w), accv[7]);
    accvp[0] = fdot2(e2, bch2(wa.x), accvp[0]);
    accvp[1] = fdot2(e2, bch2(wa.y), accvp[1]);
    accvp[2] = fdot2(e2, bch2(wa.z), accvp[2]);
    accvp[3] = fdot2(e2, bch2(wa.w), accvp[3]);
    accvp[4] = fdot2(e2, bch2(wb.x), accvp[4]);
    accvp[5] = fdot2(e2, bch2(wb.y), accvp[5]);
    accvp[6] = fdot2(e2, bch2(wb.z), accvp[6]);
    accvp[7] = fdot2(e2, bch2(wb.w), accvp[7]);
  }
  // reconcile the 4 lanes' running maxes, then reduce
  float M = fmaxf(mcur, __shfl_xor(mcur, 1));
  M = fmaxf(M, __shfl_xor(M, 2));
  {
    float r = __expf(mcur - M);
    sum *= r;
#pragma unroll
    for (int c = 0; c < 8; ++c) { accv[c] *= r; accvp[c] *= r; }
  }
  sum += __shfl_xor(sum, 1);
  sum += __shfl_xor(sum, 2);
#pragma unroll
  for (int c = 0; c < 8; ++c) {
    accv[c]  += __shfl_xor(accv[c], 1);  accv[c]  += __shfl_xor(accv[c], 2);
    accvp[c] += __shfl_xor(accvp[c], 1); accvp[c] += __shfl_xor(accvp[c], 2);
  }

  float sv = 0, ssv = 0, svp = 0, ssvp = 0;
  if (isub == 0) {
    const float fv = gv_p[0] / sum, fp2 = gvp_p[0] / sum;
    size_t base = ((size_t)(n * 8 + h) * 8) * 128 + p;
#pragma unroll
    for (int c = 0; c < 8; ++c) {
      float x1 = accv[c] * fv;
      float x2 = accvp[c] * fp2;
      av [base + c * 128] = (_Float16)x1;
      avp[base + c * 128] = (_Float16)x2;
      sv += x1; ssv += x1 * x1; svp += x2; ssvp += x2 * x2;
    }
  }
  float vals[4] = {sv, ssv, svp, ssvp};
#pragma unroll
  for (int kk = 0; kk < 4; ++kk) {
    float v = vals[kk];
#pragma unroll
    for (int off = 1; off < 64; off <<= 1) v += __shfl_xor(v, off);
    vals[kk] = v;
  }
  const int wid = tid >> 6, lane = tid & 63;
  if (lane == 0) {
#pragma unroll
    for (int kk = 0; kk < 4; ++kk) red[wid][kk] = vals[kk];
  }
  __syncthreads();
  if (tid == 0) {
    float t0 = 0, t1 = 0, t2 = 0, t3 = 0;
#pragma unroll
    for (int w = 0; w < 8; ++w) {
      t0 += red[w][0]; t1 += red[w][1]; t2 += red[w][2]; t3 += red[w][3];
    }
    float* o = Vbuf + (size_t)blockIdx.x * 4;
    o[0] = t0; o[1] = t1; o[2] = t2; o[3] = t3;
  }
}

// ---------------- KR2: reduce Vbuf + finalize v bn (merged) -----------------
__global__ __launch_bounds__(512) void kR2(
    const float* __restrict__ Vbuf, float* __restrict__ S,
    const float* __restrict__ gv, const float* __restrict__ bv)
{
  __shared__ float part[32][17];
  const int t = threadIdx.x;
  const int col = t >> 4, sub = t & 15;      // col = k*8+h
  const int k = col >> 3, h = col & 7;
  float v = 0.f;
  for (int m = 0; m < 32; ++m) {
    int n = sub + 16 * m;
    v += Vbuf[(size_t)(n * 8 + h) * 4 + k];
  }
  part[col][sub] = v;
  __syncthreads();
  if (t < 32) {
    float s = 0.f;
#pragma unroll
    for (int j = 0; j < 16; ++j) s += part[t][j];
    part[t][16] = s;
  }
  __syncthreads();
  if (t < 8) {
    const int hh = t;
    const float inv = 1.f / 524288.f;
    float m1 = part[0 * 8 + hh][16] * inv;
    float e1 = part[1 * 8 + hh][16] * inv;
    float var = e1 - m1 * m1;
    float sc = gv[hh] * rsqrtf(var + EPS);
    S[624 + hh] = sc;
    S[632 + hh] = bv[hh] - m1 * sc;
    float m2 = part[2 * 8 + hh][16] * inv;
    float e2 = part[3 * 8 + hh][16] * inv;
    var = e2 - m2 * m2;
    sc = gv[8 + hh] * rsqrtf(var + EPS);
    S[640 + hh] = sc;
    S[648 + hh] = bv[8 + hh] - m2 * sc;
  }
}

// ---------------- K7: bn apply + sum halves + LDS-tiled transpose out -------
__global__ __launch_bounds__(256) void k7_out(
    const _Float16* __restrict__ av, const _Float16* __restrict__ avp,
    const float* __restrict__ S, float* __restrict__ out)
{
  __shared__ float tile[64][129];
  const int wt = blockIdx.x & 1;
  const int d  = (blockIdx.x >> 1) & 63;
  const int b  = blockIdx.x >> 7;
  const int h = d >> 3, c = d & 7;
  const float scv = S[624 + h], shv = S[632 + h];
  const float scp = S[640 + h], shp = S[648 + h];
  const int tid = threadIdx.x;
  for (int idx = tid; idx < 8192; idx += 256) {
    int wl = idx >> 7, pp = idx & 127;
    int n = b * 128 + wt * 64 + wl;
    size_t base = (((size_t)n * 8 + h) * 8 + c) * 128 + pp;
    tile[wl][pp] = (float)av[base] * scv + shv + (float)avp[base] * scp + shp;
  }
  __syncthreads();
  for (int idx = tid; idx < 8192; idx += 256) {
    int pp = idx >> 6, wl = idx & 63;
    out[(((size_t)b * 64 + d) * 128 + pp) * 128 + wt * 64 + wl] = tile[wl][pp];
  }
}

// ---------------- launch ----------------------------------------------------
extern "C" void kernel_launch(void* const* d_in, const int* in_sizes, int n_in,
                              void* d_out, int out_size, void* d_ws, size_t ws_size,
                              hipStream_t stream)
{
  const float* x   = (const float*)d_in[0];
  const float* wq  = (const float*)d_in[1];
  const float* g1  = (const float*)d_in[2];
  const float* b1  = (const float*)d_in[3];
  const float* pos = (const float*)d_in[4];
  const float* gqr = (const float*)d_in[5];
  const float* gkr = (const float*)d_in[6];
  const float* gvp = (const float*)d_in[7];
  const float* gv  = (const float*)d_in[8];
  const float* ga  = (const float*)d_in[9];
  const float* ba  = (const float*)d_in[10];
  const float* gv2 = (const float*)d_in[11];
  const float* bv2 = (const float*)d_in[12];

  float* ws = (float*)d_ws;
  _Float16* y1h   = (_Float16*)ws;
  _Float16* av    = (_Float16*)ws;
  _Float16* avp   = (_Float16*)ws + 4194304;
  float*    Pb3   = ws + 4200000;
  float*    Vbuf  = ws + 4250000;
  float*    Pbuf  = ws + 8388608;
  unsigned* y2h   = (unsigned*)(ws + 8388608);
  float*    S     = ws + 16777216;
  unsigned* pos_h = (unsigned*)(ws + 16778240);
  float*    PT    = ws + 16781312;
  unsigned* vpxg  = (unsigned*)(ws + 16785000);
  float*    out   = (float*)d_out;

  k0_pos<<<30, 128, 0, stream>>>(pos, PT, pos_h, vpxg);
  k1_gemm<<<512, 256, 0, stream>>>(x, wq, y1h, Pbuf);
  k2_bn1<<<128, 64, 0, stream>>>(Pbuf, S, g1, b1);
  k_tr<<<256, 256, 0, stream>>>(y1h, S, y2h);
  k3_stats<<<128, 256, 0, stream>>>(y2h, PT, Pb3);
  kR1<<<1, 64, 0, stream>>>(Pb3, S, ga, ba, gqr, gkr);
  k5_apply<<<4096, 512, 0, stream>>>(y2h, pos_h, vpxg, S, av, avp, gv, gvp, Vbuf);
  kR2<<<1, 512, 0, stream>>>(Vbuf, S, gv2, bv2);
  k7_out<<<512, 256, 0, stream>>>(av, avp, S, out);
}

// Round 11
// 209.922 us; speedup vs baseline: 3.2529x; 1.0277x over previous
//
#include <hip/hip_runtime.h>
#include <hip/hip_fp16.h>

#define EPS 1e-5f

// Problem constants: B=4, C=64, H=128, W=128, N=512, OP2=128, HEAD=8, HP=16
// qk_dim=4, v_dim=8

// workspace layout (float offsets)
//  y1h: (b,l,o,w) half, 8,388,608 halves at 0    [dead after k_tr]
//  av : (n,h,c,p) half, 4,194,304 halves at 0    (k5 writes; y1h region)
//  avp: (n,h,c,p) half at float-offset 2,097,152
//  Pb3: k3 partials 512*6 f32 at 4,200,000
//  Vbuf: k5 partials 4096*4 f32 at 4,250,000
//  Pbuf: k1 partials 512*256 f32 at 4,300,000    (y1h-upper free zone; read by k_tr)
//  y2h: (n,h,slot,l) packed half2 per uint, 1,048,576 uints at 8,388,608
//       slot: 0 q01 1 q23 2 k01 3 k23 4 v01 5 v23 6 v45 7 v67 (BN applied)
//  S  : stats 1024 f32 at 16,777,216
//  pos_h: packed qk-pos [u=0..254][4 uints] at 16,778,240 (1020 uints)
//  PT : f32 window tables at 16,781,312 (3584)
//  vpxg: reversed/parity-split vp pairs, 3072 uints at 16,785,000

typedef _Float16 half2_t __attribute__((ext_vector_type(2)));

__device__ __constant__ int pair_c [10] = {0,0,0,0,1,1,1,2,2,3};
__device__ __constant__ int pair_cp[10] = {0,1,2,3,1,2,3,2,3,3};

__device__ inline float fdot2(half2_t a, half2_t b, float c) {
#if __has_builtin(__builtin_amdgcn_fdot2)
  return __builtin_amdgcn_fdot2(a, b, c, false);
#else
  return c + (float)a[0] * (float)b[0] + (float)a[1] * (float)b[1];
#endif
}
__device__ inline half2_t bch2(unsigned u) {
  union { unsigned u; half2_t h; } x; x.u = u; return x.h;
}
__device__ inline unsigned packf2(float a, float b) {
  half2_t h; h[0] = (_Float16)a; h[1] = (_Float16)b;
  union { unsigned u; half2_t h; } x; x.h = h; return x.u;
}

// ---------------- K1: qkv GEMM + relu + bn1 partials; y1 stored HALF --------
__global__ __launch_bounds__(256) void k1_gemm(
    const float* __restrict__ x, const float* __restrict__ wq,
    _Float16* __restrict__ y1h, float* __restrict__ Pbuf)
{
  __shared__ float xs[64][132];
  const int b = blockIdx.x >> 7, l = blockIdx.x & 127;
  const int tid = threadIdx.x;
  const float* xp = x + (size_t)b * 1048576 + (size_t)l * 128;
  for (int idx = tid; idx < 2048; idx += 256) {
    int c = idx >> 5, w4 = (idx & 31) * 4;
    *(float4*)&xs[c][w4] = *(const float4*)&xp[c * 16384 + w4];
  }
  __syncthreads();
  const int ty = tid >> 4, tx = tid & 15;
  const int o0 = ty * 8, w0 = tx * 4;
  float acc[8][8];
#pragma unroll
  for (int u = 0; u < 8; ++u)
#pragma unroll
    for (int v = 0; v < 8; ++v) acc[u][v] = 0.f;

  for (int c4 = 0; c4 < 64; c4 += 4) {
    float wr[8][4];
#pragma unroll
    for (int u = 0; u < 8; ++u)
      *(float4*)&wr[u][0] = *(const float4*)&wq[(o0 + u) * 64 + c4];
#pragma unroll
    for (int dc = 0; dc < 4; ++dc) {
      float4 xa = *(const float4*)&xs[c4 + dc][w0];
      float4 xb = *(const float4*)&xs[c4 + dc][w0 + 64];
#pragma unroll
      for (int u = 0; u < 8; ++u) {
        float wv = wr[u][dc];
        acc[u][0] += wv * xa.x; acc[u][1] += wv * xa.y;
        acc[u][2] += wv * xa.z; acc[u][3] += wv * xa.w;
        acc[u][4] += wv * xb.x; acc[u][5] += wv * xb.y;
        acc[u][6] += wv * xb.z; acc[u][7] += wv * xb.w;
      }
    }
  }
  _Float16* y1p = y1h + (size_t)(b * 128 + l) * 16384;
#pragma unroll
  for (int u = 0; u < 8; ++u) {
#pragma unroll
    for (int v = 0; v < 8; ++v) acc[u][v] = fmaxf(acc[u][v], 0.f);
    uint2 pa, pb;
    pa.x = packf2(acc[u][0], acc[u][1]); pa.y = packf2(acc[u][2], acc[u][3]);
    pb.x = packf2(acc[u][4], acc[u][5]); pb.y = packf2(acc[u][6], acc[u][7]);
    *(uint2*)&y1p[(o0 + u) * 128 + w0] = pa;
    *(uint2*)&y1p[(o0 + u) * 128 + w0 + 64] = pb;
    float s  = acc[u][0] + acc[u][1] + acc[u][2] + acc[u][3]
             + acc[u][4] + acc[u][5] + acc[u][6] + acc[u][7];
    float ss = acc[u][0]*acc[u][0] + acc[u][1]*acc[u][1] + acc[u][2]*acc[u][2]
             + acc[u][3]*acc[u][3] + acc[u][4]*acc[u][4] + acc[u][5]*acc[u][5]
             + acc[u][6]*acc[u][6] + acc[u][7]*acc[u][7];
#pragma unroll
    for (int off = 1; off < 16; off <<= 1) {
      s  += __shfl_xor(s, off);
      ss += __shfl_xor(ss, off);
    }
    if (tx == 0) {
      Pbuf[blockIdx.x * 256 + o0 + u] = s;
      Pbuf[blockIdx.x * 256 + 128 + o0 + u] = ss;
    }
  }
}

// ---------------- K_tr: y1h -> y2h (BN stats reduced in-block, applied) -----
// block = (b, s=o-pair 0..63); grid 256; also replaces the old k2 kernel
__global__ __launch_bounds__(256) void k_tr(
    const _Float16* __restrict__ y1h, const float* __restrict__ Pbuf,
    const float* __restrict__ g1, const float* __restrict__ b1,
    unsigned* __restrict__ y2h)
{
  __shared__ _Float16 th[2][64][134];
  __shared__ float scsh[4];
  const int s = blockIdx.x & 63, b = blockIdx.x >> 6;
  const int h = s >> 3, slot = s & 7;
  const int o0 = 2 * s, o1 = 2 * s + 1;
  const int tid = threadIdx.x;
  // in-block reduction of bn1 stats for channels o0, o1
  {
    int r = tid >> 6, lane = tid & 63;  // r: 0 sum(o0) 1 sum(o1) 2 ss(o0) 3 ss(o1)
    int row = ((r & 1) ? o1 : o0) + (r >> 1) * 128;
    float a = 0.f;
#pragma unroll
    for (int m = 0; m < 8; ++m) a += Pbuf[(lane + 64 * m) * 256 + row];
#pragma unroll
    for (int off = 1; off < 64; off <<= 1) a += __shfl_xor(a, off);
    if (lane == 0) scsh[r] = a;
  }
  __syncthreads();
  const float inv = 1.f / 65536.f;
  const float m0 = scsh[0] * inv, v0 = scsh[2] * inv - m0 * m0;
  const float m1 = scsh[1] * inv, v1 = scsh[3] * inv - m1 * m1;
  const float sc0 = g1[o0] * rsqrtf(v0 + EPS), sh0 = b1[o0] - m0 * sc0;
  const float sc1 = g1[o1] * rsqrtf(v1 + EPS), sh1 = b1[o1] - m1 * sc1;
  for (int lh = 0; lh < 2; ++lh) {
    const int l0 = lh * 64;
    for (int idx = tid; idx < 4096; idx += 256) {
      int ll = idx >> 6, wp = idx & 63;
      size_t base = ((size_t)(b * 128 + l0 + ll) * 128) * 128 + 2 * wp;
      unsigned a0 = *(const unsigned*)&y1h[base + (size_t)o0 * 128];
      unsigned a1 = *(const unsigned*)&y1h[base + (size_t)o1 * 128];
      half2_t ha = bch2(a0), hb = bch2(a1);
      *(unsigned*)&th[0][ll][2 * wp] =
          packf2((float)ha[0] * sc0 + sh0, (float)ha[1] * sc0 + sh0);
      *(unsigned*)&th[1][ll][2 * wp] =
          packf2((float)hb[0] * sc1 + sh1, (float)hb[1] * sc1 + sh1);
    }
    __syncthreads();
    for (int idx = tid; idx < 8192; idx += 256) {
      int w = idx >> 6, ll = idx & 63;
      unsigned pk;
      { half2_t hh; hh[0] = th[0][ll][w]; hh[1] = th[1][ll][w];
        union { unsigned u; half2_t h; } xx; xx.h = hh; pk = xx.u; }
      y2h[((size_t)((b * 128 + w) * 8 + h) * 8 + slot) * 128 + l0 + ll] = pk;
    }
    __syncthreads();
  }
}

// ---------------- K0: PT tables + packed qk-pos + vpx tables ----------------
// blocks 0..3: Pq, 4..13: Wq, 14..17: Pk, 18..27: Wk, 28: pos_h, 29: vpxg
__global__ __launch_bounds__(128) void k0_pos(const float* __restrict__ pos,
                                              float* __restrict__ PT,
                                              unsigned* __restrict__ pos_h,
                                              unsigned* __restrict__ vpxg)
{
  const int blk = blockIdx.x, tid = threadIdx.x;
  if (blk == 28) {
    for (int u = tid; u < 255; u += 128) {
#pragma unroll
      for (int s = 0; s < 4; ++s)
        pos_h[u * 4 + s] = packf2(pos[(2 * s) * 255 + u], pos[(2 * s + 1) * 255 + u]);
    }
    return;
  }
  if (blk == 29) {
    for (int m = tid; m < 3072; m += 128) {
      int sel = m / 1536, rem = m % 1536, rp = rem / 12, c = rem % 12;
      unsigned val = 0;
      if (c < 8) {
        int ua = (sel ? 254 : 253) - 2 * rp;
        int ub = ua - 1;
        float fa = (ua >= 0) ? pos[(8 + c) * 255 + ua] : 0.f;
        float fb = (ub >= 0) ? pos[(8 + c) * 255 + ub] : 0.f;
        val = packf2(fa, fb);
      }
      vpxg[m] = val;
    }
    return;
  }
  __shared__ float r0[255], r1[255];
  int rowA, rowB, out;
  bool prod;
  if (blk < 4)       { rowA = blk;                 rowB = rowA;               out = blk * 128;              prod = false; }
  else if (blk < 14) { int m = blk - 4;  rowA = pair_c[m];     rowB = pair_cp[m];     out = 1024 + m * 128; prod = true; }
  else if (blk < 18) { rowA = 4 + (blk - 14);      rowB = rowA;               out = 512 + (blk - 14) * 128; prod = false; }
  else               { int m = blk - 18; rowA = 4 + pair_c[m]; rowB = 4 + pair_cp[m]; out = 2304 + m * 128; prod = true; }
  for (int u = tid; u < 255; u += 128) {
    r0[u] = pos[rowA * 255 + u];
    r1[u] = pos[rowB * 255 + u];
  }
  __syncthreads();
  float s = 0.f;
  if (prod) {
    for (int d = 0; d < 128; ++d) s += r0[tid + d] * r1[tid + d];
  } else {
    for (int d = 0; d < 128; ++d) s += r0[tid + d];
  }
  PT[out + tid] = s;
}

// ---------------- K3: att stats, 8 n per wave, no atomics -------------------
__global__ __launch_bounds__(256) void k3_stats(
    const unsigned* __restrict__ y2h, const float* __restrict__ PT,
    float* __restrict__ Pb3)
{
  const int W = blockIdx.x * 4 + (threadIdx.x >> 6);
  const int lane = threadIdx.x & 63;
  const int h = W & 7;
  const int n0 = (W >> 3) * 8;
  float Pq[4][2], Pk[4][2], Wq[10][2], Wk[10][2];
#pragma unroll
  for (int c = 0; c < 4; ++c) {
    Pq[c][0] = PT[c * 128 + lane];        Pq[c][1] = PT[c * 128 + 64 + lane];
    Pk[c][0] = PT[512 + c * 128 + lane];  Pk[c][1] = PT[512 + c * 128 + 64 + lane];
  }
#pragma unroll
  for (int m = 0; m < 10; ++m) {
    Wq[m][0] = PT[1024 + m * 128 + lane]; Wq[m][1] = PT[1024 + m * 128 + 64 + lane];
    Wk[m][0] = PT[2304 + m * 128 + lane]; Wk[m][1] = PT[2304 + m * 128 + 64 + lane];
  }
  float acc_qk = 0, acc_qkss = 0, acc_qr = 0, acc_qrss = 0, acc_kr = 0, acc_krss = 0;
  for (int t = 0; t < 8; ++t) {
    const unsigned* yb = y2h + (size_t)((n0 + t) * 8 + h) * 1024;
    float q[4][2], k[4][2];
#pragma unroll
    for (int pl = 0; pl < 2; ++pl) {
      half2_t ha = bch2(yb[pl * 128 + lane]);
      half2_t hb = bch2(yb[pl * 128 + 64 + lane]);
      q[2 * pl][0] = (float)ha[0]; q[2 * pl + 1][0] = (float)ha[1];
      q[2 * pl][1] = (float)hb[0]; q[2 * pl + 1][1] = (float)hb[1];
      half2_t hc = bch2(yb[(2 + pl) * 128 + lane]);
      half2_t hd = bch2(yb[(2 + pl) * 128 + 64 + lane]);
      k[2 * pl][0] = (float)hc[0]; k[2 * pl + 1][0] = (float)hc[1];
      k[2 * pl][1] = (float)hd[0]; k[2 * pl + 1][1] = (float)hd[1];
    }
#pragma unroll
    for (int c = 0; c < 4; ++c) {
      acc_qr += q[c][0] * Pq[c][0] + q[c][1] * Pq[c][1];
      acc_kr += k[c][0] * Pk[c][0] + k[c][1] * Pk[c][1];
    }
#pragma unroll
    for (int m = 0; m < 10; ++m) {
      int c = pair_c[m], cp = pair_cp[m];
      float mult = (c == cp) ? 1.f : 2.f;
      acc_qrss += mult * (q[c][0] * q[cp][0] * Wq[m][0] + q[c][1] * q[cp][1] * Wq[m][1]);
      acc_krss += mult * (k[c][0] * k[cp][0] * Wk[m][0] + k[c][1] * k[cp][1] * Wk[m][1]);
    }
    float vals[28];
#pragma unroll
    for (int c = 0; c < 4; ++c) {
      vals[c]     = q[c][0] + q[c][1];
      vals[4 + c] = k[c][0] + k[c][1];
    }
#pragma unroll
    for (int m = 0; m < 10; ++m) {
      int c = pair_c[m], cp = pair_cp[m];
      vals[8 + m]  = q[c][0] * q[cp][0] + q[c][1] * q[cp][1];
      vals[18 + m] = k[c][0] * k[cp][0] + k[c][1] * k[cp][1];
    }
#pragma unroll
    for (int v = 0; v < 28; ++v) {
      float tv = vals[v];
#pragma unroll
      for (int off = 1; off < 64; off <<= 1) tv += __shfl_xor(tv, off);
      vals[v] = tv;
    }
    float qk = 0, qkss = 0;
#pragma unroll
    for (int c = 0; c < 4; ++c) qk += vals[c] * vals[4 + c];
#pragma unroll
    for (int m = 0; m < 10; ++m) {
      float mult = (pair_c[m] == pair_cp[m]) ? 1.f : 2.f;
      qkss += mult * vals[8 + m] * vals[18 + m];
    }
    acc_qk += qk; acc_qkss += qkss;
  }
  float lin[4] = {acc_qr, acc_qrss, acc_kr, acc_krss};
#pragma unroll
  for (int v = 0; v < 4; ++v) {
    float tv = lin[v];
#pragma unroll
    for (int off = 1; off < 64; off <<= 1) tv += __shfl_xor(tv, off);
    lin[v] = tv;
  }
  if (lane == 0) {
    float* o = Pb3 + W * 6;
    o[0] = acc_qk; o[1] = acc_qkss;
    o[2] = lin[0]; o[3] = lin[1]; o[4] = lin[2]; o[5] = lin[3];
  }
}

// ---------------- KR1: reduce Pb3 + finalize att bn coefs (merged) ----------
__global__ __launch_bounds__(64) void kR1(
    const float* __restrict__ Pb3, float* __restrict__ S,
    const float* __restrict__ ga, const float* __restrict__ ba,
    const float* __restrict__ gqr, const float* __restrict__ gkr)
{
  __shared__ float sums[48];
  const int t = threadIdx.x;
  if (t < 48) {
    int h = t / 6, k = t % 6;
    float v = 0.f;
    for (int g = 0; g < 64; ++g) v += Pb3[(h + 8 * g) * 6 + k];
    sums[t] = v;
  }
  __syncthreads();
  if (t < 8) {
    const int h = t;
    const float inv = 1.f / 8388608.f;
    float gates[3] = {1.f, gqr[0], gkr[0]};
    float csum = 0.f;
#pragma unroll
    for (int g = 0; g < 3; ++g) {
      float mr = sums[h * 6 + 2 * g] * inv;
      float er = sums[h * 6 + 2 * g + 1] * inv;
      float gt = gates[g];
      float mean = gt * mr;
      float var = gt * gt * er - mean * mean;
      float sc = ga[g * 8 + h] * rsqrtf(var + EPS);
      S[560 + g * 8 + h] = gt * sc;
      csum += ba[g * 8 + h] - mean * sc;
    }
    S[584 + h] = csum;
  }
}

// ---------------- K5: fully-unrolled 2-pair groups, online-max, dot2 PV -----
// 512 threads: p = tid>>2, isub = tid&3; 8 groups x 2 pairs per thread.
// Full unroll -> all LDS addresses are base + compile-time offset.
__global__ __launch_bounds__(512, 6) void k5_apply(
    const unsigned* __restrict__ y2h, const unsigned* __restrict__ pos_h,
    const unsigned* __restrict__ vpxg,
    float* __restrict__ S, _Float16* __restrict__ av, _Float16* __restrict__ avp,
    const float* __restrict__ gv_p, const float* __restrict__ gvp_p,
    float* __restrict__ Vbuf)
{
  __shared__ __align__(16) unsigned qkv_s[128][4];   // [l][q01,q23,k01,k23]
  __shared__ __align__(16) unsigned posm[255][4];    // [u][qp01,qp23,kp01,kp23]
  __shared__ __align__(16) unsigned vt[64][8];       // [i-pair][v ch 0..7]
  __shared__ __align__(16) unsigned vpx[2][128][12]; // [sel][rp][vp ch 0..7 +pad]
  __shared__ float red[8][4];
  const int h = blockIdx.x & 7, n = blockIdx.x >> 3;
  const int tid = threadIdx.x;
  const unsigned* yb = y2h + (size_t)(n * 8 + h) * 1024;
  {
    int l = tid >> 2, s = tid & 3;
    qkv_s[l][s] = yb[s * 128 + l];
  }
  {
    unsigned* pf = (unsigned*)posm;
    for (int m = tid; m < 1020; m += 512) pf[m] = pos_h[m];
  }
  {
    unsigned* pf = (unsigned*)vpx;
    for (int m = tid; m < 3072; m += 512) pf[m] = vpxg[m];
  }
  if (tid < 256) {
    int s = tid & 3, jp = tid >> 2;
    unsigned a0 = yb[(4 + s) * 128 + 2 * jp];
    unsigned a1 = yb[(4 + s) * 128 + 2 * jp + 1];
    vt[jp][2 * s]     = (a0 & 0xffffu) | (a1 << 16);
    vt[jp][2 * s + 1] = (a0 >> 16) | (a1 & 0xffff0000u);
  }
  __syncthreads();

  const int p = tid >> 2, isub = tid & 3;
  uint2 qk2 = *(const uint2*)&qkv_s[p][0];
  uint2 kown = *(const uint2*)&qkv_s[p][2];
  const half2_t q01 = bch2(qk2.x), q23 = bch2(qk2.y);
  const half2_t k01o = bch2(kown.x), k23o = bch2(kown.y);
  const float C0 = S[560 + h], C1 = S[568 + h], C2 = S[576 + h], C3v = S[584 + h];
  const unsigned* vprow = &vpx[p & 1][63 - (p >> 1)][0];
  const half2_t one2 = bch2(packf2(1.f, 1.f));

  float mcur = -1e30f;
  float sum = 0.f;
  float accv[8], accvp[8];
#pragma unroll
  for (int c = 0; c < 8; ++c) { accv[c] = 0.f; accvp[c] = 0.f; }

#pragma unroll
  for (int jj = 0; jj < 8; ++jj) {
    const int jpA = isub + 8 * jj;
    const int jpB = jpA + 4;
    const int i0A = 2 * jpA, i0B = 2 * jpB;
    const int uA = p - i0A + 127;
    const int uB = uA - 8;
    uint2 kaA = *(const uint2*)&qkv_s[i0A][2];
    uint2 kbA = *(const uint2*)&qkv_s[i0A + 1][2];
    uint2 kaB = *(const uint2*)&qkv_s[i0B][2];
    uint2 kbB = *(const uint2*)&qkv_s[i0B + 1][2];
    uint4 paA = *(const uint4*)&posm[uA][0];
    uint4 pbA = *(const uint4*)&posm[uA - 1][0];
    uint4 paB = *(const uint4*)&posm[uB][0];
    uint4 pbB = *(const uint4*)&posm[uB - 1][0];
    float s0 = fdot2(q23, bch2(kaA.y), fdot2(q01, bch2(kaA.x), 0.f)) * C0
             + fdot2(q23, bch2(paA.y), fdot2(q01, bch2(paA.x), 0.f)) * C1
             + fdot2(k23o, bch2(paA.w), fdot2(k01o, bch2(paA.z), 0.f)) * C2 + C3v;
    float s1 = fdot2(q23, bch2(kbA.y), fdot2(q01, bch2(kbA.x), 0.f)) * C0
             + fdot2(q23, bch2(pbA.y), fdot2(q01, bch2(pbA.x), 0.f)) * C1
             + fdot2(k23o, bch2(pbA.w), fdot2(k01o, bch2(pbA.z), 0.f)) * C2 + C3v;
    float s2 = fdot2(q23, bch2(kaB.y), fdot2(q01, bch2(kaB.x), 0.f)) * C0
             + fdot2(q23, bch2(paB.y), fdot2(q01, bch2(paB.x), 0.f)) * C1
             + fdot2(k23o, bch2(paB.w), fdot2(k01o, bch2(paB.z), 0.f)) * C2 + C3v;
    float s3 = fdot2(q23, bch2(kbB.y), fdot2(q01, bch2(kbB.x), 0.f)) * C0
             + fdot2(q23, bch2(pbB.y), fdot2(q01, bch2(pbB.x), 0.f)) * C1
             + fdot2(k23o, bch2(pbB.w), fdot2(k01o, bch2(pbB.z), 0.f)) * C2 + C3v;
    float mp = fmaxf(fmaxf(s0, s1), fmaxf(s2, s3));
    if (mp > mcur) {
      float r = __expf(mcur - mp);
      mcur = mp;
      sum *= r;
#pragma unroll
      for (int c = 0; c < 8; ++c) { accv[c] *= r; accvp[c] *= r; }
    }
    float e0 = __expf(s0 - mcur);
    float e1 = __expf(s1 - mcur);
    float e2f = __expf(s2 - mcur);
    float e3f = __expf(s3 - mcur);
    const half2_t eA = bch2(packf2(e0, e1));
    const half2_t eB = bch2(packf2(e2f, e3f));
    sum = fdot2(eB, one2, fdot2(eA, one2, sum));
    uint4 vaA = *(const uint4*)&vt[jpA][0];
    uint4 vbA = *(const uint4*)&vt[jpA][4];
    uint4 vaB = *(const uint4*)&vt[jpB][0];
    uint4 vbB = *(const uint4*)&vt[jpB][4];
    const unsigned* wrA = vprow + jpA * 12;
    const unsigned* wrB = vprow + jpB * 12;
    uint4 waA = *(const uint4*)wrA;
    uint4 wbA = *(const uint4*)(wrA + 4);
    uint4 waB = *(const uint4*)wrB;
    uint4 wbB = *(const uint4*)(wrB + 4);
    accv[0] = fdot2(eB, bch2(vaB.x), fdot2(eA, bch2(vaA.x), accv[0]));
    accv[1] = fdot2(eB, bch2(vaB.y), fdot2(eA, bch2(vaA.y), accv[1]));
    accv[2] = fdot2(eB, bch2(vaB.z), fdot2(eA, bch2(vaA.z), accv[2]));
    accv[3] = fdot2(eB, bch2(vaB.w), fdot2(eA, bch2(vaA.w), accv[3]));
    accv[4] = fdot2(eB, bch2(vbB.x), fdot2(eA, bch2(vbA.x), accv[4]));
    accv[5] = fdot2(eB, bch2(vbB.y), fdot2(eA, bch2(vbA.y), accv[5]));
    accv[6] = fdot2(eB, bch2(vbB.z), fdot2(eA, bch2(vbA.z), accv[6]));
    accv[7] = fdot2(eB, bch2(vbB.w), fdot2(eA, bch2(vbA.w), accv[7]));
    accvp[0] = fdot2(eB, bch2(waB.x), fdot2(eA, bch2(waA.x), accvp[0]));
    accvp[1] = fdot2(eB, bch2(waB.y), fdot2(eA, bch2(waA.y), accvp[1]));
    accvp[2] = fdot2(eB, bch2(waB.z), fdot2(eA, bch2(waA.z), accvp[2]));
    accvp[3] = fdot2(eB, bch2(waB.w), fdot2(eA, bch2(waA.w), accvp[3]));
    accvp[4] = fdot2(eB, bch2(wbB.x), fdot2(eA, bch2(wbA.x), accvp[4]));
    accvp[5] = fdot2(eB, bch2(wbB.y), fdot2(eA, bch2(wbA.y), accvp[5]));
    accvp[6] = fdot2(eB, bch2(wbB.z), fdot2(eA, bch2(wbA.z), accvp[6]));
    accvp[7] = fdot2(eB, bch2(wbB.w), fdot2(eA, bch2(wbA.w), accvp[7]));
  }
  // reconcile the 4 lanes' running maxes, then reduce
  float M = fmaxf(mcur, __shfl_xor(mcur, 1));
  M = fmaxf(M, __shfl_xor(M, 2));
  {
    float r = __expf(mcur - M);
    sum *= r;
#pragma unroll
    for (int c = 0; c < 8; ++c) { accv[c] *= r; accvp[c] *= r; }
  }
  sum += __shfl_xor(sum, 1);
  sum += __shfl_xor(sum, 2);
#pragma unroll
  for (int c = 0; c < 8; ++c) {
    accv[c]  += __shfl_xor(accv[c], 1);  accv[c]  += __shfl_xor(accv[c], 2);
    accvp[c] += __shfl_xor(accvp[c], 1); accvp[c] += __shfl_xor(accvp[c], 2);
  }

  float sv = 0, ssv = 0, svp = 0, ssvp = 0;
  if (isub == 0) {
    const float fv = gv_p[0] / sum, fp2 = gvp_p[0] / sum;
    size_t base = ((size_t)(n * 8 + h) * 8) * 128 + p;
#pragma unroll
    for (int c = 0; c < 8; ++c) {
      float x1 = accv[c] * fv;
      float x2 = accvp[c] * fp2;
      av [base + c * 128] = (_Float16)x1;
      avp[base + c * 128] = (_Float16)x2;
      sv += x1; ssv += x1 * x1; svp += x2; ssvp += x2 * x2;
    }
  }
  float vals[4] = {sv, ssv, svp, ssvp};
#pragma unroll
  for (int kk = 0; kk < 4; ++kk) {
    float v = vals[kk];
#pragma unroll
    for (int off = 1; off < 64; off <<= 1) v += __shfl_xor(v, off);
    vals[kk] = v;
  }
  const int wid = tid >> 6, lane = tid & 63;
  if (lane == 0) {
#pragma unroll
    for (int kk = 0; kk < 4; ++kk) red[wid][kk] = vals[kk];
  }
  __syncthreads();
  if (tid == 0) {
    float t0 = 0, t1 = 0, t2 = 0, t3 = 0;
#pragma unroll
    for (int w = 0; w < 8; ++w) {
      t0 += red[w][0]; t1 += red[w][1]; t2 += red[w][2]; t3 += red[w][3];
    }
    float* o = Vbuf + (size_t)blockIdx.x * 4;
    o[0] = t0; o[1] = t1; o[2] = t2; o[3] = t3;
  }
}

// ---------------- KR2: reduce Vbuf + finalize v bn (merged) -----------------
__global__ __launch_bounds__(512) void kR2(
    const float* __restrict__ Vbuf, float* __restrict__ S,
    const float* __restrict__ gv, const float* __restrict__ bv)
{
  __shared__ float part[32][17];
  const int t = threadIdx.x;
  const int col = t >> 4, sub = t & 15;      // col = k*8+h
  const int k = col >> 3, h = col & 7;
  float v = 0.f;
  for (int m = 0; m < 32; ++m) {
    int n = sub + 16 * m;
    v += Vbuf[(size_t)(n * 8 + h) * 4 + k];
  }
  part[col][sub] = v;
  __syncthreads();
  if (t < 32) {
    float s = 0.f;
#pragma unroll
    for (int j = 0; j < 16; ++j) s += part[t][j];
    part[t][16] = s;
  }
  __syncthreads();
  if (t < 8) {
    const int hh = t;
    const float inv = 1.f / 524288.f;
    float m1 = part[0 * 8 + hh][16] * inv;
    float e1 = part[1 * 8 + hh][16] * inv;
    float var = e1 - m1 * m1;
    float sc = gv[hh] * rsqrtf(var + EPS);
    S[624 + hh] = sc;
    S[632 + hh] = bv[hh] - m1 * sc;
    float m2 = part[2 * 8 + hh][16] * inv;
    float e2 = part[3 * 8 + hh][16] * inv;
    var = e2 - m2 * m2;
    sc = gv[8 + hh] * rsqrtf(var + EPS);
    S[640 + hh] = sc;
    S[648 + hh] = bv[8 + hh] - m2 * sc;
  }
}

// ---------------- K7: bn apply + sum halves + LDS-tiled transpose out -------
__global__ __launch_bounds__(256) void k7_out(
    const _Float16* __restrict__ av, const _Float16* __restrict__ avp,
    const float* __restrict__ S, float* __restrict__ out)
{
  __shared__ float tile[64][129];
  const int wt = blockIdx.x & 1;
  const int d  = (blockIdx.x >> 1) & 63;
  const int b  = blockIdx.x >> 7;
  const int h = d >> 3, c = d & 7;
  const float scv = S[624 + h], shv = S[632 + h];
  const float scp = S[640 + h], shp = S[648 + h];
  const int tid = threadIdx.x;
  for (int idx = tid; idx < 8192; idx += 256) {
    int wl = idx >> 7, pp = idx & 127;
    int n = b * 128 + wt * 64 + wl;
    size_t base = (((size_t)n * 8 + h) * 8 + c) * 128 + pp;
    tile[wl][pp] = (float)av[base] * scv + shv + (float)avp[base] * scp + shp;
  }
  __syncthreads();
  for (int idx = tid; idx < 8192; idx += 256) {
    int pp = idx >> 6, wl = idx & 63;
    out[(((size_t)b * 64 + d) * 128 + pp) * 128 + wt * 64 + wl] = tile[wl][pp];
  }
}

// ---------------- launch ----------------------------------------------------
extern "C" void kernel_launch(void* const* d_in, const int* in_sizes, int n_in,
                              void* d_out, int out_size, void* d_ws, size_t ws_size,
                              hipStream_t stream)
{
  const float* x   = (const float*)d_in[0];
  const float* wq  = (const float*)d_in[1];
  const float* g1  = (const float*)d_in[2];
  const float* b1  = (const float*)d_in[3];
  const float* pos = (const float*)d_in[4];
  const float* gqr = (const float*)d_in[5];
  const float* gkr = (const float*)d_in[6];
  const float* gvp = (const float*)d_in[7];
  const float* gv  = (const float*)d_in[8];
  const float* ga  = (const float*)d_in[9];
  const float* ba  = (const float*)d_in[10];
  const float* gv2 = (const float*)d_in[11];
  const float* bv2 = (const float*)d_in[12];

  float* ws = (float*)d_ws;
  _Float16* y1h   = (_Float16*)ws;
  _Float16* av    = (_Float16*)ws;
  _Float16* avp   = (_Float16*)ws + 4194304;
  float*    Pb3   = ws + 4200000;
  float*    Vbuf  = ws + 4250000;
  float*    Pbuf  = ws + 4300000;                // moved: y1h-upper free zone
  unsigned* y2h   = (unsigned*)(ws + 8388608);
  float*    S     = ws + 16777216;
  unsigned* pos_h = (unsigned*)(ws + 16778240);
  float*    PT    = ws + 16781312;
  unsigned* vpxg  = (unsigned*)(ws + 16785000);
  float*    out   = (float*)d_out;

  k0_pos<<<30, 128, 0, stream>>>(pos, PT, pos_h, vpxg);
  k1_gemm<<<512, 256, 0, stream>>>(x, wq, y1h, Pbuf);
  k_tr<<<256, 256, 0, stream>>>(y1h, Pbuf, g1, b1, y2h);
  k3_stats<<<128, 256, 0, stream>>>(y2h, PT, Pb3);
  kR1<<<1, 64, 0, stream>>>(Pb3, S, ga, ba, gqr, gkr);
  k5_apply<<<4096, 512, 0, stream>>>(y2h, pos_h, vpxg, S, av, avp, gv, gvp, Vbuf);
  kR2<<<1, 512, 0, stream>>>(Vbuf, S, gv2, bv2);
  k7_out<<<512, 256, 0, stream>>>(av, avp, S, out);
}

// Round 12
// 176.670 us; speedup vs baseline: 3.8651x; 1.1882x over previous
//
#include <hip/hip_runtime.h>
#include <hip/hip_fp16.h>

#define EPS 1e-5f

// Problem constants: B=4, C=64, H=128, W=128, N=512, OP2=128, HEAD=8, HP=16
// qk_dim=4, v_dim=8

// workspace layout (float offsets)
//  y1h: (b,l,o,w) half, 8,388,608 halves at 0    [dead after k_tr]
//  av : (n,h,c,p) half, 4,194,304 halves at 0    (k5 writes; y1h region)
//  avp: (n,h,c,p) half at float-offset 2,097,152
//  Pb3: k3 partials 4096*6 f32 at 4,200,000
//  Vbuf: k5 partials 4096*4 f32 at 4,250,000
//  Pbuf: k1 partials 512*256 f32 at 4,300,000    (y1h-upper free zone; read by k_tr)
//  y2h: (n,h,slot,l) packed half2 per uint, 1,048,576 uints at 8,388,608
//       slot: 0 q01 1 q23 2 k01 3 k23 4 v01 5 v23 6 v45 7 v67 (BN applied)
//  S  : stats 1024 f32 at 16,777,216
//  pos_h: packed qk-pos [u=0..254][4 uints] at 16,778,240 (1020 uints)
//  PT : f32 window tables at 16,781,312 (3584)
//  vpxg: reversed/parity-split vp pairs, 3072 uints at 16,785,000

typedef _Float16 half2_t __attribute__((ext_vector_type(2)));

__device__ __constant__ int pair_c [10] = {0,0,0,0,1,1,1,2,2,3};
__device__ __constant__ int pair_cp[10] = {0,1,2,3,1,2,3,2,3,3};

__device__ inline float fdot2(half2_t a, half2_t b, float c) {
#if __has_builtin(__builtin_amdgcn_fdot2)
  return __builtin_amdgcn_fdot2(a, b, c, false);
#else
  return c + (float)a[0] * (float)b[0] + (float)a[1] * (float)b[1];
#endif
}
__device__ inline half2_t bch2(unsigned u) {
  union { unsigned u; half2_t h; } x; x.u = u; return x.h;
}
__device__ inline unsigned packf2(float a, float b) {
  half2_t h; h[0] = (_Float16)a; h[1] = (_Float16)b;
  union { unsigned u; half2_t h; } x; x.h = h; return x.u;
}

// ---------------- K1: qkv GEMM + relu + bn1 partials; y1 stored HALF --------
__global__ __launch_bounds__(256) void k1_gemm(
    const float* __restrict__ x, const float* __restrict__ wq,
    _Float16* __restrict__ y1h, float* __restrict__ Pbuf)
{
  __shared__ float xs[64][132];
  const int b = blockIdx.x >> 7, l = blockIdx.x & 127;
  const int tid = threadIdx.x;
  const float* xp = x + (size_t)b * 1048576 + (size_t)l * 128;
  for (int idx = tid; idx < 2048; idx += 256) {
    int c = idx >> 5, w4 = (idx & 31) * 4;
    *(float4*)&xs[c][w4] = *(const float4*)&xp[c * 16384 + w4];
  }
  __syncthreads();
  const int ty = tid >> 4, tx = tid & 15;
  const int o0 = ty * 8, w0 = tx * 4;
  float acc[8][8];
#pragma unroll
  for (int u = 0; u < 8; ++u)
#pragma unroll
    for (int v = 0; v < 8; ++v) acc[u][v] = 0.f;

  for (int c4 = 0; c4 < 64; c4 += 4) {
    float wr[8][4];
#pragma unroll
    for (int u = 0; u < 8; ++u)
      *(float4*)&wr[u][0] = *(const float4*)&wq[(o0 + u) * 64 + c4];
#pragma unroll
    for (int dc = 0; dc < 4; ++dc) {
      float4 xa = *(const float4*)&xs[c4 + dc][w0];
      float4 xb = *(const float4*)&xs[c4 + dc][w0 + 64];
#pragma unroll
      for (int u = 0; u < 8; ++u) {
        float wv = wr[u][dc];
        acc[u][0] += wv * xa.x; acc[u][1] += wv * xa.y;
        acc[u][2] += wv * xa.z; acc[u][3] += wv * xa.w;
        acc[u][4] += wv * xb.x; acc[u][5] += wv * xb.y;
        acc[u][6] += wv * xb.z; acc[u][7] += wv * xb.w;
      }
    }
  }
  _Float16* y1p = y1h + (size_t)(b * 128 + l) * 16384;
#pragma unroll
  for (int u = 0; u < 8; ++u) {
#pragma unroll
    for (int v = 0; v < 8; ++v) acc[u][v] = fmaxf(acc[u][v], 0.f);
    uint2 pa, pb;
    pa.x = packf2(acc[u][0], acc[u][1]); pa.y = packf2(acc[u][2], acc[u][3]);
    pb.x = packf2(acc[u][4], acc[u][5]); pb.y = packf2(acc[u][6], acc[u][7]);
    *(uint2*)&y1p[(o0 + u) * 128 + w0] = pa;
    *(uint2*)&y1p[(o0 + u) * 128 + w0 + 64] = pb;
    float s  = acc[u][0] + acc[u][1] + acc[u][2] + acc[u][3]
             + acc[u][4] + acc[u][5] + acc[u][6] + acc[u][7];
    float ss = acc[u][0]*acc[u][0] + acc[u][1]*acc[u][1] + acc[u][2]*acc[u][2]
             + acc[u][3]*acc[u][3] + acc[u][4]*acc[u][4] + acc[u][5]*acc[u][5]
             + acc[u][6]*acc[u][6] + acc[u][7]*acc[u][7];
#pragma unroll
    for (int off = 1; off < 16; off <<= 1) {
      s  += __shfl_xor(s, off);
      ss += __shfl_xor(ss, off);
    }
    if (tx == 0) {
      Pbuf[blockIdx.x * 256 + o0 + u] = s;
      Pbuf[blockIdx.x * 256 + 128 + o0 + u] = ss;
    }
  }
}

// ---------------- K_tr: y1h -> y2h (BN stats reduced in-block, applied) -----
// block = (b, s=o-pair 0..63); grid 256
__global__ __launch_bounds__(256) void k_tr(
    const _Float16* __restrict__ y1h, const float* __restrict__ Pbuf,
    const float* __restrict__ g1, const float* __restrict__ b1,
    unsigned* __restrict__ y2h)
{
  __shared__ _Float16 th[2][64][134];
  __shared__ float scsh[4];
  const int s = blockIdx.x & 63, b = blockIdx.x >> 6;
  const int h = s >> 3, slot = s & 7;
  const int o0 = 2 * s, o1 = 2 * s + 1;
  const int tid = threadIdx.x;
  {
    int r = tid >> 6, lane = tid & 63;
    int row = ((r & 1) ? o1 : o0) + (r >> 1) * 128;
    float a = 0.f;
#pragma unroll
    for (int m = 0; m < 8; ++m) a += Pbuf[(lane + 64 * m) * 256 + row];
#pragma unroll
    for (int off = 1; off < 64; off <<= 1) a += __shfl_xor(a, off);
    if (lane == 0) scsh[r] = a;
  }
  __syncthreads();
  const float inv = 1.f / 65536.f;
  const float m0 = scsh[0] * inv, v0 = scsh[2] * inv - m0 * m0;
  const float m1 = scsh[1] * inv, v1 = scsh[3] * inv - m1 * m1;
  const float sc0 = g1[o0] * rsqrtf(v0 + EPS), sh0 = b1[o0] - m0 * sc0;
  const float sc1 = g1[o1] * rsqrtf(v1 + EPS), sh1 = b1[o1] - m1 * sc1;
  for (int lh = 0; lh < 2; ++lh) {
    const int l0 = lh * 64;
    for (int idx = tid; idx < 4096; idx += 256) {
      int ll = idx >> 6, wp = idx & 63;
      size_t base = ((size_t)(b * 128 + l0 + ll) * 128) * 128 + 2 * wp;
      unsigned a0 = *(const unsigned*)&y1h[base + (size_t)o0 * 128];
      unsigned a1 = *(const unsigned*)&y1h[base + (size_t)o1 * 128];
      half2_t ha = bch2(a0), hb = bch2(a1);
      *(unsigned*)&th[0][ll][2 * wp] =
          packf2((float)ha[0] * sc0 + sh0, (float)ha[1] * sc0 + sh0);
      *(unsigned*)&th[1][ll][2 * wp] =
          packf2((float)hb[0] * sc1 + sh1, (float)hb[1] * sc1 + sh1);
    }
    __syncthreads();
    for (int idx = tid; idx < 8192; idx += 256) {
      int w = idx >> 6, ll = idx & 63;
      unsigned pk;
      { half2_t hh; hh[0] = th[0][ll][w]; hh[1] = th[1][ll][w];
        union { unsigned u; half2_t h; } xx; xx.h = hh; pk = xx.u; }
      y2h[((size_t)((b * 128 + w) * 8 + h) * 8 + slot) * 128 + l0 + ll] = pk;
    }
    __syncthreads();
  }
}

// ---------------- K0: PT tables + packed qk-pos + vpx tables ----------------
__global__ __launch_bounds__(128) void k0_pos(const float* __restrict__ pos,
                                              float* __restrict__ PT,
                                              unsigned* __restrict__ pos_h,
                                              unsigned* __restrict__ vpxg)
{
  const int blk = blockIdx.x, tid = threadIdx.x;
  if (blk == 28) {
    for (int u = tid; u < 255; u += 128) {
#pragma unroll
      for (int s = 0; s < 4; ++s)
        pos_h[u * 4 + s] = packf2(pos[(2 * s) * 255 + u], pos[(2 * s + 1) * 255 + u]);
    }
    return;
  }
  if (blk == 29) {
    for (int m = tid; m < 3072; m += 128) {
      int sel = m / 1536, rem = m % 1536, rp = rem / 12, c = rem % 12;
      unsigned val = 0;
      if (c < 8) {
        int ua = (sel ? 254 : 253) - 2 * rp;
        int ub = ua - 1;
        float fa = (ua >= 0) ? pos[(8 + c) * 255 + ua] : 0.f;
        float fb = (ub >= 0) ? pos[(8 + c) * 255 + ub] : 0.f;
        val = packf2(fa, fb);
      }
      vpxg[m] = val;
    }
    return;
  }
  __shared__ float r0[255], r1[255];
  int rowA, rowB, out;
  bool prod;
  if (blk < 4)       { rowA = blk;                 rowB = rowA;               out = blk * 128;              prod = false; }
  else if (blk < 14) { int m = blk - 4;  rowA = pair_c[m];     rowB = pair_cp[m];     out = 1024 + m * 128; prod = true; }
  else if (blk < 18) { rowA = 4 + (blk - 14);      rowB = rowA;               out = 512 + (blk - 14) * 128; prod = false; }
  else               { int m = blk - 18; rowA = 4 + pair_c[m]; rowB = 4 + pair_cp[m]; out = 2304 + m * 128; prod = true; }
  for (int u = tid; u < 255; u += 128) {
    r0[u] = pos[rowA * 255 + u];
    r1[u] = pos[rowB * 255 + u];
  }
  __syncthreads();
  float s = 0.f;
  if (prod) {
    for (int d = 0; d < 128; ++d) s += r0[tid + d] * r1[tid + d];
  } else {
    for (int d = 0; d < 128; ++d) s += r0[tid + d];
  }
  PT[out + tid] = s;
}

// ---------------- K3: att stats, ONE (n,h) unit per wave, no atomics --------
// grid 1024 x 256: wave W = blockIdx*4 + wid handles unit W (= n*8+h)
__global__ __launch_bounds__(256) void k3_stats(
    const unsigned* __restrict__ y2h, const float* __restrict__ PT,
    float* __restrict__ Pb3)
{
  const int W = blockIdx.x * 4 + (threadIdx.x >> 6);
  const int lane = threadIdx.x & 63;
  const unsigned* yb = y2h + (size_t)W * 1024;
  float q[4][2], k[4][2];
#pragma unroll
  for (int pl = 0; pl < 2; ++pl) {
    half2_t ha = bch2(yb[pl * 128 + lane]);
    half2_t hb = bch2(yb[pl * 128 + 64 + lane]);
    q[2 * pl][0] = (float)ha[0]; q[2 * pl + 1][0] = (float)ha[1];
    q[2 * pl][1] = (float)hb[0]; q[2 * pl + 1][1] = (float)hb[1];
    half2_t hc = bch2(yb[(2 + pl) * 128 + lane]);
    half2_t hd = bch2(yb[(2 + pl) * 128 + 64 + lane]);
    k[2 * pl][0] = (float)hc[0]; k[2 * pl + 1][0] = (float)hc[1];
    k[2 * pl][1] = (float)hd[0]; k[2 * pl + 1][1] = (float)hd[1];
  }
  float vals[32];
#pragma unroll
  for (int c = 0; c < 4; ++c) {
    vals[c]     = q[c][0] + q[c][1];
    vals[4 + c] = k[c][0] + k[c][1];
  }
#pragma unroll
  for (int m = 0; m < 10; ++m) {
    int c = pair_c[m], cp = pair_cp[m];
    vals[8 + m]  = q[c][0] * q[cp][0] + q[c][1] * q[cp][1];
    vals[18 + m] = k[c][0] * k[cp][0] + k[c][1] * k[cp][1];
  }
  float qr = 0, qrss = 0, kr = 0, krss = 0;
#pragma unroll
  for (int c = 0; c < 4; ++c) {
    qr += q[c][0] * PT[c * 128 + lane]       + q[c][1] * PT[c * 128 + 64 + lane];
    kr += k[c][0] * PT[512 + c * 128 + lane] + k[c][1] * PT[512 + c * 128 + 64 + lane];
  }
#pragma unroll
  for (int m = 0; m < 10; ++m) {
    int c = pair_c[m], cp = pair_cp[m];
    float mult = (c == cp) ? 1.f : 2.f;
    qrss += mult * (q[c][0] * q[cp][0] * PT[1024 + m * 128 + lane]
                  + q[c][1] * q[cp][1] * PT[1024 + m * 128 + 64 + lane]);
    krss += mult * (k[c][0] * k[cp][0] * PT[2304 + m * 128 + lane]
                  + k[c][1] * k[cp][1] * PT[2304 + m * 128 + 64 + lane]);
  }
  vals[28] = qr; vals[29] = qrss; vals[30] = kr; vals[31] = krss;
#pragma unroll
  for (int v = 0; v < 32; ++v) {
    float t = vals[v];
#pragma unroll
    for (int off = 1; off < 64; off <<= 1) t += __shfl_xor(t, off);
    vals[v] = t;
  }
  if (lane == 0) {
    float qk_sum = 0, qk_ss = 0;
#pragma unroll
    for (int c = 0; c < 4; ++c) qk_sum += vals[c] * vals[4 + c];
#pragma unroll
    for (int m = 0; m < 10; ++m) {
      float mult = (pair_c[m] == pair_cp[m]) ? 1.f : 2.f;
      qk_ss += mult * vals[8 + m] * vals[18 + m];
    }
    float* o = Pb3 + W * 6;
    o[0] = qk_sum; o[1] = qk_ss;
    o[2] = vals[28]; o[3] = vals[29]; o[4] = vals[30]; o[5] = vals[31];
  }
}

// ---------------- KR1: reduce Pb3 (4096 units) + finalize att bn coefs ------
// 1 block x 384 threads: col = t>>3 (h*6+k), sub = t&7 sums 64 units each
__global__ __launch_bounds__(384) void kR1(
    const float* __restrict__ Pb3, float* __restrict__ S,
    const float* __restrict__ ga, const float* __restrict__ ba,
    const float* __restrict__ gqr, const float* __restrict__ gkr)
{
  __shared__ float sums[48];
  const int t = threadIdx.x;
  const int col = t >> 3, sub = t & 7;
  if (col < 48) {
    const int h = col / 6, k = col % 6;
    float v = 0.f;
#pragma unroll
    for (int j = 0; j < 64; ++j) {
      int n = sub * 64 + j;
      v += Pb3[(size_t)(n * 8 + h) * 6 + k];
    }
    v += __shfl_xor(v, 1);
    v += __shfl_xor(v, 2);
    v += __shfl_xor(v, 4);
    if (sub == 0) sums[col] = v;
  }
  __syncthreads();
  if (t < 8) {
    const int h = t;
    const float inv = 1.f / 8388608.f;
    float gates[3] = {1.f, gqr[0], gkr[0]};
    float csum = 0.f;
#pragma unroll
    for (int g = 0; g < 3; ++g) {
      float mr = sums[h * 6 + 2 * g] * inv;
      float er = sums[h * 6 + 2 * g + 1] * inv;
      float gt = gates[g];
      float mean = gt * mr;
      float var = gt * gt * er - mean * mean;
      float sc = ga[g * 8 + h] * rsqrtf(var + EPS);
      S[560 + g * 8 + h] = gt * sc;
      csum += ba[g * 8 + h] - mean * sc;
    }
    S[584 + h] = csum;
  }
}

// ---------------- K5: fully-unrolled 2-pair groups, online-max, dot2 PV -----
__global__ __launch_bounds__(512, 6) void k5_apply(
    const unsigned* __restrict__ y2h, const unsigned* __restrict__ pos_h,
    const unsigned* __restrict__ vpxg,
    float* __restrict__ S, _Float16* __restrict__ av, _Float16* __restrict__ avp,
    const float* __restrict__ gv_p, const float* __restrict__ gvp_p,
    float* __restrict__ Vbuf)
{
  __shared__ __align__(16) unsigned qkv_s[128][4];   // [l][q01,q23,k01,k23]
  __shared__ __align__(16) unsigned posm[255][4];    // [u][qp01,qp23,kp01,kp23]
  __shared__ __align__(16) unsigned vt[64][8];       // [i-pair][v ch 0..7]
  __shared__ __align__(16) unsigned vpx[2][128][12]; // [sel][rp][vp ch 0..7 +pad]
  __shared__ float red[8][4];
  const int h = blockIdx.x & 7, n = blockIdx.x >> 3;
  const int tid = threadIdx.x;
  const unsigned* yb = y2h + (size_t)(n * 8 + h) * 1024;
  {
    int l = tid >> 2, s = tid & 3;
    qkv_s[l][s] = yb[s * 128 + l];
  }
  {
    unsigned* pf = (unsigned*)posm;
    for (int m = tid; m < 1020; m += 512) pf[m] = pos_h[m];
  }
  {
    unsigned* pf = (unsigned*)vpx;
    for (int m = tid; m < 3072; m += 512) pf[m] = vpxg[m];
  }
  if (tid < 256) {
    int s = tid & 3, jp = tid >> 2;
    unsigned a0 = yb[(4 + s) * 128 + 2 * jp];
    unsigned a1 = yb[(4 + s) * 128 + 2 * jp + 1];
    vt[jp][2 * s]     = (a0 & 0xffffu) | (a1 << 16);
    vt[jp][2 * s + 1] = (a0 >> 16) | (a1 & 0xffff0000u);
  }
  __syncthreads();

  const int p = tid >> 2, isub = tid & 3;
  uint2 qk2 = *(const uint2*)&qkv_s[p][0];
  uint2 kown = *(const uint2*)&qkv_s[p][2];
  const half2_t q01 = bch2(qk2.x), q23 = bch2(qk2.y);
  const half2_t k01o = bch2(kown.x), k23o = bch2(kown.y);
  const float C0 = S[560 + h], C1 = S[568 + h], C2 = S[576 + h], C3v = S[584 + h];
  const unsigned* vprow = &vpx[p & 1][63 - (p >> 1)][0];
  const half2_t one2 = bch2(packf2(1.f, 1.f));

  float mcur = -1e30f;
  float sum = 0.f;
  float accv[8], accvp[8];
#pragma unroll
  for (int c = 0; c < 8; ++c) { accv[c] = 0.f; accvp[c] = 0.f; }

#pragma unroll
  for (int jj = 0; jj < 8; ++jj) {
    const int jpA = isub + 8 * jj;
    const int jpB = jpA + 4;
    const int i0A = 2 * jpA, i0B = 2 * jpB;
    const int uA = p - i0A + 127;
    const int uB = uA - 8;
    uint2 kaA = *(const uint2*)&qkv_s[i0A][2];
    uint2 kbA = *(const uint2*)&qkv_s[i0A + 1][2];
    uint2 kaB = *(const uint2*)&qkv_s[i0B][2];
    uint2 kbB = *(const uint2*)&qkv_s[i0B + 1][2];
    uint4 paA = *(const uint4*)&posm[uA][0];
    uint4 pbA = *(const uint4*)&posm[uA - 1][0];
    uint4 paB = *(const uint4*)&posm[uB][0];
    uint4 pbB = *(const uint4*)&posm[uB - 1][0];
    float s0 = fdot2(q23, bch2(kaA.y), fdot2(q01, bch2(kaA.x), 0.f)) * C0
             + fdot2(q23, bch2(paA.y), fdot2(q01, bch2(paA.x), 0.f)) * C1
             + fdot2(k23o, bch2(paA.w), fdot2(k01o, bch2(paA.z), 0.f)) * C2 + C3v;
    float s1 = fdot2(q23, bch2(kbA.y), fdot2(q01, bch2(kbA.x), 0.f)) * C0
             + fdot2(q23, bch2(pbA.y), fdot2(q01, bch2(pbA.x), 0.f)) * C1
             + fdot2(k23o, bch2(pbA.w), fdot2(k01o, bch2(pbA.z), 0.f)) * C2 + C3v;
    float s2 = fdot2(q23, bch2(kaB.y), fdot2(q01, bch2(kaB.x), 0.f)) * C0
             + fdot2(q23, bch2(paB.y), fdot2(q01, bch2(paB.x), 0.f)) * C1
             + fdot2(k23o, bch2(paB.w), fdot2(k01o, bch2(paB.z), 0.f)) * C2 + C3v;
    float s3 = fdot2(q23, bch2(kbB.y), fdot2(q01, bch2(kbB.x), 0.f)) * C0
             + fdot2(q23, bch2(pbB.y), fdot2(q01, bch2(pbB.x), 0.f)) * C1
             + fdot2(k23o, bch2(pbB.w), fdot2(k01o, bch2(pbB.z), 0.f)) * C2 + C3v;
    float mp = fmaxf(fmaxf(s0, s1), fmaxf(s2, s3));
    if (mp > mcur) {
      float r = __expf(mcur - mp);
      mcur = mp;
      sum *= r;
#pragma unroll
      for (int c = 0; c < 8; ++c) { accv[c] *= r; accvp[c] *= r; }
    }
    float e0 = __expf(s0 - mcur);
    float e1 = __expf(s1 - mcur);
    float e2f = __expf(s2 - mcur);
    float e3f = __expf(s3 - mcur);
    const half2_t eA = bch2(packf2(e0, e1));
    const half2_t eB = bch2(packf2(e2f, e3f));
    sum = fdot2(eB, one2, fdot2(eA, one2, sum));
    uint4 vaA = *(const uint4*)&vt[jpA][0];
    uint4 vbA = *(const uint4*)&vt[jpA][4];
    uint4 vaB = *(const uint4*)&vt[jpB][0];
    uint4 vbB = *(const uint4*)&vt[jpB][4];
    const unsigned* wrA = vprow + jpA * 12;
    const unsigned* wrB = vprow + jpB * 12;
    uint4 waA = *(const uint4*)wrA;
    uint4 wbA = *(const uint4*)(wrA + 4);
    uint4 waB = *(const uint4*)wrB;
    uint4 wbB = *(const uint4*)(wrB + 4);
    accv[0] = fdot2(eB, bch2(vaB.x), fdot2(eA, bch2(vaA.x), accv[0]));
    accv[1] = fdot2(eB, bch2(vaB.y), fdot2(eA, bch2(vaA.y), accv[1]));
    accv[2] = fdot2(eB, bch2(vaB.z), fdot2(eA, bch2(vaA.z), accv[2]));
    accv[3] = fdot2(eB, bch2(vaB.w), fdot2(eA, bch2(vaA.w), accv[3]));
    accv[4] = fdot2(eB, bch2(vbB.x), fdot2(eA, bch2(vbA.x), accv[4]));
    accv[5] = fdot2(eB, bch2(vbB.y), fdot2(eA, bch2(vbA.y), accv[5]));
    accv[6] = fdot2(eB, bch2(vbB.z), fdot2(eA, bch2(vbA.z), accv[6]));
    accv[7] = fdot2(eB, bch2(vbB.w), fdot2(eA, bch2(vbA.w), accv[7]));
    accvp[0] = fdot2(eB, bch2(waB.x), fdot2(eA, bch2(waA.x), accvp[0]));
    accvp[1] = fdot2(eB, bch2(waB.y), fdot2(eA, bch2(waA.y), accvp[1]));
    accvp[2] = fdot2(eB, bch2(waB.z), fdot2(eA, bch2(waA.z), accvp[2]));
    accvp[3] = fdot2(eB, bch2(waB.w), fdot2(eA, bch2(waA.w), accvp[3]));
    accvp[4] = fdot2(eB, bch2(wbB.x), fdot2(eA, bch2(wbA.x), accvp[4]));
    accvp[5] = fdot2(eB, bch2(wbB.y), fdot2(eA, bch2(wbA.y), accvp[5]));
    accvp[6] = fdot2(eB, bch2(wbB.z), fdot2(eA, bch2(wbA.z), accvp[6]));
    accvp[7] = fdot2(eB, bch2(wbB.w), fdot2(eA, bch2(wbA.w), accvp[7]));
  }
  float M = fmaxf(mcur, __shfl_xor(mcur, 1));
  M = fmaxf(M, __shfl_xor(M, 2));
  {
    float r = __expf(mcur - M);
    sum *= r;
#pragma unroll
    for (int c = 0; c < 8; ++c) { accv[c] *= r; accvp[c] *= r; }
  }
  sum += __shfl_xor(sum, 1);
  sum += __shfl_xor(sum, 2);
#pragma unroll
  for (int c = 0; c < 8; ++c) {
    accv[c]  += __shfl_xor(accv[c], 1);  accv[c]  += __shfl_xor(accv[c], 2);
    accvp[c] += __shfl_xor(accvp[c], 1); accvp[c] += __shfl_xor(accvp[c], 2);
  }

  float sv = 0, ssv = 0, svp = 0, ssvp = 0;
  if (isub == 0) {
    const float fv = gv_p[0] / sum, fp2 = gvp_p[0] / sum;
    size_t base = ((size_t)(n * 8 + h) * 8) * 128 + p;
#pragma unroll
    for (int c = 0; c < 8; ++c) {
      float x1 = accv[c] * fv;
      float x2 = accvp[c] * fp2;
      av [base + c * 128] = (_Float16)x1;
      avp[base + c * 128] = (_Float16)x2;
      sv += x1; ssv += x1 * x1; svp += x2; ssvp += x2 * x2;
    }
  }
  float vals[4] = {sv, ssv, svp, ssvp};
#pragma unroll
  for (int kk = 0; kk < 4; ++kk) {
    float v = vals[kk];
#pragma unroll
    for (int off = 1; off < 64; off <<= 1) v += __shfl_xor(v, off);
    vals[kk] = v;
  }
  const int wid = tid >> 6, lane = tid & 63;
  if (lane == 0) {
#pragma unroll
    for (int kk = 0; kk < 4; ++kk) red[wid][kk] = vals[kk];
  }
  __syncthreads();
  if (tid == 0) {
    float t0 = 0, t1 = 0, t2 = 0, t3 = 0;
#pragma unroll
    for (int w = 0; w < 8; ++w) {
      t0 += red[w][0]; t1 += red[w][1]; t2 += red[w][2]; t3 += red[w][3];
    }
    float* o = Vbuf + (size_t)blockIdx.x * 4;
    o[0] = t0; o[1] = t1; o[2] = t2; o[3] = t3;
  }
}

// ---------------- KR2: reduce Vbuf + finalize v bn (merged) -----------------
__global__ __launch_bounds__(512) void kR2(
    const float* __restrict__ Vbuf, float* __restrict__ S,
    const float* __restrict__ gv, const float* __restrict__ bv)
{
  __shared__ float part[32][17];
  const int t = threadIdx.x;
  const int col = t >> 4, sub = t & 15;      // col = k*8+h
  const int k = col >> 3, h = col & 7;
  float v = 0.f;
  for (int m = 0; m < 32; ++m) {
    int n = sub + 16 * m;
    v += Vbuf[(size_t)(n * 8 + h) * 4 + k];
  }
  part[col][sub] = v;
  __syncthreads();
  if (t < 32) {
    float s = 0.f;
#pragma unroll
    for (int j = 0; j < 16; ++j) s += part[t][j];
    part[t][16] = s;
  }
  __syncthreads();
  if (t < 8) {
    const int hh = t;
    const float inv = 1.f / 524288.f;
    float m1 = part[0 * 8 + hh][16] * inv;
    float e1 = part[1 * 8 + hh][16] * inv;
    float var = e1 - m1 * m1;
    float sc = gv[hh] * rsqrtf(var + EPS);
    S[624 + hh] = sc;
    S[632 + hh] = bv[hh] - m1 * sc;
    float m2 = part[2 * 8 + hh][16] * inv;
    float e2 = part[3 * 8 + hh][16] * inv;
    var = e2 - m2 * m2;
    sc = gv[8 + hh] * rsqrtf(var + EPS);
    S[640 + hh] = sc;
    S[648 + hh] = bv[8 + hh] - m2 * sc;
  }
}

// ---------------- K7: bn apply + sum halves + LDS-tiled transpose out -------
__global__ __launch_bounds__(256) void k7_out(
    const _Float16* __restrict__ av, const _Float16* __restrict__ avp,
    const float* __restrict__ S, float* __restrict__ out)
{
  __shared__ float tile[64][129];
  const int wt = blockIdx.x & 1;
  const int d  = (blockIdx.x >> 1) & 63;
  const int b  = blockIdx.x >> 7;
  const int h = d >> 3, c = d & 7;
  const float scv = S[624 + h], shv = S[632 + h];
  const float scp = S[640 + h], shp = S[648 + h];
  const int tid = threadIdx.x;
  for (int idx = tid; idx < 8192; idx += 256) {
    int wl = idx >> 7, pp = idx & 127;
    int n = b * 128 + wt * 64 + wl;
    size_t base = (((size_t)n * 8 + h) * 8 + c) * 128 + pp;
    tile[wl][pp] = (float)av[base] * scv + shv + (float)avp[base] * scp + shp;
  }
  __syncthreads();
  for (int idx = tid; idx < 8192; idx += 256) {
    int pp = idx >> 6, wl = idx & 63;
    out[(((size_t)b * 64 + d) * 128 + pp) * 128 + wt * 64 + wl] = tile[wl][pp];
  }
}

// ---------------- launch ----------------------------------------------------
extern "C" void kernel_launch(void* const* d_in, const int* in_sizes, int n_in,
                              void* d_out, int out_size, void* d_ws, size_t ws_size,
                              hipStream_t stream)
{
  const float* x   = (const float*)d_in[0];
  const float* wq  = (const float*)d_in[1];
  const float* g1  = (const float*)d_in[2];
  const float* b1  = (const float*)d_in[3];
  const float* pos = (const float*)d_in[4];
  const float* gqr = (const float*)d_in[5];
  const float* gkr = (const float*)d_in[6];
  const float* gvp = (const float*)d_in[7];
  const float* gv  = (const float*)d_in[8];
  const float* ga  = (const float*)d_in[9];
  const float* ba  = (const float*)d_in[10];
  const float* gv2 = (const float*)d_in[11];
  const float* bv2 = (const float*)d_in[12];

  float* ws = (float*)d_ws;
  _Float16* y1h   = (_Float16*)ws;
  _Float16* av    = (_Float16*)ws;
  _Float16* avp   = (_Float16*)ws + 4194304;
  float*    Pb3   = ws + 4200000;
  float*    Vbuf  = ws + 4250000;
  float*    Pbuf  = ws + 4300000;
  unsigned* y2h   = (unsigned*)(ws + 8388608);
  float*    S     = ws + 16777216;
  unsigned* pos_h = (unsigned*)(ws + 16778240);
  float*    PT    = ws + 16781312;
  unsigned* vpxg  = (unsigned*)(ws + 16785000);
  float*    out   = (float*)d_out;

  k0_pos<<<30, 128, 0, stream>>>(pos, PT, pos_h, vpxg);
  k1_gemm<<<512, 256, 0, stream>>>(x, wq, y1h, Pbuf);
  k_tr<<<256, 256, 0, stream>>>(y1h, Pbuf, g1, b1, y2h);
  k3_stats<<<1024, 256, 0, stream>>>(y2h, PT, Pb3);
  kR1<<<1, 384, 0, stream>>>(Pb3, S, ga, ba, gqr, gkr);
  k5_apply<<<4096, 512, 0, stream>>>(y2h, pos_h, vpxg, S, av, avp, gv, gvp, Vbuf);
  kR2<<<1, 512, 0, stream>>>(Vbuf, S, gv2, bv2);
  k7_out<<<512, 256, 0, stream>>>(av, avp, S, out);
}

// Round 13
// 175.644 us; speedup vs baseline: 3.8877x; 1.0058x over previous
//
#include <hip/hip_runtime.h>
#include <hip/hip_fp16.h>

#define EPS 1e-5f

// Problem constants: B=4, C=64, H=128, W=128, N=512, OP2=128, HEAD=8, HP=16
// qk_dim=4, v_dim=8

// workspace layout (float offsets)
//  y1h: (b,l,o,w) half, 8,388,608 halves at 0    [dead after k_tr]
//  av : (n,h,c,p) half, 4,194,304 halves at 0    (k5 writes; y1h region)
//  avp: (n,h,c,p) half at float-offset 2,097,152
//  Pb3: k3 partials 4096*6 f32 at 4,200,000
//  Vbuf: k5 partials 4096*4 f32 at 4,250,000
//  Pbuf: k1 partials 512*256 f32 at 4,300,000    (y1h-upper free zone; read by k_tr)
//  y2h: (n,h,slot,l) packed half2 per uint, 1,048,576 uints at 8,388,608
//       slot: 0 q01 1 q23 2 k01 3 k23 4 v01 5 v23 6 v45 7 v67 (BN applied)
//  S  : stats 1024 f32 at 16,777,216
//  pos_h: packed qk-pos [u=0..254][4 uints] at 16,778,240 (1020 uints)
//  PT : f32 window tables at 16,781,312 (3584)
//  vpxg: flat vpx table (sel-shifted), 3084 uints at 16,785,000

typedef _Float16 half2_t __attribute__((ext_vector_type(2)));

__device__ __constant__ int pair_c [10] = {0,0,0,0,1,1,1,2,2,3};
__device__ __constant__ int pair_cp[10] = {0,1,2,3,1,2,3,2,3,3};

__device__ inline float fdot2(half2_t a, half2_t b, float c) {
#if __has_builtin(__builtin_amdgcn_fdot2)
  return __builtin_amdgcn_fdot2(a, b, c, false);
#else
  return c + (float)a[0] * (float)b[0] + (float)a[1] * (float)b[1];
#endif
}
__device__ inline half2_t bch2(unsigned u) {
  union { unsigned u; half2_t h; } x; x.u = u; return x.h;
}
__device__ inline unsigned bcu(half2_t h) {
  union { unsigned u; half2_t h; } x; x.h = h; return x.u;
}
__device__ inline unsigned packf2(float a, float b) {
  half2_t h; h[0] = (_Float16)a; h[1] = (_Float16)b;
  union { unsigned u; half2_t h; } x; x.h = h; return x.u;
}
__device__ inline unsigned pkmul(unsigned u, half2_t c) {
  return bcu(bch2(u) * c);   // v_pk_mul_f16
}

// ---------------- K1: qkv GEMM + relu + bn1 partials; y1 stored HALF --------
__global__ __launch_bounds__(256) void k1_gemm(
    const float* __restrict__ x, const float* __restrict__ wq,
    _Float16* __restrict__ y1h, float* __restrict__ Pbuf)
{
  __shared__ float xs[64][132];
  const int b = blockIdx.x >> 7, l = blockIdx.x & 127;
  const int tid = threadIdx.x;
  const float* xp = x + (size_t)b * 1048576 + (size_t)l * 128;
  for (int idx = tid; idx < 2048; idx += 256) {
    int c = idx >> 5, w4 = (idx & 31) * 4;
    *(float4*)&xs[c][w4] = *(const float4*)&xp[c * 16384 + w4];
  }
  __syncthreads();
  const int ty = tid >> 4, tx = tid & 15;
  const int o0 = ty * 8, w0 = tx * 4;
  float acc[8][8];
#pragma unroll
  for (int u = 0; u < 8; ++u)
#pragma unroll
    for (int v = 0; v < 8; ++v) acc[u][v] = 0.f;

  for (int c4 = 0; c4 < 64; c4 += 4) {
    float wr[8][4];
#pragma unroll
    for (int u = 0; u < 8; ++u)
      *(float4*)&wr[u][0] = *(const float4*)&wq[(o0 + u) * 64 + c4];
#pragma unroll
    for (int dc = 0; dc < 4; ++dc) {
      float4 xa = *(const float4*)&xs[c4 + dc][w0];
      float4 xb = *(const float4*)&xs[c4 + dc][w0 + 64];
#pragma unroll
      for (int u = 0; u < 8; ++u) {
        float wv = wr[u][dc];
        acc[u][0] += wv * xa.x; acc[u][1] += wv * xa.y;
        acc[u][2] += wv * xa.z; acc[u][3] += wv * xa.w;
        acc[u][4] += wv * xb.x; acc[u][5] += wv * xb.y;
        acc[u][6] += wv * xb.z; acc[u][7] += wv * xb.w;
      }
    }
  }
  _Float16* y1p = y1h + (size_t)(b * 128 + l) * 16384;
#pragma unroll
  for (int u = 0; u < 8; ++u) {
#pragma unroll
    for (int v = 0; v < 8; ++v) acc[u][v] = fmaxf(acc[u][v], 0.f);
    uint2 pa, pb;
    pa.x = packf2(acc[u][0], acc[u][1]); pa.y = packf2(acc[u][2], acc[u][3]);
    pb.x = packf2(acc[u][4], acc[u][5]); pb.y = packf2(acc[u][6], acc[u][7]);
    *(uint2*)&y1p[(o0 + u) * 128 + w0] = pa;
    *(uint2*)&y1p[(o0 + u) * 128 + w0 + 64] = pb;
    float s  = acc[u][0] + acc[u][1] + acc[u][2] + acc[u][3]
             + acc[u][4] + acc[u][5] + acc[u][6] + acc[u][7];
    float ss = acc[u][0]*acc[u][0] + acc[u][1]*acc[u][1] + acc[u][2]*acc[u][2]
             + acc[u][3]*acc[u][3] + acc[u][4]*acc[u][4] + acc[u][5]*acc[u][5]
             + acc[u][6]*acc[u][6] + acc[u][7]*acc[u][7];
#pragma unroll
    for (int off = 1; off < 16; off <<= 1) {
      s  += __shfl_xor(s, off);
      ss += __shfl_xor(ss, off);
    }
    if (tx == 0) {
      Pbuf[blockIdx.x * 256 + o0 + u] = s;
      Pbuf[blockIdx.x * 256 + 128 + o0 + u] = ss;
    }
  }
}

// ---------------- K_tr: y1h -> y2h (BN stats reduced in-block, applied) -----
__global__ __launch_bounds__(256) void k_tr(
    const _Float16* __restrict__ y1h, const float* __restrict__ Pbuf,
    const float* __restrict__ g1, const float* __restrict__ b1,
    unsigned* __restrict__ y2h)
{
  __shared__ _Float16 th[2][64][134];
  __shared__ float scsh[4];
  const int s = blockIdx.x & 63, b = blockIdx.x >> 6;
  const int h = s >> 3, slot = s & 7;
  const int o0 = 2 * s, o1 = 2 * s + 1;
  const int tid = threadIdx.x;
  {
    int r = tid >> 6, lane = tid & 63;
    int row = ((r & 1) ? o1 : o0) + (r >> 1) * 128;
    float a = 0.f;
#pragma unroll
    for (int m = 0; m < 8; ++m) a += Pbuf[(lane + 64 * m) * 256 + row];
#pragma unroll
    for (int off = 1; off < 64; off <<= 1) a += __shfl_xor(a, off);
    if (lane == 0) scsh[r] = a;
  }
  __syncthreads();
  const float inv = 1.f / 65536.f;
  const float m0 = scsh[0] * inv, v0 = scsh[2] * inv - m0 * m0;
  const float m1 = scsh[1] * inv, v1 = scsh[3] * inv - m1 * m1;
  const float sc0 = g1[o0] * rsqrtf(v0 + EPS), sh0 = b1[o0] - m0 * sc0;
  const float sc1 = g1[o1] * rsqrtf(v1 + EPS), sh1 = b1[o1] - m1 * sc1;
  for (int lh = 0; lh < 2; ++lh) {
    const int l0 = lh * 64;
    for (int idx = tid; idx < 4096; idx += 256) {
      int ll = idx >> 6, wp = idx & 63;
      size_t base = ((size_t)(b * 128 + l0 + ll) * 128) * 128 + 2 * wp;
      unsigned a0 = *(const unsigned*)&y1h[base + (size_t)o0 * 128];
      unsigned a1 = *(const unsigned*)&y1h[base + (size_t)o1 * 128];
      half2_t ha = bch2(a0), hb = bch2(a1);
      *(unsigned*)&th[0][ll][2 * wp] =
          packf2((float)ha[0] * sc0 + sh0, (float)ha[1] * sc0 + sh0);
      *(unsigned*)&th[1][ll][2 * wp] =
          packf2((float)hb[0] * sc1 + sh1, (float)hb[1] * sc1 + sh1);
    }
    __syncthreads();
    for (int idx = tid; idx < 8192; idx += 256) {
      int w = idx >> 6, ll = idx & 63;
      unsigned pk;
      { half2_t hh; hh[0] = th[0][ll][w]; hh[1] = th[1][ll][w];
        union { unsigned u; half2_t h; } xx; xx.h = hh; pk = xx.u; }
      y2h[((size_t)((b * 128 + w) * 8 + h) * 8 + slot) * 128 + l0 + ll] = pk;
    }
    __syncthreads();
  }
}

// ---------------- K0: PT tables + packed qk-pos + vpx tables ----------------
__global__ __launch_bounds__(128) void k0_pos(const float* __restrict__ pos,
                                              float* __restrict__ PT,
                                              unsigned* __restrict__ pos_h,
                                              unsigned* __restrict__ vpxg)
{
  const int blk = blockIdx.x, tid = threadIdx.x;
  if (blk == 28) {
    for (int u = tid; u < 255; u += 128) {
#pragma unroll
      for (int s = 0; s < 4; ++s)
        pos_h[u * 4 + s] = packf2(pos[(2 * s) * 255 + u], pos[(2 * s + 1) * 255 + u]);
    }
    return;
  }
  if (blk == 29) {
    // flat vpx, sel-shifted: index = sel*1540 + rp*12 + c  (1540 = 4 mod 32 words)
    for (int m = tid; m < 3084; m += 128) {
      int sel = m / 1540, rem = m - sel * 1540;
      unsigned val = 0;
      if (sel < 2 && rem < 1536) {
        int rp = rem / 12, c = rem % 12;
        if (c < 8) {
          int ua = (sel ? 254 : 253) - 2 * rp;
          int ub = ua - 1;
          float fa = (ua >= 0) ? pos[(8 + c) * 255 + ua] : 0.f;
          float fb = (ub >= 0) ? pos[(8 + c) * 255 + ub] : 0.f;
          val = packf2(fa, fb);
        }
      }
      vpxg[m] = val;
    }
    return;
  }
  __shared__ float r0[255], r1[255];
  int rowA, rowB, out;
  bool prod;
  if (blk < 4)       { rowA = blk;                 rowB = rowA;               out = blk * 128;              prod = false; }
  else if (blk < 14) { int m = blk - 4;  rowA = pair_c[m];     rowB = pair_cp[m];     out = 1024 + m * 128; prod = true; }
  else if (blk < 18) { rowA = 4 + (blk - 14);      rowB = rowA;               out = 512 + (blk - 14) * 128; prod = false; }
  else               { int m = blk - 18; rowA = 4 + pair_c[m]; rowB = 4 + pair_cp[m]; out = 2304 + m * 128; prod = true; }
  for (int u = tid; u < 255; u += 128) {
    r0[u] = pos[rowA * 255 + u];
    r1[u] = pos[rowB * 255 + u];
  }
  __syncthreads();
  float s = 0.f;
  if (prod) {
    for (int d = 0; d < 128; ++d) s += r0[tid + d] * r1[tid + d];
  } else {
    for (int d = 0; d < 128; ++d) s += r0[tid + d];
  }
  PT[out + tid] = s;
}

// ---------------- K3: att stats, ONE (n,h) unit per wave, no atomics --------
__global__ __launch_bounds__(256) void k3_stats(
    const unsigned* __restrict__ y2h, const float* __restrict__ PT,
    float* __restrict__ Pb3)
{
  const int W = blockIdx.x * 4 + (threadIdx.x >> 6);
  const int lane = threadIdx.x & 63;
  const unsigned* yb = y2h + (size_t)W * 1024;
  float q[4][2], k[4][2];
#pragma unroll
  for (int pl = 0; pl < 2; ++pl) {
    half2_t ha = bch2(yb[pl * 128 + lane]);
    half2_t hb = bch2(yb[pl * 128 + 64 + lane]);
    q[2 * pl][0] = (float)ha[0]; q[2 * pl + 1][0] = (float)ha[1];
    q[2 * pl][1] = (float)hb[0]; q[2 * pl + 1][1] = (float)hb[1];
    half2_t hc = bch2(yb[(2 + pl) * 128 + lane]);
    half2_t hd = bch2(yb[(2 + pl) * 128 + 64 + lane]);
    k[2 * pl][0] = (float)hc[0]; k[2 * pl + 1][0] = (float)hc[1];
    k[2 * pl][1] = (float)hd[0]; k[2 * pl + 1][1] = (float)hd[1];
  }
  float vals[32];
#pragma unroll
  for (int c = 0; c < 4; ++c) {
    vals[c]     = q[c][0] + q[c][1];
    vals[4 + c] = k[c][0] + k[c][1];
  }
#pragma unroll
  for (int m = 0; m < 10; ++m) {
    int c = pair_c[m], cp = pair_cp[m];
    vals[8 + m]  = q[c][0] * q[cp][0] + q[c][1] * q[cp][1];
    vals[18 + m] = k[c][0] * k[cp][0] + k[c][1] * k[cp][1];
  }
  float qr = 0, qrss = 0, kr = 0, krss = 0;
#pragma unroll
  for (int c = 0; c < 4; ++c) {
    qr += q[c][0] * PT[c * 128 + lane]       + q[c][1] * PT[c * 128 + 64 + lane];
    kr += k[c][0] * PT[512 + c * 128 + lane] + k[c][1] * PT[512 + c * 128 + 64 + lane];
  }
#pragma unroll
  for (int m = 0; m < 10; ++m) {
    int c = pair_c[m], cp = pair_cp[m];
    float mult = (c == cp) ? 1.f : 2.f;
    qrss += mult * (q[c][0] * q[cp][0] * PT[1024 + m * 128 + lane]
                  + q[c][1] * q[cp][1] * PT[1024 + m * 128 + 64 + lane]);
    krss += mult * (k[c][0] * k[cp][0] * PT[2304 + m * 128 + lane]
                  + k[c][1] * k[cp][1] * PT[2304 + m * 128 + 64 + lane]);
  }
  vals[28] = qr; vals[29] = qrss; vals[30] = kr; vals[31] = krss;
#pragma unroll
  for (int v = 0; v < 32; ++v) {
    float t = vals[v];
#pragma unroll
    for (int off = 1; off < 64; off <<= 1) t += __shfl_xor(t, off);
    vals[v] = t;
  }
  if (lane == 0) {
    float qk_sum = 0, qk_ss = 0;
#pragma unroll
    for (int c = 0; c < 4; ++c) qk_sum += vals[c] * vals[4 + c];
#pragma unroll
    for (int m = 0; m < 10; ++m) {
      float mult = (pair_c[m] == pair_cp[m]) ? 1.f : 2.f;
      qk_ss += mult * vals[8 + m] * vals[18 + m];
    }
    float* o = Pb3 + W * 6;
    o[0] = qk_sum; o[1] = qk_ss;
    o[2] = vals[28]; o[3] = vals[29]; o[4] = vals[30]; o[5] = vals[31];
  }
}

// ---------------- KR1: reduce Pb3 (4096 units) + finalize att bn coefs ------
__global__ __launch_bounds__(384) void kR1(
    const float* __restrict__ Pb3, float* __restrict__ S,
    const float* __restrict__ ga, const float* __restrict__ ba,
    const float* __restrict__ gqr, const float* __restrict__ gkr)
{
  __shared__ float sums[48];
  const int t = threadIdx.x;
  const int col = t >> 3, sub = t & 7;
  if (col < 48) {
    const int h = col / 6, k = col % 6;
    float v = 0.f;
#pragma unroll
    for (int j = 0; j < 64; ++j) {
      int n = sub * 64 + j;
      v += Pb3[(size_t)(n * 8 + h) * 6 + k];
    }
    v += __shfl_xor(v, 1);
    v += __shfl_xor(v, 2);
    v += __shfl_xor(v, 4);
    if (sub == 0) sums[col] = v;
  }
  __syncthreads();
  if (t < 8) {
    const int h = t;
    const float inv = 1.f / 8388608.f;
    float gates[3] = {1.f, gqr[0], gkr[0]};
    float csum = 0.f;
#pragma unroll
    for (int g = 0; g < 3; ++g) {
      float mr = sums[h * 6 + 2 * g] * inv;
      float er = sums[h * 6 + 2 * g + 1] * inv;
      float gt = gates[g];
      float mean = gt * mr;
      float var = gt * gt * er - mean * mean;
      float sc = ga[g * 8 + h] * rsqrtf(var + EPS);
      S[560 + g * 8 + h] = gt * sc;
      csum += ba[g * 8 + h] - mean * sc;
    }
    S[584 + h] = csum;
  }
}

// ---------------- K5: C-folded operands, online-max softmax, dot2 PV --------
// qkv_s rows (32B): 0 qa01 1 qa23 (q*C0) 2 qb01 3 qb23 (q*C1)
//                   4 k01 5 k23 (raw)    6 kc01 7 kc23 (k*C2)
__global__ __launch_bounds__(512, 6) void k5_apply(
    const unsigned* __restrict__ y2h, const unsigned* __restrict__ pos_h,
    const unsigned* __restrict__ vpxg,
    float* __restrict__ S, _Float16* __restrict__ av, _Float16* __restrict__ avp,
    const float* __restrict__ gv_p, const float* __restrict__ gvp_p,
    float* __restrict__ Vbuf)
{
  __shared__ __align__(16) unsigned qkv_s[128][8];
  __shared__ __align__(16) unsigned posm[255][4];
  __shared__ __align__(16) unsigned vt[64][8];
  __shared__ __align__(16) unsigned vpxf[3084];  // flat, sel-shifted (1540/sel)
  __shared__ float red[8][4];
  const int h = blockIdx.x & 7, n = blockIdx.x >> 3;
  const int tid = threadIdx.x;
  const unsigned* yb = y2h + (size_t)(n * 8 + h) * 1024;
  const float C0 = S[560 + h], C1 = S[568 + h], C2 = S[576 + h], C3v = S[584 + h];
  half2_t C0h, C1h, C2h;
  C0h[0] = C0h[1] = (_Float16)C0;
  C1h[0] = C1h[1] = (_Float16)C1;
  C2h[0] = C2h[1] = (_Float16)C2;
  {
    int l = tid >> 2, s = tid & 3;
    if (s == 0) {
      unsigned q01 = yb[l], q23 = yb[128 + l];
      qkv_s[l][0] = pkmul(q01, C0h); qkv_s[l][1] = pkmul(q23, C0h);
    } else if (s == 1) {
      unsigned q01 = yb[l], q23 = yb[128 + l];
      qkv_s[l][2] = pkmul(q01, C1h); qkv_s[l][3] = pkmul(q23, C1h);
    } else if (s == 2) {
      qkv_s[l][4] = yb[256 + l]; qkv_s[l][5] = yb[384 + l];
    } else {
      qkv_s[l][6] = pkmul(yb[256 + l], C2h); qkv_s[l][7] = pkmul(yb[384 + l], C2h);
    }
  }
  {
    unsigned* pf = (unsigned*)posm;
    for (int m = tid; m < 1020; m += 512) pf[m] = pos_h[m];
  }
  for (int m = tid; m < 3084; m += 512) vpxf[m] = vpxg[m];
  if (tid < 256) {
    int s = tid & 3, jp = tid >> 2;
    unsigned a0 = yb[(4 + s) * 128 + 2 * jp];
    unsigned a1 = yb[(4 + s) * 128 + 2 * jp + 1];
    vt[jp][2 * s]     = (a0 & 0xffffu) | (a1 << 16);
    vt[jp][2 * s + 1] = (a0 >> 16) | (a1 & 0xffff0000u);
  }
  __syncthreads();

  const int p = tid >> 2, isub = tid & 3;
  uint4 qown = *(const uint4*)&qkv_s[p][0];
  uint2 kco  = *(const uint2*)&qkv_s[p][6];
  const half2_t qa01 = bch2(qown.x), qa23 = bch2(qown.y);
  const half2_t qb01 = bch2(qown.z), qb23 = bch2(qown.w);
  const half2_t kc01 = bch2(kco.x),  kc23 = bch2(kco.y);
  const unsigned* vprow = &vpxf[(p & 1) * 1540 + (63 - (p >> 1)) * 12];
  const half2_t one2 = bch2(packf2(1.f, 1.f));

  float mcur = -1e30f;
  float sum = 0.f;
  float accv[8], accvp[8];
#pragma unroll
  for (int c = 0; c < 8; ++c) { accv[c] = 0.f; accvp[c] = 0.f; }

#pragma unroll
  for (int jj = 0; jj < 8; ++jj) {
    const int jpA = isub + 8 * jj;
    const int jpB = jpA + 4;
    const int i0A = 2 * jpA, i0B = 2 * jpB;
    const int uA = p - i0A + 127;
    const int uB = uA - 8;
    uint2 kaA = *(const uint2*)&qkv_s[i0A][4];
    uint2 kbA = *(const uint2*)&qkv_s[i0A + 1][4];
    uint2 kaB = *(const uint2*)&qkv_s[i0B][4];
    uint2 kbB = *(const uint2*)&qkv_s[i0B + 1][4];
    uint4 paA = *(const uint4*)&posm[uA][0];
    uint4 pbA = *(const uint4*)&posm[uA - 1][0];
    uint4 paB = *(const uint4*)&posm[uB][0];
    uint4 pbB = *(const uint4*)&posm[uB - 1][0];
    float s0 = fdot2(qa01, bch2(kaA.x), fdot2(qa23, bch2(kaA.y),
               fdot2(qb01, bch2(paA.x), fdot2(qb23, bch2(paA.y),
               fdot2(kc01, bch2(paA.z), fdot2(kc23, bch2(paA.w), C3v))))));
    float s1 = fdot2(qa01, bch2(kbA.x), fdot2(qa23, bch2(kbA.y),
               fdot2(qb01, bch2(pbA.x), fdot2(qb23, bch2(pbA.y),
               fdot2(kc01, bch2(pbA.z), fdot2(kc23, bch2(pbA.w), C3v))))));
    float s2 = fdot2(qa01, bch2(kaB.x), fdot2(qa23, bch2(kaB.y),
               fdot2(qb01, bch2(paB.x), fdot2(qb23, bch2(paB.y),
               fdot2(kc01, bch2(paB.z), fdot2(kc23, bch2(paB.w), C3v))))));
    float s3 = fdot2(qa01, bch2(kbB.x), fdot2(qa23, bch2(kbB.y),
               fdot2(qb01, bch2(pbB.x), fdot2(qb23, bch2(pbB.y),
               fdot2(kc01, bch2(pbB.z), fdot2(kc23, bch2(pbB.w), C3v))))));
    float mp = fmaxf(fmaxf(s0, s1), fmaxf(s2, s3));
    if (mp > mcur) {
      float r = __expf(mcur - mp);
      mcur = mp;
      sum *= r;
#pragma unroll
      for (int c = 0; c < 8; ++c) { accv[c] *= r; accvp[c] *= r; }
    }
    float e0 = __expf(s0 - mcur);
    float e1 = __expf(s1 - mcur);
    float e2f = __expf(s2 - mcur);
    float e3f = __expf(s3 - mcur);
    const half2_t eA = bch2(packf2(e0, e1));
    const half2_t eB = bch2(packf2(e2f, e3f));
    sum = fdot2(eB, one2, fdot2(eA, one2, sum));
    uint4 vaA = *(const uint4*)&vt[jpA][0];
    uint4 vbA = *(const uint4*)&vt[jpA][4];
    uint4 vaB = *(const uint4*)&vt[jpB][0];
    uint4 vbB = *(const uint4*)&vt[jpB][4];
    const unsigned* wrA = vprow + jpA * 12;
    const unsigned* wrB = vprow + jpB * 12;
    uint4 waA = *(const uint4*)wrA;
    uint4 wbA = *(const uint4*)(wrA + 4);
    uint4 waB = *(const uint4*)wrB;
    uint4 wbB = *(const uint4*)(wrB + 4);
    accv[0] = fdot2(eB, bch2(vaB.x), fdot2(eA, bch2(vaA.x), accv[0]));
    accv[1] = fdot2(eB, bch2(vaB.y), fdot2(eA, bch2(vaA.y), accv[1]));
    accv[2] = fdot2(eB, bch2(vaB.z), fdot2(eA, bch2(vaA.z), accv[2]));
    accv[3] = fdot2(eB, bch2(vaB.w), fdot2(eA, bch2(vaA.w), accv[3]));
    accv[4] = fdot2(eB, bch2(vbB.x), fdot2(eA, bch2(vbA.x), accv[4]));
    accv[5] = fdot2(eB, bch2(vbB.y), fdot2(eA, bch2(vbA.y), accv[5]));
    accv[6] = fdot2(eB, bch2(vbB.z), fdot2(eA, bch2(vbA.z), accv[6]));
    accv[7] = fdot2(eB, bch2(vbB.w), fdot2(eA, bch2(vbA.w), accv[7]));
    accvp[0] = fdot2(eB, bch2(waB.x), fdot2(eA, bch2(waA.x), accvp[0]));
    accvp[1] = fdot2(eB, bch2(waB.y), fdot2(eA, bch2(waA.y), accvp[1]));
    accvp[2] = fdot2(eB, bch2(waB.z), fdot2(eA, bch2(waA.z), accvp[2]));
    accvp[3] = fdot2(eB, bch2(waB.w), fdot2(eA, bch2(waA.w), accvp[3]));
    accvp[4] = fdot2(eB, bch2(wbB.x), fdot2(eA, bch2(wbA.x), accvp[4]));
    accvp[5] = fdot2(eB, bch2(wbB.y), fdot2(eA, bch2(wbA.y), accvp[5]));
    accvp[6] = fdot2(eB, bch2(wbB.z), fdot2(eA, bch2(wbA.z), accvp[6]));
    accvp[7] = fdot2(eB, bch2(wbB.w), fdot2(eA, bch2(wbA.w), accvp[7]));
  }
  float M = fmaxf(mcur, __shfl_xor(mcur, 1));
  M = fmaxf(M, __shfl_xor(M, 2));
  {
    float r = __expf(mcur - M);
    sum *= r;
#pragma unroll
    for (int c = 0; c < 8; ++c) { accv[c] *= r; accvp[c] *= r; }
  }
  sum += __shfl_xor(sum, 1);
  sum += __shfl_xor(sum, 2);
#pragma unroll
  for (int c = 0; c < 8; ++c) {
    accv[c]  += __shfl_xor(accv[c], 1);  accv[c]  += __shfl_xor(accv[c], 2);
    accvp[c] += __shfl_xor(accvp[c], 1); accvp[c] += __shfl_xor(accvp[c], 2);
  }

  float sv = 0, ssv = 0, svp = 0, ssvp = 0;
  if (isub == 0) {
    const float fv = gv_p[0] / sum, fp2 = gvp_p[0] / sum;
    size_t base = ((size_t)(n * 8 + h) * 8) * 128 + p;
#pragma unroll
    for (int c = 0; c < 8; ++c) {
      float x1 = accv[c] * fv;
      float x2 = accvp[c] * fp2;
      av [base + c * 128] = (_Float16)x1;
      avp[base + c * 128] = (_Float16)x2;
      sv += x1; ssv += x1 * x1; svp += x2; ssvp += x2 * x2;
    }
  }
  float vals[4] = {sv, ssv, svp, ssvp};
#pragma unroll
  for (int kk = 0; kk < 4; ++kk) {
    float v = vals[kk];
#pragma unroll
    for (int off = 1; off < 64; off <<= 1) v += __shfl_xor(v, off);
    vals[kk] = v;
  }
  const int wid = tid >> 6, lane = tid & 63;
  if (lane == 0) {
#pragma unroll
    for (int kk = 0; kk < 4; ++kk) red[wid][kk] = vals[kk];
  }
  __syncthreads();
  if (tid == 0) {
    float t0 = 0, t1 = 0, t2 = 0, t3 = 0;
#pragma unroll
    for (int w = 0; w < 8; ++w) {
      t0 += red[w][0]; t1 += red[w][1]; t2 += red[w][2]; t3 += red[w][3];
    }
    float* o = Vbuf + (size_t)blockIdx.x * 4;
    o[0] = t0; o[1] = t1; o[2] = t2; o[3] = t3;
  }
}

// ---------------- KR2: reduce Vbuf + finalize v bn (merged) -----------------
__global__ __launch_bounds__(512) void kR2(
    const float* __restrict__ Vbuf, float* __restrict__ S,
    const float* __restrict__ gv, const float* __restrict__ bv)
{
  __shared__ float part[32][17];
  const int t = threadIdx.x;
  const int col = t >> 4, sub = t & 15;
  const int k = col >> 3, h = col & 7;
  float v = 0.f;
  for (int m = 0; m < 32; ++m) {
    int n = sub + 16 * m;
    v += Vbuf[(size_t)(n * 8 + h) * 4 + k];
  }
  part[col][sub] = v;
  __syncthreads();
  if (t < 32) {
    float s = 0.f;
#pragma unroll
    for (int j = 0; j < 16; ++j) s += part[t][j];
    part[t][16] = s;
  }
  __syncthreads();
  if (t < 8) {
    const int hh = t;
    const float inv = 1.f / 524288.f;
    float m1 = part[0 * 8 + hh][16] * inv;
    float e1 = part[1 * 8 + hh][16] * inv;
    float var = e1 - m1 * m1;
    float sc = gv[hh] * rsqrtf(var + EPS);
    S[624 + hh] = sc;
    S[632 + hh] = bv[hh] - m1 * sc;
    float m2 = part[2 * 8 + hh][16] * inv;
    float e2 = part[3 * 8 + hh][16] * inv;
    var = e2 - m2 * m2;
    sc = gv[8 + hh] * rsqrtf(var + EPS);
    S[640 + hh] = sc;
    S[648 + hh] = bv[8 + hh] - m2 * sc;
  }
}

// ---------------- K7: bn apply + sum halves + LDS-tiled transpose out -------
__global__ __launch_bounds__(256) void k7_out(
    const _Float16* __restrict__ av, const _Float16* __restrict__ avp,
    const float* __restrict__ S, float* __restrict__ out)
{
  __shared__ float tile[64][129];
  const int wt = blockIdx.x & 1;
  const int d  = (blockIdx.x >> 1) & 63;
  const int b  = blockIdx.x >> 7;
  const int h = d >> 3, c = d & 7;
  const float scv = S[624 + h], shv = S[632 + h];
  const float scp = S[640 + h], shp = S[648 + h];
  const int tid = threadIdx.x;
  for (int idx = tid; idx < 8192; idx += 256) {
    int wl = idx >> 7, pp = idx & 127;
    int n = b * 128 + wt * 64 + wl;
    size_t base = (((size_t)n * 8 + h) * 8 + c) * 128 + pp;
    tile[wl][pp] = (float)av[base] * scv + shv + (float)avp[base] * scp + shp;
  }
  __syncthreads();
  for (int idx = tid; idx < 8192; idx += 256) {
    int pp = idx >> 6, wl = idx & 63;
    out[(((size_t)b * 64 + d) * 128 + pp) * 128 + wt * 64 + wl] = tile[wl][pp];
  }
}

// ---------------- launch ----------------------------------------------------
extern "C" void kernel_launch(void* const* d_in, const int* in_sizes, int n_in,
                              void* d_out, int out_size, void* d_ws, size_t ws_size,
                              hipStream_t stream)
{
  const float* x   = (const float*)d_in[0];
  const float* wq  = (const float*)d_in[1];
  const float* g1  = (const float*)d_in[2];
  const float* b1  = (const float*)d_in[3];
  const float* pos = (const float*)d_in[4];
  const float* gqr = (const float*)d_in[5];
  const float* gkr = (const float*)d_in[6];
  const float* gvp = (const float*)d_in[7];
  const float* gv  = (const float*)d_in[8];
  const float* ga  = (const float*)d_in[9];
  const float* ba  = (const float*)d_in[10];
  const float* gv2 = (const float*)d_in[11];
  const float* bv2 = (const float*)d_in[12];

  float* ws = (float*)d_ws;
  _Float16* y1h   = (_Float16*)ws;
  _Float16* av    = (_Float16*)ws;
  _Float16* avp   = (_Float16*)ws + 4194304;
  float*    Pb3   = ws + 4200000;
  float*    Vbuf  = ws + 4250000;
  float*    Pbuf  = ws + 4300000;
  unsigned* y2h   = (unsigned*)(ws + 8388608);
  float*    S     = ws + 16777216;
  unsigned* pos_h = (unsigned*)(ws + 16778240);
  float*    PT    = ws + 16781312;
  unsigned* vpxg  = (unsigned*)(ws + 16785000);
  float*    out   = (float*)d_out;

  k0_pos<<<30, 128, 0, stream>>>(pos, PT, pos_h, vpxg);
  k1_gemm<<<512, 256, 0, stream>>>(x, wq, y1h, Pbuf);
  k_tr<<<256, 256, 0, stream>>>(y1h, Pbuf, g1, b1, y2h);
  k3_stats<<<1024, 256, 0, stream>>>(y2h, PT, Pb3);
  kR1<<<1, 384, 0, stream>>>(Pb3, S, ga, ba, gqr, gkr);
  k5_apply<<<4096, 512, 0, stream>>>(y2h, pos_h, vpxg, S, av, avp, gv, gvp, Vbuf);
  kR2<<<1, 512, 0, stream>>>(Vbuf, S, gv2, bv2);
  k7_out<<<512, 256, 0, stream>>>(av, avp, S, out);
}